// Round 4
// baseline (366.346 us; speedup 1.0000x reference)
//
#include <hip/hip_runtime.h>
#include <hip/hip_bf16.h>

// Problem constants (B=2, S=1024, D=1024, F=2048, H=16, hd=64, G=4, Epg=2, E=8)
#define TT 2048
#define DD 1024
#define FF 2048
#define SS 1024
#define NHD 16
#define HDD 64
#define NG 4
#define EPG 2
#define NE 8

typedef __attribute__((ext_vector_type(8))) short bf16x8;
typedef __attribute__((ext_vector_type(4))) float f32x4;
typedef __attribute__((ext_vector_type(4))) unsigned short ush4;

__device__ __forceinline__ unsigned short f2bf(float x) {
    unsigned int u = __float_as_uint(x);
    u = (u + 0x7fffu + ((u >> 16) & 1u)) >> 16;
    return (unsigned short)u;
}
__device__ __forceinline__ float bf2f(unsigned short h) {
    return __uint_as_float((unsigned int)h << 16);
}

__device__ __forceinline__ float wave_sum(float s) {
#pragma unroll
    for (int off = 32; off > 0; off >>= 1) s += __shfl_xor(s, off);
    return s;
}

// ---------------------------------------------------------------------------
// fp32 -> bf16 hi/lo split planes
// ---------------------------------------------------------------------------
__global__ __launch_bounds__(256) void split_bf16_kernel(
    const float* __restrict__ in, unsigned short* __restrict__ hi,
    unsigned short* __restrict__ lo, int n4)
{
    const int i = blockIdx.x * 256 + threadIdx.x;
    if (i >= n4) return;
    const float4 v = ((const float4*)in)[i];
    float vv[4] = {v.x, v.y, v.z, v.w};
    ush4 h, l;
#pragma unroll
    for (int j = 0; j < 4; ++j) {
        const unsigned short hb = f2bf(vv[j]);
        ((unsigned short*)&h)[j] = hb;
        ((unsigned short*)&l)[j] = f2bf(vv[j] - bf2f(hb));
    }
    ((ush4*)hi)[i] = h;
    ((ush4*)lo)[i] = l;
}

// ---------------------------------------------------------------------------
// Split-precision GEMM: C[M,N] = A[M,K] . B[N,K]^T + bias (+resid).
// A ~ Ah+Al, B ~ Bh+Bl (bf16 planes). 3-term MFMA: AhBh + AhBl + AlBh.
// 128x128 tile, BK=64, 4 waves, XOR-swizzled LDS.
// ---------------------------------------------------------------------------
__global__ __launch_bounds__(256, 2) void gemm_split_kernel(
    const unsigned short* __restrict__ Ah, const unsigned short* __restrict__ Al,
    const unsigned short* __restrict__ Bh, const unsigned short* __restrict__ Bl,
    const float* __restrict__ bias, const float* __restrict__ resid,
    float* __restrict__ C, unsigned short* __restrict__ Chi,
    unsigned short* __restrict__ Clo, int qscale_n, int M, int N, int K)
{
    __shared__ unsigned short sAh[128 * 64];
    __shared__ unsigned short sAl[128 * 64];
    __shared__ unsigned short sBh[128 * 64];
    __shared__ unsigned short sBl[128 * 64];
    const int tid = threadIdx.x;
    const int lane = tid & 63, wid = tid >> 6;
    const int l15 = lane & 15, lg = lane >> 4;
    const int wr = wid >> 1, wc = wid & 1;
    const int n0 = blockIdx.x << 7, m0 = blockIdx.y << 7;

    f32x4 acc[4][4];
#pragma unroll
    for (int mi = 0; mi < 4; ++mi)
#pragma unroll
        for (int ni = 0; ni < 4; ++ni) acc[mi][ni] = (f32x4){0.f, 0.f, 0.f, 0.f};

    for (int k0 = 0; k0 < K; k0 += 64) {
#pragma unroll
        for (int r = 0; r < 4; ++r) {
            const int s = tid + (r << 8);
            const int row = s >> 3, c = s & 7;
            const int phys = (s & ~7) | (c ^ (row & 7));
            const size_t ga = (size_t)(m0 + row) * K + k0 + (c << 3);
            const size_t gb = (size_t)(n0 + row) * K + k0 + (c << 3);
            *(bf16x8*)&sAh[phys << 3] = *(const bf16x8*)(Ah + ga);
            *(bf16x8*)&sAl[phys << 3] = *(const bf16x8*)(Al + ga);
            *(bf16x8*)&sBh[phys << 3] = *(const bf16x8*)(Bh + gb);
            *(bf16x8*)&sBl[phys << 3] = *(const bf16x8*)(Bl + gb);
        }
        __syncthreads();
#pragma unroll
        for (int ks = 0; ks < 2; ++ks) {
            bf16x8 ah[4], al[4], bh[4], bl[4];
            const int ac = (ks << 2) + lg;
#pragma unroll
            for (int i = 0; i < 4; ++i) {
                const int ar = (wr << 6) + (i << 4) + l15;
                const int pa = ((ar << 3) | (ac ^ (ar & 7))) << 3;
                ah[i] = *(const bf16x8*)&sAh[pa];
                al[i] = *(const bf16x8*)&sAl[pa];
                const int br = (wc << 6) + (i << 4) + l15;
                const int pb = ((br << 3) | (ac ^ (br & 7))) << 3;
                bh[i] = *(const bf16x8*)&sBh[pb];
                bl[i] = *(const bf16x8*)&sBl[pb];
            }
#pragma unroll
            for (int mi = 0; mi < 4; ++mi)
#pragma unroll
                for (int ni = 0; ni < 4; ++ni) {
                    acc[mi][ni] = __builtin_amdgcn_mfma_f32_16x16x32_bf16(ah[mi], bh[ni], acc[mi][ni], 0, 0, 0);
                    acc[mi][ni] = __builtin_amdgcn_mfma_f32_16x16x32_bf16(ah[mi], bl[ni], acc[mi][ni], 0, 0, 0);
                    acc[mi][ni] = __builtin_amdgcn_mfma_f32_16x16x32_bf16(al[mi], bh[ni], acc[mi][ni], 0, 0, 0);
                }
        }
        __syncthreads();
    }
#pragma unroll
    for (int mi = 0; mi < 4; ++mi)
#pragma unroll
        for (int ni = 0; ni < 4; ++ni)
#pragma unroll
            for (int r2 = 0; r2 < 4; ++r2) {
                const int m = m0 + (wr << 6) + (mi << 4) + (lg << 2) + r2;
                const int n = n0 + (wc << 6) + (ni << 4) + l15;
                float v = acc[mi][ni][r2] + bias[n];
                if (resid) v += resid[(size_t)m * N + n];
                const size_t idx = (size_t)m * N + n;
                if (Chi) {
                    if (n < qscale_n) v *= 0.125f;
                    const unsigned short hb = f2bf(v);
                    Chi[idx] = hb;
                    Clo[idx] = f2bf(v - bf2f(hb));
                } else {
                    C[idx] = v;
                }
            }
}

// ---------------------------------------------------------------------------
// V^T extraction: bf16 plane [t][3072] (V = cols 2048..3071 per head) ->
// [bh][64 d][1024 s] transposed plane.
// ---------------------------------------------------------------------------
__global__ __launch_bounds__(256) void vtrans_kernel(
    const unsigned short* __restrict__ src, unsigned short* __restrict__ dst)
{
    __shared__ unsigned short tile[64][65];
    const int bh = blockIdx.y, b = bh >> 4, h = bh & 15;
    const int s0 = blockIdx.x << 6;
    const int tid = threadIdx.x;
#pragma unroll
    for (int r = 0; r < 2; ++r) {
        const int sl = tid + (r << 8);
        const int rr = sl >> 3, c8 = (sl & 7) << 3;
        const bf16x8 v = *(const bf16x8*)(src + (size_t)(b * SS + s0 + rr) * 3072 + 2048 + h * HDD + c8);
#pragma unroll
        for (int j = 0; j < 8; ++j) tile[rr][c8 + j] = ((const unsigned short*)&v)[j];
    }
    __syncthreads();
#pragma unroll
    for (int r = 0; r < 2; ++r) {
        const int sl = tid + (r << 8);
        const int d = sl >> 3, s8 = (sl & 7) << 3;
        bf16x8 o;
#pragma unroll
        for (int j = 0; j < 8; ++j) ((unsigned short*)&o)[j] = tile[s8 + j][d];
        *(bf16x8*)(dst + (size_t)(bh * HDD + d) * SS + s0 + s8) = o;
    }
}

// ---------------------------------------------------------------------------
// Split-precision MFMA flash attention, kv-split x2.
// grid (S/64, B*H, 2), 256 threads = 4 waves, each wave owns 16 q-rows.
// P stored wave-private as [q][kv] (swizzled) -> vector b128 PV reads, and
// no barrier needed between P store and PV. Writes unnormalized partials.
// ---------------------------------------------------------------------------
__global__ __launch_bounds__(256) void attn_mfma_kernel(
    const unsigned short* __restrict__ qh, const unsigned short* __restrict__ ql,
    const unsigned short* __restrict__ vth, const unsigned short* __restrict__ vtl,
    float* __restrict__ opart, float* __restrict__ mpart, float* __restrict__ lpart)
{
    __shared__ unsigned short sQh[4096], sQl[4096];
    __shared__ unsigned short sKh[4096], sKl[4096];   // P[q][kv] hi/lo after QK
    __shared__ unsigned short sVh[4096], sVl[4096];
    const int bh = blockIdx.y, b = bh >> 4, h = bh & 15;
    const int q0 = blockIdx.x << 6;
    const int z = blockIdx.z;
    const int tid = threadIdx.x, lane = tid & 63, w = tid >> 6;
    const int l15 = lane & 15, lg = lane >> 4;

    // stage Q tile (rows q0..q0+63), swizzled [row][slot^(row&7)]
#pragma unroll
    for (int r = 0; r < 2; ++r) {
        const int s = tid + (r << 8);
        const int row = s >> 3, c = s & 7;
        const int phys = ((row << 3) | (c ^ (row & 7))) << 3;
        const size_t g = (size_t)(b * SS + q0 + row) * 3072 + h * HDD + (c << 3);
        *(bf16x8*)&sQh[phys] = *(const bf16x8*)(qh + g);
        *(bf16x8*)&sQl[phys] = *(const bf16x8*)(ql + g);
    }

    f32x4 accO[4];
#pragma unroll
    for (int nt = 0; nt < 4; ++nt) accO[nt] = (f32x4){0.f, 0.f, 0.f, 0.f};
    float m_run[4], l_run[4];
#pragma unroll
    for (int r2 = 0; r2 < 4; ++r2) { m_run[r2] = -3.0e38f; l_run[r2] = 0.f; }

    const int kvbeg = z << 9;
    for (int kv0 = kvbeg; kv0 < kvbeg + 512; kv0 += 64) {
        // stage K tile + V^T tile
#pragma unroll
        for (int r = 0; r < 2; ++r) {
            const int s = tid + (r << 8);
            const int row = s >> 3, c = s & 7;
            const int phys = ((row << 3) | (c ^ (row & 7))) << 3;
            const size_t gk = (size_t)(b * SS + kv0 + row) * 3072 + DD + h * HDD + (c << 3);
            *(bf16x8*)&sKh[phys] = *(const bf16x8*)(qh + gk);
            *(bf16x8*)&sKl[phys] = *(const bf16x8*)(ql + gk);
            const size_t gv = (size_t)(bh * HDD + row) * SS + kv0 + (c << 3);
            *(bf16x8*)&sVh[phys] = *(const bf16x8*)(vth + gv);
            *(bf16x8*)&sVl[phys] = *(const bf16x8*)(vtl + gv);
        }
        __syncthreads();

        // QK^T: S[q=w*16+lg*4+r2][kv=i*16+l15]
        f32x4 sacc[4];
#pragma unroll
        for (int i = 0; i < 4; ++i) sacc[i] = (f32x4){0.f, 0.f, 0.f, 0.f};
        __builtin_amdgcn_s_setprio(1);
#pragma unroll
        for (int ks = 0; ks < 2; ++ks) {
            const int ac = (ks << 2) + lg;
            const int ar = (w << 4) + l15;
            const int pa = ((ar << 3) | (ac ^ (ar & 7))) << 3;
            const bf16x8 ah = *(const bf16x8*)&sQh[pa];
            const bf16x8 al = *(const bf16x8*)&sQl[pa];
#pragma unroll
            for (int i = 0; i < 4; ++i) {
                const int br = (i << 4) + l15;
                const int pb = ((br << 3) | (ac ^ (br & 7))) << 3;
                const bf16x8 kbh = *(const bf16x8*)&sKh[pb];
                const bf16x8 kbl = *(const bf16x8*)&sKl[pb];
                sacc[i] = __builtin_amdgcn_mfma_f32_16x16x32_bf16(ah, kbh, sacc[i], 0, 0, 0);
                sacc[i] = __builtin_amdgcn_mfma_f32_16x16x32_bf16(ah, kbl, sacc[i], 0, 0, 0);
                sacc[i] = __builtin_amdgcn_mfma_f32_16x16x32_bf16(al, kbh, sacc[i], 0, 0, 0);
            }
        }
        __builtin_amdgcn_s_setprio(0);
        __syncthreads();   // all waves done reading K before P overwrites it

        // online softmax per q-row (reduce across the 16 lanes of l15)
#pragma unroll
        for (int r2 = 0; r2 < 4; ++r2) {
            float mx = fmaxf(fmaxf(sacc[0][r2], sacc[1][r2]), fmaxf(sacc[2][r2], sacc[3][r2]));
#pragma unroll
            for (int off = 1; off < 16; off <<= 1) mx = fmaxf(mx, __shfl_xor(mx, off));
            const float mn = fmaxf(m_run[r2], mx);
            const float corr = __expf(m_run[r2] - mn);
            m_run[r2] = mn;
            float ls = 0.f;
#pragma unroll
            for (int nt = 0; nt < 4; ++nt) {
                const float p = __expf(sacc[nt][r2] - mn);
                sacc[nt][r2] = p;
                ls += p;
            }
#pragma unroll
            for (int off = 1; off < 16; off <<= 1) ls += __shfl_xor(ls, off);
            l_run[r2] = l_run[r2] * corr + ls;
#pragma unroll
            for (int nt = 0; nt < 4; ++nt) accO[nt][r2] *= corr;
        }

        // store P[q][kv] hi/lo into dead K LDS (wave-private rows, swizzled)
#pragma unroll
        for (int nt = 0; nt < 4; ++nt)
#pragma unroll
            for (int r2 = 0; r2 < 4; ++r2) {
                const int qq = (w << 4) + (lg << 2) + r2;
                const int kv = (nt << 4) + l15;
                const int idx = (qq << 6) + ((((kv >> 3) ^ (qq & 7))) << 3) + (kv & 7);
                const float p = sacc[nt][r2];
                const unsigned short hb = f2bf(p);
                sKh[idx] = hb;
                sKl[idx] = f2bf(p - bf2f(hb));
            }
        // no barrier: each wave reads back only its own 16 q-rows

        // PV: O[q][d=nt*16+l15] += P[q][kv] * V[kv][d]
        __builtin_amdgcn_s_setprio(1);
#pragma unroll
        for (int ks = 0; ks < 2; ++ks) {
            const int qq = (w << 4) + l15;
            const int slot = (ks << 2) + lg;
            const int pidx = (qq << 6) + ((slot ^ (qq & 7)) << 3);
            const bf16x8 pah = *(const bf16x8*)&sKh[pidx];
            const bf16x8 pal = *(const bf16x8*)&sKl[pidx];
            const int ac = (ks << 2) + lg;
#pragma unroll
            for (int nt = 0; nt < 4; ++nt) {
                const int dr = (nt << 4) + l15;
                const int pv = ((dr << 3) | (ac ^ (dr & 7))) << 3;
                const bf16x8 vbh = *(const bf16x8*)&sVh[pv];
                const bf16x8 vbl = *(const bf16x8*)&sVl[pv];
                accO[nt] = __builtin_amdgcn_mfma_f32_16x16x32_bf16(pah, vbh, accO[nt], 0, 0, 0);
                accO[nt] = __builtin_amdgcn_mfma_f32_16x16x32_bf16(pah, vbl, accO[nt], 0, 0, 0);
                accO[nt] = __builtin_amdgcn_mfma_f32_16x16x32_bf16(pal, vbh, accO[nt], 0, 0, 0);
            }
        }
        __builtin_amdgcn_s_setprio(0);
        __syncthreads();   // P/V reads done before next tile's staging
    }

    // epilogue: unnormalized partial O' + per-row (m,l)
#pragma unroll
    for (int nt = 0; nt < 4; ++nt)
#pragma unroll
        for (int r2 = 0; r2 < 4; ++r2) {
            const int qq = q0 + (w << 4) + (lg << 2) + r2;
            const int dd = h * HDD + (nt << 4) + l15;
            opart[((size_t)z * TT + b * SS + qq) * DD + dd] = accO[nt][r2];
        }
    if (l15 == 0) {
#pragma unroll
        for (int r2 = 0; r2 < 4; ++r2) {
            const int qq = q0 + (w << 4) + (lg << 2) + r2;
            const int idx = z * (32 * SS) + bh * SS + qq;
            mpart[idx] = m_run[r2];
            lpart[idx] = l_run[r2];
        }
    }
}

// ---------------------------------------------------------------------------
// Combine the 2 kv-split partials -> split o hi/lo planes.
// ---------------------------------------------------------------------------
__global__ __launch_bounds__(256) void attn_combine_kernel(
    const float* __restrict__ opart, const float* __restrict__ mpart,
    const float* __restrict__ lpart, unsigned short* __restrict__ ohi,
    unsigned short* __restrict__ olo)
{
    const int t = blockIdx.x;
    const int tid = threadIdx.x;
    const int b = t >> 10, q = t & 1023;
    const int d0 = tid << 2;
    const int bh = (b << 4) + (d0 >> 6);
    const int mi = bh * SS + q;
    const float m0 = mpart[mi], m1 = mpart[32 * SS + mi];
    const float l0 = lpart[mi], l1 = lpart[32 * SS + mi];
    const float m = fmaxf(m0, m1);
    const float e0 = __expf(m0 - m), e1 = __expf(m1 - m);
    const float inv = 1.0f / (l0 * e0 + l1 * e1);
    const float4 a = *(const float4*)(opart + (size_t)t * DD + d0);
    const float4 c = *(const float4*)(opart + (size_t)(TT + t) * DD + d0);
    const float vv[4] = { (a.x * e0 + c.x * e1) * inv, (a.y * e0 + c.y * e1) * inv,
                          (a.z * e0 + c.z * e1) * inv, (a.w * e0 + c.w * e1) * inv };
    ush4 hh, ll;
#pragma unroll
    for (int j = 0; j < 4; ++j) {
        const unsigned short hb = f2bf(vv[j]);
        hh[j] = hb;
        ll[j] = f2bf(vv[j] - bf2f(hb));
    }
    *(ush4*)(ohi + (size_t)t * DD + d0) = hh;
    *(ush4*)(olo + (size_t)t * DD + d0) = ll;
}

// ---------------------------------------------------------------------------
// LayerNorm per row; writes fp32 (+ optional bf16 copy).
// ---------------------------------------------------------------------------
__global__ __launch_bounds__(256) void ln_kernel(
    const float* __restrict__ in, const float* __restrict__ gamma,
    const float* __restrict__ beta, float* __restrict__ outf,
    unsigned short* __restrict__ outb)
{
    const int t = blockIdx.x;
    const int tid = threadIdx.x;
    __shared__ float red[8];
    const float4 v = ((const float4*)(in + (size_t)t * DD))[tid];
    float s = v.x + v.y + v.z + v.w;
    s = wave_sum(s);
    const int wid = tid >> 6, lane = tid & 63;
    if (lane == 0) red[wid] = s;
    __syncthreads();
    const float mu = (red[0] + red[1] + red[2] + red[3]) * (1.0f / DD);
    const float d0 = v.x - mu, d1 = v.y - mu, d2 = v.z - mu, d3 = v.w - mu;
    float q = d0 * d0 + d1 * d1 + d2 * d2 + d3 * d3;
    q = wave_sum(q);
    if (lane == 0) red[4 + wid] = q;
    __syncthreads();
    const float var = (red[4] + red[5] + red[6] + red[7]) * (1.0f / DD);
    const float rstd = 1.0f / sqrtf(var + 1e-5f);
    const float4 g4 = ((const float4*)gamma)[tid];
    const float4 b4 = ((const float4*)beta)[tid];
    const float o0 = d0 * rstd * g4.x + b4.x;
    const float o1 = d1 * rstd * g4.y + b4.y;
    const float o2 = d2 * rstd * g4.z + b4.z;
    const float o3 = d3 * rstd * g4.w + b4.w;
    float4 ov = {o0, o1, o2, o3};
    ((float4*)(outf + (size_t)t * DD))[tid] = ov;
    if (outb) {
        ush4 wv = { f2bf(o0), f2bf(o1), f2bf(o2), f2bf(o3) };
        *(ush4*)(outb + (size_t)t * DD + (tid << 2)) = wv;
    }
}

// ---------------------------------------------------------------------------
// Hierarchical top-1 routing. One wave per token (fp32, exact-order reductions).
// ---------------------------------------------------------------------------
__global__ __launch_bounds__(256) void route_kernel(
    const float* __restrict__ x1, const float* __restrict__ wg,
    const float* __restrict__ bg, const float* __restrict__ we,
    const float* __restrict__ be, int* __restrict__ eid,
    float* __restrict__ gate, int* __restrict__ counts)
{
    const int lane = threadIdx.x & 63;
    const int t = (blockIdx.x << 2) + (threadIdx.x >> 6);
    const float* row = x1 + (size_t)t * DD;
    float zg[NG] = {};
    float ze[NG][EPG] = {};
#pragma unroll
    for (int jj = 0; jj < 16; ++jj) {
        const int c = (lane << 4) + jj;
        const float xv = row[c];
#pragma unroll
        for (int g = 0; g < NG; ++g) {
            zg[g] = fmaf(xv, wg[c * NG + g], zg[g]);
#pragma unroll
            for (int e2 = 0; e2 < EPG; ++e2)
                ze[g][e2] = fmaf(xv, we[(g * DD + c) * EPG + e2], ze[g][e2]);
        }
    }
#pragma unroll
    for (int off = 1; off < 64; off <<= 1) {
#pragma unroll
        for (int g = 0; g < NG; ++g) {
            zg[g] += __shfl_xor(zg[g], off);
#pragma unroll
            for (int e2 = 0; e2 < EPG; ++e2) ze[g][e2] += __shfl_xor(ze[g][e2], off);
        }
    }
    if (lane == 0) {
        float z[NG];
#pragma unroll
        for (int g = 0; g < NG; ++g) z[g] = zg[g] + bg[g];
        int gi = 0; float zb = z[0];
#pragma unroll
        for (int g = 1; g < NG; ++g) if (z[g] > zb) { zb = z[g]; gi = g; }
        float se = 0.f;
#pragma unroll
        for (int g = 0; g < NG; ++g) se += __expf(z[g] - zb);
        const float gprob = 1.0f / se;
        float e0 = 0.f, e1 = 0.f;
#pragma unroll
        for (int g = 0; g < NG; ++g) {
            if (g == gi) { e0 = ze[g][0] + be[g * EPG + 0]; e1 = ze[g][1] + be[g * EPG + 1]; }
        }
        const int ei = (e1 > e0) ? 1 : 0;
        const float ehi = ei ? e1 : e0, elo = ei ? e0 : e1;
        const float eprob = 1.0f / (1.0f + __expf(elo - ehi));
        eid[t] = gi * EPG + ei;
        gate[t] = gprob * eprob;
        atomicAdd(&counts[gi * EPG + ei], 1);
    }
}

__global__ void zero_counts_kernel(int* __restrict__ counts) {
    if (threadIdx.x < NE) counts[threadIdx.x] = 0;
}

__global__ void offsets_kernel(const int* __restrict__ counts, int* __restrict__ offs,
                               int* __restrict__ cursor) {
    if (threadIdx.x == 0) {
        int run = 0;
        for (int e = 0; e < NE; ++e) { offs[e] = run; cursor[e] = run; run += counts[e]; }
        offs[NE] = run;
    }
}

__global__ __launch_bounds__(256) void scatter_kernel(const int* __restrict__ eid,
                                                      int* __restrict__ cursor,
                                                      int* __restrict__ perm) {
    const int t = blockIdx.x * 256 + threadIdx.x;
    const int slot = atomicAdd(&cursor[eid[t]], 1);
    perm[slot] = t;
}

// ---------------------------------------------------------------------------
// fp32 [batch][R][C] -> bf16 [batch][C][R] (LDS-tiled transpose + convert)
// ---------------------------------------------------------------------------
__global__ __launch_bounds__(256) void transpose_bf16_kernel(
    const float* __restrict__ in, unsigned short* __restrict__ out, int R, int C)
{
    __shared__ float tile[32][33];
    const int c0 = blockIdx.x << 5, r0 = blockIdx.y << 5;
    const size_t bo = (size_t)blockIdx.z * R * C;
    const int tc = threadIdx.x & 31, tr8 = threadIdx.x >> 5;
#pragma unroll
    for (int p = 0; p < 4; ++p) {
        const int rr = tr8 + (p << 3);
        tile[rr][tc] = in[bo + (size_t)(r0 + rr) * C + c0 + tc];
    }
    __syncthreads();
#pragma unroll
    for (int p = 0; p < 4; ++p) {
        const int rr = tr8 + (p << 3);
        out[bo + (size_t)(c0 + rr) * R + r0 + tc] = f2bf(tile[tc][rr]);
    }
}

// ---------------------------------------------------------------------------
// MoE expert GEMM 1: h[slot][F] = relu(x1b[perm[slot]] . w1t[e]^T + b1[e])
// ---------------------------------------------------------------------------
__global__ __launch_bounds__(256) void moe_gemm1_kernel(
    const unsigned short* __restrict__ x1b, const unsigned short* __restrict__ w1t,
    const float* __restrict__ b1, const int* __restrict__ offs,
    const int* __restrict__ perm, unsigned short* __restrict__ hbuf)
{
    const int e = blockIdx.y >> 5, mt = blockIdx.y & 31;
    const int row0 = offs[e] + (mt << 6);
    const int rend = offs[e + 1];
    if (row0 >= rend) return;
    const int valid = (rend - row0 < 64) ? (rend - row0) : 64;
    const int n0 = blockIdx.x << 6;
    __shared__ unsigned short As[64][72];
    __shared__ unsigned short Bs[64][72];
    const int lane = threadIdx.x & 63, wid = threadIdx.x >> 6;
    const int l15 = lane & 15, lg = lane >> 4;
    f32x4 acc0 = {0.f, 0.f, 0.f, 0.f}, acc1 = acc0, acc2 = acc0, acc3 = acc0;
    const unsigned short* Bbase = w1t + (size_t)e * FF * DD + (size_t)n0 * DD;
    for (int k0 = 0; k0 < DD; k0 += 64) {
#pragma unroll
        for (int rep = 0; rep < 2; ++rep) {
            const int idx = threadIdx.x + (rep << 8);
            const int rr = idx >> 3, c8 = (idx & 7) << 3;
            bf16x8 av = {0, 0, 0, 0, 0, 0, 0, 0};
            if (rr < valid) {
                const int tk = perm[row0 + rr];
                av = *(const bf16x8*)(x1b + (size_t)tk * DD + k0 + c8);
            }
            *(bf16x8*)&As[rr][c8] = av;
            const bf16x8 bv = *(const bf16x8*)(Bbase + (size_t)rr * DD + k0 + c8);
            *(bf16x8*)&Bs[rr][c8] = bv;
        }
        __syncthreads();
#pragma unroll
        for (int ks = 0; ks < 2; ++ks) {
            const int kc = (ks << 5) + (lg << 3);
            const bf16x8 a  = *(const bf16x8*)&As[(wid << 4) + l15][kc];
            const bf16x8 f0 = *(const bf16x8*)&Bs[ 0 + l15][kc];
            const bf16x8 f1 = *(const bf16x8*)&Bs[16 + l15][kc];
            const bf16x8 f2 = *(const bf16x8*)&Bs[32 + l15][kc];
            const bf16x8 f3 = *(const bf16x8*)&Bs[48 + l15][kc];
            acc0 = __builtin_amdgcn_mfma_f32_16x16x32_bf16(a, f0, acc0, 0, 0, 0);
            acc1 = __builtin_amdgcn_mfma_f32_16x16x32_bf16(a, f1, acc1, 0, 0, 0);
            acc2 = __builtin_amdgcn_mfma_f32_16x16x32_bf16(a, f2, acc2, 0, 0, 0);
            acc3 = __builtin_amdgcn_mfma_f32_16x16x32_bf16(a, f3, acc3, 0, 0, 0);
        }
        __syncthreads();
    }
    const float* bias = b1 + e * FF + n0;
    const int mbase = (wid << 4) + (lg << 2);
#pragma unroll
    for (int nt = 0; nt < 4; ++nt) {
        const f32x4 ac = (nt == 0) ? acc0 : (nt == 1) ? acc1 : (nt == 2) ? acc2 : acc3;
        const int n = (nt << 4) + l15;
#pragma unroll
        for (int r2 = 0; r2 < 4; ++r2) {
            const int m = mbase + r2;
            if (m < valid) {
                float v = ac[r2] + bias[n];
                v = fmaxf(v, 0.f);
                hbuf[(size_t)(row0 + m) * FF + n0 + n] = f2bf(v);
            }
        }
    }
}

// ---------------------------------------------------------------------------
// MoE expert GEMM 2: res2[tk] = x1[tk] + gate[tk]*(h[slot] . w2t[e]^T + b2[e])
// ---------------------------------------------------------------------------
__global__ __launch_bounds__(256) void moe_gemm2_kernel(
    const unsigned short* __restrict__ hbuf, const unsigned short* __restrict__ w2t,
    const float* __restrict__ b2, const int* __restrict__ offs,
    const int* __restrict__ perm, const float* __restrict__ gate,
    const float* __restrict__ x1, float* __restrict__ res2)
{
    const int e = blockIdx.y >> 5, mt = blockIdx.y & 31;
    const int row0 = offs[e] + (mt << 6);
    const int rend = offs[e + 1];
    if (row0 >= rend) return;
    const int valid = (rend - row0 < 64) ? (rend - row0) : 64;
    const int n0 = blockIdx.x << 6;
    __shared__ unsigned short As[64][72];
    __shared__ unsigned short Bs[64][72];
    const int lane = threadIdx.x & 63, wid = threadIdx.x >> 6;
    const int l15 = lane & 15, lg = lane >> 4;
    f32x4 acc0 = {0.f, 0.f, 0.f, 0.f}, acc1 = acc0, acc2 = acc0, acc3 = acc0;
    const unsigned short* Bbase = w2t + (size_t)e * DD * FF + (size_t)n0 * FF;
    for (int k0 = 0; k0 < FF; k0 += 64) {
#pragma unroll
        for (int rep = 0; rep < 2; ++rep) {
            const int idx = threadIdx.x + (rep << 8);
            const int rr = idx >> 3, c8 = (idx & 7) << 3;
            bf16x8 av = {0, 0, 0, 0, 0, 0, 0, 0};
            if (rr < valid) av = *(const bf16x8*)(hbuf + (size_t)(row0 + rr) * FF + k0 + c8);
            *(bf16x8*)&As[rr][c8] = av;
            const bf16x8 bv = *(const bf16x8*)(Bbase + (size_t)rr * FF + k0 + c8);
            *(bf16x8*)&Bs[rr][c8] = bv;
        }
        __syncthreads();
#pragma unroll
        for (int ks = 0; ks < 2; ++ks) {
            const int kc = (ks << 5) + (lg << 3);
            const bf16x8 a  = *(const bf16x8*)&As[(wid << 4) + l15][kc];
            const bf16x8 f0 = *(const bf16x8*)&Bs[ 0 + l15][kc];
            const bf16x8 f1 = *(const bf16x8*)&Bs[16 + l15][kc];
            const bf16x8 f2 = *(const bf16x8*)&Bs[32 + l15][kc];
            const bf16x8 f3 = *(const bf16x8*)&Bs[48 + l15][kc];
            acc0 = __builtin_amdgcn_mfma_f32_16x16x32_bf16(a, f0, acc0, 0, 0, 0);
            acc1 = __builtin_amdgcn_mfma_f32_16x16x32_bf16(a, f1, acc1, 0, 0, 0);
            acc2 = __builtin_amdgcn_mfma_f32_16x16x32_bf16(a, f2, acc2, 0, 0, 0);
            acc3 = __builtin_amdgcn_mfma_f32_16x16x32_bf16(a, f3, acc3, 0, 0, 0);
        }
        __syncthreads();
    }
    const int mbase = (wid << 4) + (lg << 2);
#pragma unroll
    for (int nt = 0; nt < 4; ++nt) {
        const f32x4 ac = (nt == 0) ? acc0 : (nt == 1) ? acc1 : (nt == 2) ? acc2 : acc3;
        const int nl = (nt << 4) + l15;
#pragma unroll
        for (int r2 = 0; r2 < 4; ++r2) {
            const int m = mbase + r2;
            if (m < valid) {
                const int tk = perm[row0 + m];
                const float v = ac[r2] + b2[e * DD + n0 + nl];
                const size_t oi = (size_t)tk * DD + n0 + nl;
                res2[oi] = x1[oi] + gate[tk] * v;
            }
        }
    }
}

// ---------------------------------------------------------------------------
extern "C" void kernel_launch(void* const* d_in, const int* in_sizes, int n_in,
                              void* d_out, int out_size, void* d_ws, size_t ws_size,
                              hipStream_t stream)
{
    (void)in_sizes; (void)n_in; (void)out_size; (void)ws_size;
    const float* x   = (const float*)d_in[0];
    const float* wi  = (const float*)d_in[1];
    const float* bi  = (const float*)d_in[2];
    const float* wo  = (const float*)d_in[3];
    const float* bo  = (const float*)d_in[4];
    const float* g1  = (const float*)d_in[5];
    const float* be1 = (const float*)d_in[6];
    const float* g2  = (const float*)d_in[7];
    const float* be2 = (const float*)d_in[8];
    const float* wgr = (const float*)d_in[9];
    const float* bgr = (const float*)d_in[10];
    const float* wex = (const float*)d_in[11];
    const float* bex = (const float*)d_in[12];
    const float* w1  = (const float*)d_in[13];
    const float* b1  = (const float*)d_in[14];
    const float* w2  = (const float*)d_in[15];
    const float* b2  = (const float*)d_in[16];
    float* out = (float*)d_out;

    char* ws = (char*)d_ws;
    // Workspace map (regions reused across phases; total ~121.7 MB):
    unsigned short* qkvh  = (unsigned short*)(ws + 0);         // 12 MB [t][3072]
    unsigned short* qkvl  = (unsigned short*)(ws + 12582912);  // 12 MB
    unsigned short* hbuf  = (unsigned short*)(ws + 0);         // 8 MB (post-attn)
    float* res2           = (float*)(ws + 8388608);            // 8 MB (post-attn)
    unsigned short* vth   = (unsigned short*)(ws + 25165824);  // 4 MB [bh][64][1024]
    unsigned short* vtl   = (unsigned short*)(ws + 29360128);  // 4 MB
    float* res1           = (float*)(ws + 33554432);           // 8 MB
    float* x1             = (float*)(ws + 41943040);           // 8 MB
    unsigned short* x1b   = (unsigned short*)(ws + 50331648);  // 4 MB
    unsigned short* w1t   = (unsigned short*)(ws + 54525952);  // 32 MB
    unsigned short* w2t   = (unsigned short*)(ws + 88080384);  // 32 MB
    char* misc = ws + 121634816;
    int*   eid    = (int*)(misc);
    float* gate   = (float*)(misc + 8192);
    int*   perm   = (int*)(misc + 16384);
    int*   counts = (int*)(misc + 24576);
    int*   offs   = (int*)(misc + 24640);
    int*   cursor = (int*)(misc + 24704);

    // Aliased split-plane buffers (dead before their host region is written):
    unsigned short* xs_hi = (unsigned short*)(ws + 33554432);            // res1 region
    unsigned short* xs_lo = (unsigned short*)(ws + 33554432 + 4194304);
    unsigned short* wi_hi = (unsigned short*)(ws + 54525952);            // w1t region
    unsigned short* wi_lo = (unsigned short*)(ws + 54525952 + 6291456);
    unsigned short* o_hi  = (unsigned short*)(ws + 41943040);            // x1 region
    unsigned short* o_lo  = (unsigned short*)(ws + 41943040 + 4194304);
    unsigned short* wo_hi = (unsigned short*)(ws + 88080384);            // w2t region
    unsigned short* wo_lo = (unsigned short*)(ws + 88080384 + 2097152);

    // Attention partials live in the w1t region (dead between QKV gemm and the
    // expert-weight transposes): O' 16 MB + m/l 512 KB.
    float* opart = (float*)(ws + 54525952);
    float* mpart = (float*)(ws + 54525952 + 16777216);
    float* lpart = (float*)(ws + 54525952 + 17039360);

    // --- split x and in_proj_w; QKV = x @ wi^T + bi -> split planes, Q pre-scaled 1/8
    split_bf16_kernel<<<dim3((TT * DD / 4 + 255) / 256), dim3(256), 0, stream>>>(x, xs_hi, xs_lo, TT * DD / 4);
    split_bf16_kernel<<<dim3((3 * DD * DD / 4 + 255) / 256), dim3(256), 0, stream>>>(wi, wi_hi, wi_lo, 3 * DD * DD / 4);
    gemm_split_kernel<<<dim3(3 * DD / 128, TT / 128), dim3(256), 0, stream>>>(
        xs_hi, xs_lo, wi_hi, wi_lo, bi, (const float*)nullptr,
        (float*)nullptr, qkvh, qkvl, DD, TT, 3 * DD, DD);

    // --- V^T planes for the PV MFMA B-operand
    vtrans_kernel<<<dim3(SS / 64, 2 * NHD), dim3(256), 0, stream>>>(qkvh, vth);
    vtrans_kernel<<<dim3(SS / 64, 2 * NHD), dim3(256), 0, stream>>>(qkvl, vtl);

    // --- split-precision MFMA flash attention (kv-split x2) + combine
    attn_mfma_kernel<<<dim3(SS / 64, 2 * NHD, 2), dim3(256), 0, stream>>>(
        qkvh, qkvl, vth, vtl, opart, mpart, lpart);
    attn_combine_kernel<<<dim3(TT), dim3(256), 0, stream>>>(opart, mpart, lpart, o_hi, o_lo);

    // --- split out_proj_w; res1 = x + o @ wo^T + bo (fp32 out)
    split_bf16_kernel<<<dim3((DD * DD / 4 + 255) / 256), dim3(256), 0, stream>>>(wo, wo_hi, wo_lo, DD * DD / 4);
    gemm_split_kernel<<<dim3(DD / 128, TT / 128), dim3(256), 0, stream>>>(
        o_hi, o_lo, wo_hi, wo_lo, bo, x,
        res1, (unsigned short*)nullptr, (unsigned short*)nullptr, 0, TT, DD, DD);

    // --- LN1 -> x1 (fp32) + x1b (bf16)   (overwrites o_hi/o_lo: now dead)
    ln_kernel<<<dim3(TT), dim3(256), 0, stream>>>(res1, g1, be1, x1, x1b);

    // --- routing
    zero_counts_kernel<<<dim3(1), dim3(64), 0, stream>>>(counts);
    route_kernel<<<dim3(TT / 4), dim3(256), 0, stream>>>(x1, wgr, bgr, wex, bex, eid, gate, counts);
    offsets_kernel<<<dim3(1), dim3(64), 0, stream>>>(counts, offs, cursor);
    scatter_kernel<<<dim3(TT / 256), dim3(256), 0, stream>>>(eid, cursor, perm);

    // --- expert weights -> bf16 [N][K] (overwrites attn partials: now dead)
    transpose_bf16_kernel<<<dim3(FF / 32, DD / 32, NE), dim3(256), 0, stream>>>(w1, w1t, DD, FF);
    transpose_bf16_kernel<<<dim3(DD / 32, FF / 32, NE), dim3(256), 0, stream>>>(w2, w2t, FF, DD);

    // --- sparse expert FFN (bf16 MFMA)
    moe_gemm1_kernel<<<dim3(FF / 64, NE * 32), dim3(256), 0, stream>>>(x1b, w1t, b1, offs, perm, hbuf);
    moe_gemm2_kernel<<<dim3(DD / 64, NE * 32), dim3(256), 0, stream>>>(hbuf, w2t, b2, offs, perm, gate, x1, res2);

    // --- LN2 -> final output (fp32)
    ln_kernel<<<dim3(TT), dim3(256), 0, stream>>>(res2, g2, be2, out, (unsigned short*)nullptr);
}

// Round 5
// 336.648 us; speedup vs baseline: 1.0882x; 1.0882x over previous
//
#include <hip/hip_runtime.h>
#include <hip/hip_bf16.h>

// Problem constants (B=2, S=1024, D=1024, F=2048, H=16, hd=64, G=4, Epg=2, E=8)
#define TT 2048
#define DD 1024
#define FF 2048
#define SS 1024
#define NHD 16
#define HDD 64
#define NG 4
#define EPG 2
#define NE 8

// 0.125 (1/sqrt(hd)) * log2(e): puts QK^T scores in exp2 domain.
#define QSC 0.18033688011112042f

typedef __attribute__((ext_vector_type(8))) short bf16x8;
typedef __attribute__((ext_vector_type(4))) float f32x4;
typedef __attribute__((ext_vector_type(4))) unsigned short ush4;

__device__ __forceinline__ unsigned short f2bf(float x) {
    unsigned int u = __float_as_uint(x);
    u = (u + 0x7fffu + ((u >> 16) & 1u)) >> 16;
    return (unsigned short)u;
}
__device__ __forceinline__ float bf2f(unsigned short h) {
    return __uint_as_float((unsigned int)h << 16);
}

__device__ __forceinline__ float wave_sum(float s) {
#pragma unroll
    for (int off = 32; off > 0; off >>= 1) s += __shfl_xor(s, off);
    return s;
}

// async global -> LDS, 16B per lane; lds dest = wave-uniform base + lane*16
__device__ __forceinline__ void gl16(const void* g, void* l) {
    auto gp = reinterpret_cast<const unsigned int __attribute__((address_space(1)))*>(
        (unsigned long long)g);
    auto lp = reinterpret_cast<unsigned int __attribute__((address_space(3)))*>(
        (unsigned int)(unsigned long long)l);
    __builtin_amdgcn_global_load_lds(gp, lp, 16, 0, 0);
}

// ---------------------------------------------------------------------------
// fp32 -> bf16 hi/lo split planes
// ---------------------------------------------------------------------------
__global__ __launch_bounds__(256) void split_bf16_kernel(
    const float* __restrict__ in, unsigned short* __restrict__ hi,
    unsigned short* __restrict__ lo, int n4)
{
    const int i = blockIdx.x * 256 + threadIdx.x;
    if (i >= n4) return;
    const float4 v = ((const float4*)in)[i];
    float vv[4] = {v.x, v.y, v.z, v.w};
    ush4 h, l;
#pragma unroll
    for (int j = 0; j < 4; ++j) {
        const unsigned short hb = f2bf(vv[j]);
        ((unsigned short*)&h)[j] = hb;
        ((unsigned short*)&l)[j] = f2bf(vv[j] - bf2f(hb));
    }
    ((ush4*)hi)[i] = h;
    ((ush4*)lo)[i] = l;
}

// ---------------------------------------------------------------------------
// Split-precision GEMM: C[M,N] = A[M,K] . B[N,K]^T + bias (+resid).
// 3-term MFMA: AhBh + AhBl + AlBh. 128x128 tile, BK=64, 4 waves.
// Staging via global_load_lds with inverse-swizzled source (linear LDS dest).
// ---------------------------------------------------------------------------
__global__ __launch_bounds__(256, 2) void gemm_split_kernel(
    const unsigned short* __restrict__ Ah, const unsigned short* __restrict__ Al,
    const unsigned short* __restrict__ Bh, const unsigned short* __restrict__ Bl,
    const float* __restrict__ bias, const float* __restrict__ resid,
    float* __restrict__ C, unsigned short* __restrict__ Chi,
    unsigned short* __restrict__ Clo, int qscale_n, int M, int N, int K)
{
    __shared__ unsigned short sAh[128 * 64];
    __shared__ unsigned short sAl[128 * 64];
    __shared__ unsigned short sBh[128 * 64];
    __shared__ unsigned short sBl[128 * 64];
    const int tid = threadIdx.x;
    const int lane = tid & 63, wid = tid >> 6;
    const int l15 = lane & 15, lg = lane >> 4;
    const int wr = wid >> 1, wc = wid & 1;
    const int n0 = blockIdx.x << 7, m0 = blockIdx.y << 7;

    f32x4 acc[4][4];
#pragma unroll
    for (int mi = 0; mi < 4; ++mi)
#pragma unroll
        for (int ni = 0; ni < 4; ++ni) acc[mi][ni] = (f32x4){0.f, 0.f, 0.f, 0.f};

    for (int k0 = 0; k0 < K; k0 += 64) {
#pragma unroll
        for (int r = 0; r < 4; ++r) {
            const int s = (r << 8) + tid;           // 16B slot, [128 rows][8 slots]
            const int row = s >> 3;
            const int cs = (s & 7) ^ (row & 7);     // inverse swizzle on source
            const int lb = (s & ~63) << 3;          // wave-uniform LDS base (shorts)
            const size_t ga = (size_t)(m0 + row) * K + k0 + (cs << 3);
            const size_t gb = (size_t)(n0 + row) * K + k0 + (cs << 3);
            gl16(Ah + ga, &sAh[lb]);
            gl16(Al + ga, &sAl[lb]);
            gl16(Bh + gb, &sBh[lb]);
            gl16(Bl + gb, &sBl[lb]);
        }
        __syncthreads();
#pragma unroll
        for (int ks = 0; ks < 2; ++ks) {
            bf16x8 ah[4], al[4], bh[4], bl[4];
            const int ac = (ks << 2) + lg;
#pragma unroll
            for (int i = 0; i < 4; ++i) {
                const int ar = (wr << 6) + (i << 4) + l15;
                const int pa = ((ar << 3) | (ac ^ (ar & 7))) << 3;
                ah[i] = *(const bf16x8*)&sAh[pa];
                al[i] = *(const bf16x8*)&sAl[pa];
                const int br = (wc << 6) + (i << 4) + l15;
                const int pb = ((br << 3) | (ac ^ (br & 7))) << 3;
                bh[i] = *(const bf16x8*)&sBh[pb];
                bl[i] = *(const bf16x8*)&sBl[pb];
            }
#pragma unroll
            for (int mi = 0; mi < 4; ++mi)
#pragma unroll
                for (int ni = 0; ni < 4; ++ni) {
                    acc[mi][ni] = __builtin_amdgcn_mfma_f32_16x16x32_bf16(ah[mi], bh[ni], acc[mi][ni], 0, 0, 0);
                    acc[mi][ni] = __builtin_amdgcn_mfma_f32_16x16x32_bf16(ah[mi], bl[ni], acc[mi][ni], 0, 0, 0);
                    acc[mi][ni] = __builtin_amdgcn_mfma_f32_16x16x32_bf16(al[mi], bh[ni], acc[mi][ni], 0, 0, 0);
                }
        }
        __syncthreads();
    }
#pragma unroll
    for (int mi = 0; mi < 4; ++mi)
#pragma unroll
        for (int ni = 0; ni < 4; ++ni)
#pragma unroll
            for (int r2 = 0; r2 < 4; ++r2) {
                const int m = m0 + (wr << 6) + (mi << 4) + (lg << 2) + r2;
                const int n = n0 + (wc << 6) + (ni << 4) + l15;
                float v = acc[mi][ni][r2] + bias[n];
                if (resid) v += resid[(size_t)m * N + n];
                const size_t idx = (size_t)m * N + n;
                if (Chi) {
                    if (n < qscale_n) v *= QSC;
                    const unsigned short hb = f2bf(v);
                    Chi[idx] = hb;
                    Clo[idx] = f2bf(v - bf2f(hb));
                } else {
                    C[idx] = v;
                }
            }
}

// ---------------------------------------------------------------------------
// V^T extraction: bf16 plane [t][3072] -> [bh][64 d][1024 s] transposed plane.
// ---------------------------------------------------------------------------
__global__ __launch_bounds__(256) void vtrans_kernel(
    const unsigned short* __restrict__ src, unsigned short* __restrict__ dst)
{
    __shared__ unsigned short tile[64][65];
    const int bh = blockIdx.y, b = bh >> 4, h = bh & 15;
    const int s0 = blockIdx.x << 6;
    const int tid = threadIdx.x;
#pragma unroll
    for (int r = 0; r < 2; ++r) {
        const int sl = tid + (r << 8);
        const int rr = sl >> 3, c8 = (sl & 7) << 3;
        const bf16x8 v = *(const bf16x8*)(src + (size_t)(b * SS + s0 + rr) * 3072 + 2048 + h * HDD + c8);
#pragma unroll
        for (int j = 0; j < 8; ++j) tile[rr][c8 + j] = ((const unsigned short*)&v)[j];
    }
    __syncthreads();
#pragma unroll
    for (int r = 0; r < 2; ++r) {
        const int sl = tid + (r << 8);
        const int d = sl >> 3, s8 = (sl & 7) << 3;
        bf16x8 o;
#pragma unroll
        for (int j = 0; j < 8; ++j) ((unsigned short*)&o)[j] = tile[s8 + j][d];
        *(bf16x8*)(dst + (size_t)(bh * HDD + d) * SS + s0 + s8) = o;
    }
}

// ---------------------------------------------------------------------------
// Split-precision MFMA flash attention, kv-split x2, Q in registers.
// LDS 32 KB (K + V hi/lo only) -> 5 blocks/CU capacity, grid 4/CU.
// Scores arrive in exp2 domain (QSC folded upstream).
// ---------------------------------------------------------------------------
__global__ __launch_bounds__(256, 4) void attn_mfma_kernel(
    const unsigned short* __restrict__ qh, const unsigned short* __restrict__ ql,
    const unsigned short* __restrict__ vth, const unsigned short* __restrict__ vtl,
    float* __restrict__ opart, float* __restrict__ mpart, float* __restrict__ lpart)
{
    __shared__ unsigned short sKh[4096], sKl[4096];   // K tiles; P[q][kv] after QK
    __shared__ unsigned short sVh[4096], sVl[4096];
    const int bh = blockIdx.y, b = bh >> 4, h = bh & 15;
    const int q0 = blockIdx.x << 6;
    const int z = blockIdx.z;
    const int tid = threadIdx.x, lane = tid & 63, w = tid >> 6;
    const int l15 = lane & 15, lg = lane >> 4;

    // stage Q tile through (currently dead) sK, pull fragments to registers
#pragma unroll
    for (int r = 0; r < 2; ++r) {
        const int s = (r << 8) + tid;
        const int row = s >> 3;
        const int cs = (s & 7) ^ (row & 7);
        const int lb = (s & ~63) << 3;
        const size_t gq = (size_t)(b * SS + q0 + row) * 3072 + h * HDD + (cs << 3);
        gl16(qh + gq, &sKh[lb]);
        gl16(ql + gq, &sKl[lb]);
    }
    __syncthreads();
    bf16x8 qah[2], qal[2];
#pragma unroll
    for (int ks = 0; ks < 2; ++ks) {
        const int ar = (w << 4) + l15;
        const int ac = (ks << 2) + lg;
        const int pa = ((ar << 3) | (ac ^ (ar & 7))) << 3;
        qah[ks] = *(const bf16x8*)&sKh[pa];
        qal[ks] = *(const bf16x8*)&sKl[pa];
    }
    __syncthreads();

    f32x4 accO[4];
#pragma unroll
    for (int nt = 0; nt < 4; ++nt) accO[nt] = (f32x4){0.f, 0.f, 0.f, 0.f};
    float m_run[4], l_run[4];
#pragma unroll
    for (int r2 = 0; r2 < 4; ++r2) { m_run[r2] = -3.0e38f; l_run[r2] = 0.f; }

    const int kvbeg = z << 9;
    for (int kv0 = kvbeg; kv0 < kvbeg + 512; kv0 += 64) {
        // stage K tile + V^T tile (async direct-to-LDS)
#pragma unroll
        for (int r = 0; r < 2; ++r) {
            const int s = (r << 8) + tid;
            const int row = s >> 3;
            const int cs = (s & 7) ^ (row & 7);
            const int lb = (s & ~63) << 3;
            const size_t gk = (size_t)(b * SS + kv0 + row) * 3072 + DD + h * HDD + (cs << 3);
            gl16(qh + gk, &sKh[lb]);
            gl16(ql + gk, &sKl[lb]);
            const size_t gv = (size_t)(bh * HDD + row) * SS + kv0 + (cs << 3);
            gl16(vth + gv, &sVh[lb]);
            gl16(vtl + gv, &sVl[lb]);
        }
        __syncthreads();

        // QK^T: S[q=w*16+lg*4+r2][kv=i*16+l15]  (scores in log2 units)
        f32x4 sacc[4];
#pragma unroll
        for (int i = 0; i < 4; ++i) sacc[i] = (f32x4){0.f, 0.f, 0.f, 0.f};
        __builtin_amdgcn_s_setprio(1);
#pragma unroll
        for (int ks = 0; ks < 2; ++ks) {
            const int ac = (ks << 2) + lg;
#pragma unroll
            for (int i = 0; i < 4; ++i) {
                const int br = (i << 4) + l15;
                const int pb = ((br << 3) | (ac ^ (br & 7))) << 3;
                const bf16x8 kbh = *(const bf16x8*)&sKh[pb];
                const bf16x8 kbl = *(const bf16x8*)&sKl[pb];
                sacc[i] = __builtin_amdgcn_mfma_f32_16x16x32_bf16(qah[ks], kbh, sacc[i], 0, 0, 0);
                sacc[i] = __builtin_amdgcn_mfma_f32_16x16x32_bf16(qah[ks], kbl, sacc[i], 0, 0, 0);
                sacc[i] = __builtin_amdgcn_mfma_f32_16x16x32_bf16(qal[ks], kbh, sacc[i], 0, 0, 0);
            }
        }
        __builtin_amdgcn_s_setprio(0);
        __syncthreads();   // all waves done reading K before P overwrites it

        // online softmax per q-row (exp2 domain), reduce across 16 lanes
#pragma unroll
        for (int r2 = 0; r2 < 4; ++r2) {
            float mx = fmaxf(fmaxf(sacc[0][r2], sacc[1][r2]), fmaxf(sacc[2][r2], sacc[3][r2]));
#pragma unroll
            for (int off = 1; off < 16; off <<= 1) mx = fmaxf(mx, __shfl_xor(mx, off));
            const float mn = fmaxf(m_run[r2], mx);
            const float corr = exp2f(m_run[r2] - mn);
            m_run[r2] = mn;
            float ls = 0.f;
#pragma unroll
            for (int nt = 0; nt < 4; ++nt) {
                const float p = exp2f(sacc[nt][r2] - mn);
                sacc[nt][r2] = p;
                ls += p;
            }
#pragma unroll
            for (int off = 1; off < 16; off <<= 1) ls += __shfl_xor(ls, off);
            l_run[r2] = l_run[r2] * corr + ls;
#pragma unroll
            for (int nt = 0; nt < 4; ++nt) accO[nt][r2] *= corr;
        }

        // store P[q][kv] hi/lo into dead K LDS (wave-private rows, truncating split)
#pragma unroll
        for (int nt = 0; nt < 4; ++nt)
#pragma unroll
            for (int r2 = 0; r2 < 4; ++r2) {
                const int qq = (w << 4) + (lg << 2) + r2;
                const int kv = (nt << 4) + l15;
                const int idx = (qq << 6) + ((((kv >> 3) ^ (qq & 7))) << 3) + (kv & 7);
                const float p = sacc[nt][r2];
                const unsigned short hb = (unsigned short)(__float_as_uint(p) >> 16);
                sKh[idx] = hb;
                sKl[idx] = (unsigned short)(__float_as_uint(p - bf2f(hb)) >> 16);
            }
        // no barrier: each wave reads back only its own 16 q-rows

        // PV: O[q][d=nt*16+l15] += P[q][kv] * V[kv][d]
        __builtin_amdgcn_s_setprio(1);
#pragma unroll
        for (int ks = 0; ks < 2; ++ks) {
            const int qq = (w << 4) + l15;
            const int slot = (ks << 2) + lg;
            const int pidx = (qq << 6) + ((slot ^ (qq & 7)) << 3);
            const bf16x8 pah = *(const bf16x8*)&sKh[pidx];
            const bf16x8 pal = *(const bf16x8*)&sKl[pidx];
            const int ac = (ks << 2) + lg;
#pragma unroll
            for (int nt = 0; nt < 4; ++nt) {
                const int dr = (nt << 4) + l15;
                const int pv = ((dr << 3) | (ac ^ (dr & 7))) << 3;
                const bf16x8 vbh = *(const bf16x8*)&sVh[pv];
                const bf16x8 vbl = *(const bf16x8*)&sVl[pv];
                accO[nt] = __builtin_amdgcn_mfma_f32_16x16x32_bf16(pah, vbh, accO[nt], 0, 0, 0);
                accO[nt] = __builtin_amdgcn_mfma_f32_16x16x32_bf16(pah, vbl, accO[nt], 0, 0, 0);
                accO[nt] = __builtin_amdgcn_mfma_f32_16x16x32_bf16(pal, vbh, accO[nt], 0, 0, 0);
            }
        }
        __builtin_amdgcn_s_setprio(0);
        __syncthreads();   // P/V reads done before next tile's staging
    }

    // epilogue: unnormalized partial O' + per-row (m,l)
#pragma unroll
    for (int nt = 0; nt < 4; ++nt)
#pragma unroll
        for (int r2 = 0; r2 < 4; ++r2) {
            const int qq = q0 + (w << 4) + (lg << 2) + r2;
            const int dd = h * HDD + (nt << 4) + l15;
            opart[((size_t)z * TT + b * SS + qq) * DD + dd] = accO[nt][r2];
        }
    if (l15 == 0) {
#pragma unroll
        for (int r2 = 0; r2 < 4; ++r2) {
            const int qq = q0 + (w << 4) + (lg << 2) + r2;
            const int idx = z * (32 * SS) + bh * SS + qq;
            mpart[idx] = m_run[r2];
            lpart[idx] = l_run[r2];
        }
    }
}

// ---------------------------------------------------------------------------
// Combine the 2 kv-split partials -> split o hi/lo planes (exp2 domain m/l).
// ---------------------------------------------------------------------------
__global__ __launch_bounds__(256) void attn_combine_kernel(
    const float* __restrict__ opart, const float* __restrict__ mpart,
    const float* __restrict__ lpart, unsigned short* __restrict__ ohi,
    unsigned short* __restrict__ olo)
{
    const int t = blockIdx.x;
    const int tid = threadIdx.x;
    const int b = t >> 10, q = t & 1023;
    const int d0 = tid << 2;
    const int bh = (b << 4) + (d0 >> 6);
    const int mi = bh * SS + q;
    const float m0 = mpart[mi], m1 = mpart[32 * SS + mi];
    const float l0 = lpart[mi], l1 = lpart[32 * SS + mi];
    const float m = fmaxf(m0, m1);
    const float e0 = exp2f(m0 - m), e1 = exp2f(m1 - m);
    const float inv = 1.0f / (l0 * e0 + l1 * e1);
    const float4 a = *(const float4*)(opart + (size_t)t * DD + d0);
    const float4 c = *(const float4*)(opart + (size_t)(TT + t) * DD + d0);
    const float vv[4] = { (a.x * e0 + c.x * e1) * inv, (a.y * e0 + c.y * e1) * inv,
                          (a.z * e0 + c.z * e1) * inv, (a.w * e0 + c.w * e1) * inv };
    ush4 hh, ll;
#pragma unroll
    for (int j = 0; j < 4; ++j) {
        const unsigned short hb = f2bf(vv[j]);
        hh[j] = hb;
        ll[j] = f2bf(vv[j] - bf2f(hb));
    }
    *(ush4*)(ohi + (size_t)t * DD + d0) = hh;
    *(ush4*)(olo + (size_t)t * DD + d0) = ll;
}

// ---------------------------------------------------------------------------
// LayerNorm per row (LN2).
// ---------------------------------------------------------------------------
__global__ __launch_bounds__(256) void ln_kernel(
    const float* __restrict__ in, const float* __restrict__ gamma,
    const float* __restrict__ beta, float* __restrict__ outf)
{
    const int t = blockIdx.x;
    const int tid = threadIdx.x;
    __shared__ float red[8];
    const float4 v = ((const float4*)(in + (size_t)t * DD))[tid];
    float s = v.x + v.y + v.z + v.w;
    s = wave_sum(s);
    const int wid = tid >> 6, lane = tid & 63;
    if (lane == 0) red[wid] = s;
    __syncthreads();
    const float mu = (red[0] + red[1] + red[2] + red[3]) * (1.0f / DD);
    const float d0 = v.x - mu, d1 = v.y - mu, d2 = v.z - mu, d3 = v.w - mu;
    float q = d0 * d0 + d1 * d1 + d2 * d2 + d3 * d3;
    q = wave_sum(q);
    if (lane == 0) red[4 + wid] = q;
    __syncthreads();
    const float var = (red[4] + red[5] + red[6] + red[7]) * (1.0f / DD);
    const float rstd = 1.0f / sqrtf(var + 1e-5f);
    const float4 g4 = ((const float4*)gamma)[tid];
    const float4 b4 = ((const float4*)beta)[tid];
    float4 ov = { d0 * rstd * g4.x + b4.x, d1 * rstd * g4.y + b4.y,
                  d2 * rstd * g4.z + b4.z, d3 * rstd * g4.w + b4.w };
    ((float4*)(outf + (size_t)t * DD))[tid] = ov;
}

// ---------------------------------------------------------------------------
// Fused LN1 + hierarchical top-1 routing. One token per block.
// ---------------------------------------------------------------------------
__global__ __launch_bounds__(256) void ln_route_kernel(
    const float* __restrict__ in, const float* __restrict__ gamma,
    const float* __restrict__ beta, float* __restrict__ outf,
    unsigned short* __restrict__ outb,
    const float* __restrict__ wg, const float* __restrict__ bg,
    const float* __restrict__ we, const float* __restrict__ be,
    int* __restrict__ eid, float* __restrict__ gate, int* __restrict__ counts)
{
    const int t = blockIdx.x;
    const int tid = threadIdx.x;
    __shared__ float red[8];
    __shared__ float red2[4][12];
    const float4 v = ((const float4*)(in + (size_t)t * DD))[tid];
    float s = v.x + v.y + v.z + v.w;
    s = wave_sum(s);
    const int wid = tid >> 6, lane = tid & 63;
    if (lane == 0) red[wid] = s;
    __syncthreads();
    const float mu = (red[0] + red[1] + red[2] + red[3]) * (1.0f / DD);
    const float d0 = v.x - mu, d1 = v.y - mu, d2 = v.z - mu, d3 = v.w - mu;
    float q = d0 * d0 + d1 * d1 + d2 * d2 + d3 * d3;
    q = wave_sum(q);
    if (lane == 0) red[4 + wid] = q;
    __syncthreads();
    const float var = (red[4] + red[5] + red[6] + red[7]) * (1.0f / DD);
    const float rstd = 1.0f / sqrtf(var + 1e-5f);
    const float4 g4 = ((const float4*)gamma)[tid];
    const float4 b4 = ((const float4*)beta)[tid];
    const float o0 = d0 * rstd * g4.x + b4.x;
    const float o1 = d1 * rstd * g4.y + b4.y;
    const float o2 = d2 * rstd * g4.z + b4.z;
    const float o3 = d3 * rstd * g4.w + b4.w;
    float4 ov = {o0, o1, o2, o3};
    ((float4*)(outf + (size_t)t * DD))[tid] = ov;
    ush4 wv = { f2bf(o0), f2bf(o1), f2bf(o2), f2bf(o3) };
    *(ush4*)(outb + (size_t)t * DD + (tid << 2)) = wv;

    // routing partials: 4 group + 8 expert logits
    float pz[12];
#pragma unroll
    for (int k = 0; k < 12; ++k) pz[k] = 0.f;
    const float xo[4] = {o0, o1, o2, o3};
#pragma unroll
    for (int j = 0; j < 4; ++j) {
        const int c = (tid << 2) + j;
        const float xv = xo[j];
        const float4 wgv = *(const float4*)(wg + c * NG);
        pz[0] = fmaf(xv, wgv.x, pz[0]);
        pz[1] = fmaf(xv, wgv.y, pz[1]);
        pz[2] = fmaf(xv, wgv.z, pz[2]);
        pz[3] = fmaf(xv, wgv.w, pz[3]);
#pragma unroll
        for (int g = 0; g < NG; ++g) {
            const float2 wev = *(const float2*)(we + ((size_t)g * DD + c) * EPG);
            pz[4 + 2 * g]     = fmaf(xv, wev.x, pz[4 + 2 * g]);
            pz[4 + 2 * g + 1] = fmaf(xv, wev.y, pz[4 + 2 * g + 1]);
        }
    }
#pragma unroll
    for (int k = 0; k < 12; ++k) pz[k] = wave_sum(pz[k]);
    if (lane == 0) {
#pragma unroll
        for (int k = 0; k < 12; ++k) red2[wid][k] = pz[k];
    }
    __syncthreads();
    if (tid == 0) {
        float zs[12];
#pragma unroll
        for (int k = 0; k < 12; ++k)
            zs[k] = red2[0][k] + red2[1][k] + red2[2][k] + red2[3][k];
        float z[NG];
#pragma unroll
        for (int g = 0; g < NG; ++g) z[g] = zs[g] + bg[g];
        int gi = 0; float zb = z[0];
#pragma unroll
        for (int g = 1; g < NG; ++g) if (z[g] > zb) { zb = z[g]; gi = g; }
        float se = 0.f;
#pragma unroll
        for (int g = 0; g < NG; ++g) se += __expf(z[g] - zb);
        const float gprob = 1.0f / se;
        float e0 = 0.f, e1 = 0.f;
#pragma unroll
        for (int g = 0; g < NG; ++g) {
            if (g == gi) {
                e0 = zs[4 + 2 * g] + be[g * EPG + 0];
                e1 = zs[4 + 2 * g + 1] + be[g * EPG + 1];
            }
        }
        const int ei = (e1 > e0) ? 1 : 0;
        const float ehi = ei ? e1 : e0, elo = ei ? e0 : e1;
        const float eprob = 1.0f / (1.0f + __expf(elo - ehi));
        eid[t] = gi * EPG + ei;
        gate[t] = gprob * eprob;
        atomicAdd(&counts[gi * EPG + ei], 1);
    }
}

__global__ void zero_counts_kernel(int* __restrict__ counts) {
    if (threadIdx.x < NE) counts[threadIdx.x] = 0;
}

__global__ void offsets_kernel(const int* __restrict__ counts, int* __restrict__ offs,
                               int* __restrict__ cursor) {
    if (threadIdx.x == 0) {
        int run = 0;
        for (int e = 0; e < NE; ++e) { offs[e] = run; cursor[e] = run; run += counts[e]; }
        offs[NE] = run;
    }
}

__global__ __launch_bounds__(256) void scatter_kernel(const int* __restrict__ eid,
                                                      int* __restrict__ cursor,
                                                      int* __restrict__ perm) {
    const int t = blockIdx.x * 256 + threadIdx.x;
    const int slot = atomicAdd(&cursor[eid[t]], 1);
    perm[slot] = t;
}

// ---------------------------------------------------------------------------
// fp32 [batch][R][C] -> bf16 [batch][C][R] (LDS-tiled transpose + convert)
// ---------------------------------------------------------------------------
__global__ __launch_bounds__(256) void transpose_bf16_kernel(
    const float* __restrict__ in, unsigned short* __restrict__ out, int R, int C)
{
    __shared__ float tile[32][33];
    const int c0 = blockIdx.x << 5, r0 = blockIdx.y << 5;
    const size_t bo = (size_t)blockIdx.z * R * C;
    const int tc = threadIdx.x & 31, tr8 = threadIdx.x >> 5;
#pragma unroll
    for (int p = 0; p < 4; ++p) {
        const int rr = tr8 + (p << 3);
        tile[rr][tc] = in[bo + (size_t)(r0 + rr) * C + c0 + tc];
    }
    __syncthreads();
#pragma unroll
    for (int p = 0; p < 4; ++p) {
        const int rr = tr8 + (p << 3);
        out[bo + (size_t)(c0 + rr) * R + r0 + tc] = f2bf(tile[tc][rr]);
    }
}

// ---------------------------------------------------------------------------
// MoE expert GEMM 1: h[slot][F] = relu(x1b[perm[slot]] . w1t[e]^T + b1[e])
// ---------------------------------------------------------------------------
__global__ __launch_bounds__(256) void moe_gemm1_kernel(
    const unsigned short* __restrict__ x1b, const unsigned short* __restrict__ w1t,
    const float* __restrict__ b1, const int* __restrict__ offs,
    const int* __restrict__ perm, unsigned short* __restrict__ hbuf)
{
    const int e = blockIdx.y >> 5, mt = blockIdx.y & 31;
    const int row0 = offs[e] + (mt << 6);
    const int rend = offs[e + 1];
    if (row0 >= rend) return;
    const int valid = (rend - row0 < 64) ? (rend - row0) : 64;
    const int n0 = blockIdx.x << 6;
    __shared__ unsigned short As[64][72];
    __shared__ unsigned short Bs[64][72];
    const int lane = threadIdx.x & 63, wid = threadIdx.x >> 6;
    const int l15 = lane & 15, lg = lane >> 4;
    f32x4 acc0 = {0.f, 0.f, 0.f, 0.f}, acc1 = acc0, acc2 = acc0, acc3 = acc0;
    const unsigned short* Bbase = w1t + (size_t)e * FF * DD + (size_t)n0 * DD;
    for (int k0 = 0; k0 < DD; k0 += 64) {
#pragma unroll
        for (int rep = 0; rep < 2; ++rep) {
            const int idx = threadIdx.x + (rep << 8);
            const int rr = idx >> 3, c8 = (idx & 7) << 3;
            bf16x8 av = {0, 0, 0, 0, 0, 0, 0, 0};
            if (rr < valid) {
                const int tk = perm[row0 + rr];
                av = *(const bf16x8*)(x1b + (size_t)tk * DD + k0 + c8);
            }
            *(bf16x8*)&As[rr][c8] = av;
            const bf16x8 bv = *(const bf16x8*)(Bbase + (size_t)rr * DD + k0 + c8);
            *(bf16x8*)&Bs[rr][c8] = bv;
        }
        __syncthreads();
#pragma unroll
        for (int ks = 0; ks < 2; ++ks) {
            const int kc = (ks << 5) + (lg << 3);
            const bf16x8 a  = *(const bf16x8*)&As[(wid << 4) + l15][kc];
            const bf16x8 f0 = *(const bf16x8*)&Bs[ 0 + l15][kc];
            const bf16x8 f1 = *(const bf16x8*)&Bs[16 + l15][kc];
            const bf16x8 f2 = *(const bf16x8*)&Bs[32 + l15][kc];
            const bf16x8 f3 = *(const bf16x8*)&Bs[48 + l15][kc];
            acc0 = __builtin_amdgcn_mfma_f32_16x16x32_bf16(a, f0, acc0, 0, 0, 0);
            acc1 = __builtin_amdgcn_mfma_f32_16x16x32_bf16(a, f1, acc1, 0, 0, 0);
            acc2 = __builtin_amdgcn_mfma_f32_16x16x32_bf16(a, f2, acc2, 0, 0, 0);
            acc3 = __builtin_amdgcn_mfma_f32_16x16x32_bf16(a, f3, acc3, 0, 0, 0);
        }
        __syncthreads();
    }
    const float* bias = b1 + e * FF + n0;
    const int mbase = (wid << 4) + (lg << 2);
#pragma unroll
    for (int nt = 0; nt < 4; ++nt) {
        const f32x4 ac = (nt == 0) ? acc0 : (nt == 1) ? acc1 : (nt == 2) ? acc2 : acc3;
        const int n = (nt << 4) + l15;
#pragma unroll
        for (int r2 = 0; r2 < 4; ++r2) {
            const int m = mbase + r2;
            if (m < valid) {
                float v = ac[r2] + bias[n];
                v = fmaxf(v, 0.f);
                hbuf[(size_t)(row0 + m) * FF + n0 + n] = f2bf(v);
            }
        }
    }
}

// ---------------------------------------------------------------------------
// MoE expert GEMM 2: res2[tk] = x1[tk] + gate[tk]*(h[slot] . w2t[e]^T + b2[e])
// ---------------------------------------------------------------------------
__global__ __launch_bounds__(256) void moe_gemm2_kernel(
    const unsigned short* __restrict__ hbuf, const unsigned short* __restrict__ w2t,
    const float* __restrict__ b2, const int* __restrict__ offs,
    const int* __restrict__ perm, const float* __restrict__ gate,
    const float* __restrict__ x1, float* __restrict__ res2)
{
    const int e = blockIdx.y >> 5, mt = blockIdx.y & 31;
    const int row0 = offs[e] + (mt << 6);
    const int rend = offs[e + 1];
    if (row0 >= rend) return;
    const int valid = (rend - row0 < 64) ? (rend - row0) : 64;
    const int n0 = blockIdx.x << 6;
    __shared__ unsigned short As[64][72];
    __shared__ unsigned short Bs[64][72];
    const int lane = threadIdx.x & 63, wid = threadIdx.x >> 6;
    const int l15 = lane & 15, lg = lane >> 4;
    f32x4 acc0 = {0.f, 0.f, 0.f, 0.f}, acc1 = acc0, acc2 = acc0, acc3 = acc0;
    const unsigned short* Bbase = w2t + (size_t)e * DD * FF + (size_t)n0 * FF;
    for (int k0 = 0; k0 < FF; k0 += 64) {
#pragma unroll
        for (int rep = 0; rep < 2; ++rep) {
            const int idx = threadIdx.x + (rep << 8);
            const int rr = idx >> 3, c8 = (idx & 7) << 3;
            bf16x8 av = {0, 0, 0, 0, 0, 0, 0, 0};
            if (rr < valid) av = *(const bf16x8*)(hbuf + (size_t)(row0 + rr) * FF + k0 + c8);
            *(bf16x8*)&As[rr][c8] = av;
            const bf16x8 bv = *(const bf16x8*)(Bbase + (size_t)rr * FF + k0 + c8);
            *(bf16x8*)&Bs[rr][c8] = bv;
        }
        __syncthreads();
#pragma unroll
        for (int ks = 0; ks < 2; ++ks) {
            const int kc = (ks << 5) + (lg << 3);
            const bf16x8 a  = *(const bf16x8*)&As[(wid << 4) + l15][kc];
            const bf16x8 f0 = *(const bf16x8*)&Bs[ 0 + l15][kc];
            const bf16x8 f1 = *(const bf16x8*)&Bs[16 + l15][kc];
            const bf16x8 f2 = *(const bf16x8*)&Bs[32 + l15][kc];
            const bf16x8 f3 = *(const bf16x8*)&Bs[48 + l15][kc];
            acc0 = __builtin_amdgcn_mfma_f32_16x16x32_bf16(a, f0, acc0, 0, 0, 0);
            acc1 = __builtin_amdgcn_mfma_f32_16x16x32_bf16(a, f1, acc1, 0, 0, 0);
            acc2 = __builtin_amdgcn_mfma_f32_16x16x32_bf16(a, f2, acc2, 0, 0, 0);
            acc3 = __builtin_amdgcn_mfma_f32_16x16x32_bf16(a, f3, acc3, 0, 0, 0);
        }
        __syncthreads();
    }
    const int mbase = (wid << 4) + (lg << 2);
#pragma unroll
    for (int nt = 0; nt < 4; ++nt) {
        const f32x4 ac = (nt == 0) ? acc0 : (nt == 1) ? acc1 : (nt == 2) ? acc2 : acc3;
        const int nl = (nt << 4) + l15;
#pragma unroll
        for (int r2 = 0; r2 < 4; ++r2) {
            const int m = mbase + r2;
            if (m < valid) {
                const int tk = perm[row0 + m];
                const float v = ac[r2] + b2[e * DD + n0 + nl];
                const size_t oi = (size_t)tk * DD + n0 + nl;
                res2[oi] = x1[oi] + gate[tk] * v;
            }
        }
    }
}

// ---------------------------------------------------------------------------
extern "C" void kernel_launch(void* const* d_in, const int* in_sizes, int n_in,
                              void* d_out, int out_size, void* d_ws, size_t ws_size,
                              hipStream_t stream)
{
    (void)in_sizes; (void)n_in; (void)out_size; (void)ws_size;
    const float* x   = (const float*)d_in[0];
    const float* wi  = (const float*)d_in[1];
    const float* bi  = (const float*)d_in[2];
    const float* wo  = (const float*)d_in[3];
    const float* bo  = (const float*)d_in[4];
    const float* g1  = (const float*)d_in[5];
    const float* be1 = (const float*)d_in[6];
    const float* g2  = (const float*)d_in[7];
    const float* be2 = (const float*)d_in[8];
    const float* wgr = (const float*)d_in[9];
    const float* bgr = (const float*)d_in[10];
    const float* wex = (const float*)d_in[11];
    const float* bex = (const float*)d_in[12];
    const float* w1  = (const float*)d_in[13];
    const float* b1  = (const float*)d_in[14];
    const float* w2  = (const float*)d_in[15];
    const float* b2  = (const float*)d_in[16];
    float* out = (float*)d_out;

    char* ws = (char*)d_ws;
    unsigned short* qkvh  = (unsigned short*)(ws + 0);         // 12 MB [t][3072]
    unsigned short* qkvl  = (unsigned short*)(ws + 12582912);  // 12 MB
    unsigned short* hbuf  = (unsigned short*)(ws + 0);         // 8 MB (post-attn)
    float* res2           = (float*)(ws + 8388608);            // 8 MB (post-attn)
    unsigned short* vth   = (unsigned short*)(ws + 25165824);  // 4 MB [bh][64][1024]
    unsigned short* vtl   = (unsigned short*)(ws + 29360128);  // 4 MB
    float* res1           = (float*)(ws + 33554432);           // 8 MB
    float* x1             = (float*)(ws + 41943040);           // 8 MB
    unsigned short* x1b   = (unsigned short*)(ws + 50331648);  // 4 MB
    unsigned short* w1t   = (unsigned short*)(ws + 54525952);  // 32 MB
    unsigned short* w2t   = (unsigned short*)(ws + 88080384);  // 32 MB
    char* misc = ws + 121634816;
    int*   eid    = (int*)(misc);
    float* gate   = (float*)(misc + 8192);
    int*   perm   = (int*)(misc + 16384);
    int*   counts = (int*)(misc + 24576);
    int*   offs   = (int*)(misc + 24640);
    int*   cursor = (int*)(misc + 24704);

    // Aliased split-plane buffers (dead before their host region is written):
    unsigned short* xs_hi = (unsigned short*)(ws + 33554432);            // res1 region
    unsigned short* xs_lo = (unsigned short*)(ws + 33554432 + 4194304);
    unsigned short* wi_hi = (unsigned short*)(ws + 54525952);            // w1t region
    unsigned short* wi_lo = (unsigned short*)(ws + 54525952 + 6291456);
    unsigned short* o_hi  = (unsigned short*)(ws + 41943040);            // x1 region
    unsigned short* o_lo  = (unsigned short*)(ws + 41943040 + 4194304);
    unsigned short* wo_hi = (unsigned short*)(ws + 88080384);            // w2t region
    unsigned short* wo_lo = (unsigned short*)(ws + 88080384 + 2097152);

    // Attention partials in the w1t region (dead until expert-weight transposes):
    float* opart = (float*)(ws + 54525952);
    float* mpart = (float*)(ws + 54525952 + 16777216);
    float* lpart = (float*)(ws + 54525952 + 17039360);

    zero_counts_kernel<<<dim3(1), dim3(64), 0, stream>>>(counts);

    // --- split x and in_proj_w; QKV = x @ wi^T + bi -> split planes, Q pre-scaled
    split_bf16_kernel<<<dim3((TT * DD / 4 + 255) / 256), dim3(256), 0, stream>>>(x, xs_hi, xs_lo, TT * DD / 4);
    split_bf16_kernel<<<dim3((3 * DD * DD / 4 + 255) / 256), dim3(256), 0, stream>>>(wi, wi_hi, wi_lo, 3 * DD * DD / 4);
    gemm_split_kernel<<<dim3(3 * DD / 128, TT / 128), dim3(256), 0, stream>>>(
        xs_hi, xs_lo, wi_hi, wi_lo, bi, (const float*)nullptr,
        (float*)nullptr, qkvh, qkvl, DD, TT, 3 * DD, DD);

    // --- V^T planes for the PV MFMA B-operand
    vtrans_kernel<<<dim3(SS / 64, 2 * NHD), dim3(256), 0, stream>>>(qkvh, vth);
    vtrans_kernel<<<dim3(SS / 64, 2 * NHD), dim3(256), 0, stream>>>(qkvl, vtl);

    // --- split-precision MFMA flash attention (kv-split x2) + combine
    attn_mfma_kernel<<<dim3(SS / 64, 2 * NHD, 2), dim3(256), 0, stream>>>(
        qkvh, qkvl, vth, vtl, opart, mpart, lpart);
    attn_combine_kernel<<<dim3(TT), dim3(256), 0, stream>>>(opart, mpart, lpart, o_hi, o_lo);

    // --- split out_proj_w; res1 = x + o @ wo^T + bo (fp32 out)
    split_bf16_kernel<<<dim3((DD * DD / 4 + 255) / 256), dim3(256), 0, stream>>>(wo, wo_hi, wo_lo, DD * DD / 4);
    gemm_split_kernel<<<dim3(DD / 128, TT / 128), dim3(256), 0, stream>>>(
        o_hi, o_lo, wo_hi, wo_lo, bo, x,
        res1, (unsigned short*)nullptr, (unsigned short*)nullptr, 0, TT, DD, DD);

    // --- fused LN1 + routing -> x1, x1b, eid, gate, counts
    ln_route_kernel<<<dim3(TT), dim3(256), 0, stream>>>(
        res1, g1, be1, x1, x1b, wgr, bgr, wex, bex, eid, gate, counts);
    offsets_kernel<<<dim3(1), dim3(64), 0, stream>>>(counts, offs, cursor);
    scatter_kernel<<<dim3(TT / 256), dim3(256), 0, stream>>>(eid, cursor, perm);

    // --- expert weights -> bf16 [N][K] (overwrites attn partials: now dead)
    transpose_bf16_kernel<<<dim3(FF / 32, DD / 32, NE), dim3(256), 0, stream>>>(w1, w1t, DD, FF);
    transpose_bf16_kernel<<<dim3(DD / 32, FF / 32, NE), dim3(256), 0, stream>>>(w2, w2t, FF, DD);

    // --- sparse expert FFN (bf16 MFMA)
    moe_gemm1_kernel<<<dim3(FF / 64, NE * 32), dim3(256), 0, stream>>>(x1b, w1t, b1, offs, perm, hbuf);
    moe_gemm2_kernel<<<dim3(DD / 64, NE * 32), dim3(256), 0, stream>>>(hbuf, w2t, b2, offs, perm, gate, x1, res2);

    // --- LN2 -> final output (fp32)
    ln_kernel<<<dim3(TT), dim3(256), 0, stream>>>(res2, g2, be2, out);
}

// Round 6
// 318.553 us; speedup vs baseline: 1.1500x; 1.0568x over previous
//
#include <hip/hip_runtime.h>
#include <hip/hip_bf16.h>

// Problem constants (B=2, S=1024, D=1024, F=2048, H=16, hd=64, G=4, Epg=2, E=8)
#define TT 2048
#define DD 1024
#define FF 2048
#define SS 1024
#define NHD 16
#define HDD 64
#define NG 4
#define EPG 2
#define NE 8

// 0.125 (1/sqrt(hd)) * log2(e): puts QK^T scores in exp2 domain.
#define QSC 0.18033688011112042f

typedef __attribute__((ext_vector_type(8))) short bf16x8;
typedef __attribute__((ext_vector_type(4))) float f32x4;
typedef __attribute__((ext_vector_type(4))) unsigned short ush4;

__device__ __forceinline__ unsigned short f2bf(float x) {
    unsigned int u = __float_as_uint(x);
    u = (u + 0x7fffu + ((u >> 16) & 1u)) >> 16;
    return (unsigned short)u;
}
__device__ __forceinline__ float bf2f(unsigned short h) {
    return __uint_as_float((unsigned int)h << 16);
}

__device__ __forceinline__ float wave_sum(float s) {
#pragma unroll
    for (int off = 32; off > 0; off >>= 1) s += __shfl_xor(s, off);
    return s;
}

// async global -> LDS, 16B per lane; lds dest = wave-uniform base + lane*16
__device__ __forceinline__ void gl16(const void* g, void* l) {
    auto gp = reinterpret_cast<const unsigned int __attribute__((address_space(1)))*>(
        (unsigned long long)g);
    auto lp = reinterpret_cast<unsigned int __attribute__((address_space(3)))*>(
        (unsigned int)(unsigned long long)l);
    __builtin_amdgcn_global_load_lds(gp, lp, 16, 0, 0);
}

// ---------------------------------------------------------------------------
// fp32 -> bf16 hi/lo split planes
// ---------------------------------------------------------------------------
__global__ __launch_bounds__(256) void split_bf16_kernel(
    const float* __restrict__ in, unsigned short* __restrict__ hi,
    unsigned short* __restrict__ lo, int n4)
{
    const int i = blockIdx.x * 256 + threadIdx.x;
    if (i >= n4) return;
    const float4 v = ((const float4*)in)[i];
    float vv[4] = {v.x, v.y, v.z, v.w};
    ush4 h, l;
#pragma unroll
    for (int j = 0; j < 4; ++j) {
        const unsigned short hb = f2bf(vv[j]);
        ((unsigned short*)&h)[j] = hb;
        ((unsigned short*)&l)[j] = f2bf(vv[j] - bf2f(hb));
    }
    ((ush4*)hi)[i] = h;
    ((ush4*)lo)[i] = l;
}

// ---------------------------------------------------------------------------
// Split-precision GEMM: C[M,N] = A[M,K] . B[N,K]^T + bias (+resid).
// 3-term MFMA: AhBh + AhBl + AlBh. 128(M)x64(N) tile, BK=64, 4 waves each
// owning 32 rows x 64 cols. LDS 48KB -> 3 blocks/CU. Staging via
// global_load_lds with inverse-swizzled source (linear LDS dest).
// ---------------------------------------------------------------------------
__global__ __launch_bounds__(256, 3) void gemm_split_kernel(
    const unsigned short* __restrict__ Ah, const unsigned short* __restrict__ Al,
    const unsigned short* __restrict__ Bh, const unsigned short* __restrict__ Bl,
    const float* __restrict__ bias, const float* __restrict__ resid,
    float* __restrict__ C, unsigned short* __restrict__ Chi,
    unsigned short* __restrict__ Clo, int qscale_n, int M, int N, int K)
{
    __shared__ unsigned short sAh[128 * 64];
    __shared__ unsigned short sAl[128 * 64];
    __shared__ unsigned short sBh[64 * 64];
    __shared__ unsigned short sBl[64 * 64];
    const int tid = threadIdx.x;
    const int lane = tid & 63, wid = tid >> 6;
    const int l15 = lane & 15, lg = lane >> 4;
    const int n0 = blockIdx.x << 6, m0 = blockIdx.y << 7;

    f32x4 acc[2][4];
#pragma unroll
    for (int mi = 0; mi < 2; ++mi)
#pragma unroll
        for (int ni = 0; ni < 4; ++ni) acc[mi][ni] = (f32x4){0.f, 0.f, 0.f, 0.f};

    for (int k0 = 0; k0 < K; k0 += 64) {
        // stage A tile (128 rows x 64 k) hi/lo
#pragma unroll
        for (int r = 0; r < 4; ++r) {
            const int s = (r << 8) + tid;           // 16B slot, [128 rows][8 slots]
            const int row = s >> 3;
            const int cs = (s & 7) ^ (row & 7);     // inverse swizzle on source
            const int lb = (s & ~63) << 3;          // wave-uniform LDS base (shorts)
            const size_t ga = (size_t)(m0 + row) * K + k0 + (cs << 3);
            gl16(Ah + ga, &sAh[lb]);
            gl16(Al + ga, &sAl[lb]);
        }
        // stage B tile (64 rows x 64 k) hi/lo
#pragma unroll
        for (int r = 0; r < 2; ++r) {
            const int s = (r << 8) + tid;
            const int row = s >> 3;
            const int cs = (s & 7) ^ (row & 7);
            const int lb = (s & ~63) << 3;
            const size_t gb = (size_t)(n0 + row) * K + k0 + (cs << 3);
            gl16(Bh + gb, &sBh[lb]);
            gl16(Bl + gb, &sBl[lb]);
        }
        __syncthreads();
#pragma unroll
        for (int ks = 0; ks < 2; ++ks) {
            bf16x8 ah[2], al[2], bh[4], bl[4];
            const int ac = (ks << 2) + lg;
#pragma unroll
            for (int i = 0; i < 2; ++i) {
                const int ar = (wid << 5) + (i << 4) + l15;
                const int pa = ((ar << 3) | (ac ^ (ar & 7))) << 3;
                ah[i] = *(const bf16x8*)&sAh[pa];
                al[i] = *(const bf16x8*)&sAl[pa];
            }
#pragma unroll
            for (int i = 0; i < 4; ++i) {
                const int br = (i << 4) + l15;
                const int pb = ((br << 3) | (ac ^ (br & 7))) << 3;
                bh[i] = *(const bf16x8*)&sBh[pb];
                bl[i] = *(const bf16x8*)&sBl[pb];
            }
#pragma unroll
            for (int mi = 0; mi < 2; ++mi)
#pragma unroll
                for (int ni = 0; ni < 4; ++ni) {
                    acc[mi][ni] = __builtin_amdgcn_mfma_f32_16x16x32_bf16(ah[mi], bh[ni], acc[mi][ni], 0, 0, 0);
                    acc[mi][ni] = __builtin_amdgcn_mfma_f32_16x16x32_bf16(ah[mi], bl[ni], acc[mi][ni], 0, 0, 0);
                    acc[mi][ni] = __builtin_amdgcn_mfma_f32_16x16x32_bf16(al[mi], bh[ni], acc[mi][ni], 0, 0, 0);
                }
        }
        __syncthreads();
    }
#pragma unroll
    for (int mi = 0; mi < 2; ++mi)
#pragma unroll
        for (int ni = 0; ni < 4; ++ni)
#pragma unroll
            for (int r2 = 0; r2 < 4; ++r2) {
                const int m = m0 + (wid << 5) + (mi << 4) + (lg << 2) + r2;
                const int n = n0 + (ni << 4) + l15;
                float v = acc[mi][ni][r2] + bias[n];
                if (resid) v += resid[(size_t)m * N + n];
                const size_t idx = (size_t)m * N + n;
                if (Chi) {
                    if (n < qscale_n) v *= QSC;
                    const unsigned short hb = f2bf(v);
                    Chi[idx] = hb;
                    Clo[idx] = f2bf(v - bf2f(hb));
                } else {
                    C[idx] = v;
                }
            }
}

// ---------------------------------------------------------------------------
// V^T extraction: bf16 plane [t][3072] -> [bh][64 d][1024 s] transposed plane.
// ---------------------------------------------------------------------------
__global__ __launch_bounds__(256) void vtrans_kernel(
    const unsigned short* __restrict__ src, unsigned short* __restrict__ dst)
{
    __shared__ unsigned short tile[64][65];
    const int bh = blockIdx.y, b = bh >> 4, h = bh & 15;
    const int s0 = blockIdx.x << 6;
    const int tid = threadIdx.x;
#pragma unroll
    for (int r = 0; r < 2; ++r) {
        const int sl = tid + (r << 8);
        const int rr = sl >> 3, c8 = (sl & 7) << 3;
        const bf16x8 v = *(const bf16x8*)(src + (size_t)(b * SS + s0 + rr) * 3072 + 2048 + h * HDD + c8);
#pragma unroll
        for (int j = 0; j < 8; ++j) tile[rr][c8 + j] = ((const unsigned short*)&v)[j];
    }
    __syncthreads();
#pragma unroll
    for (int r = 0; r < 2; ++r) {
        const int sl = tid + (r << 8);
        const int d = sl >> 3, s8 = (sl & 7) << 3;
        bf16x8 o;
#pragma unroll
        for (int j = 0; j < 8; ++j) ((unsigned short*)&o)[j] = tile[s8 + j][d];
        *(bf16x8*)(dst + (size_t)(bh * HDD + d) * SS + s0 + s8) = o;
    }
}

// ---------------------------------------------------------------------------
// Split-precision MFMA flash attention, kv-split x2, Q in registers.
// ---------------------------------------------------------------------------
__global__ __launch_bounds__(256, 4) void attn_mfma_kernel(
    const unsigned short* __restrict__ qh, const unsigned short* __restrict__ ql,
    const unsigned short* __restrict__ vth, const unsigned short* __restrict__ vtl,
    float* __restrict__ opart, float* __restrict__ mpart, float* __restrict__ lpart)
{
    __shared__ unsigned short sKh[4096], sKl[4096];   // K tiles; P[q][kv] after QK
    __shared__ unsigned short sVh[4096], sVl[4096];
    const int bh = blockIdx.y, b = bh >> 4, h = bh & 15;
    const int q0 = blockIdx.x << 6;
    const int z = blockIdx.z;
    const int tid = threadIdx.x, lane = tid & 63, w = tid >> 6;
    const int l15 = lane & 15, lg = lane >> 4;

    // stage Q tile through (currently dead) sK, pull fragments to registers
#pragma unroll
    for (int r = 0; r < 2; ++r) {
        const int s = (r << 8) + tid;
        const int row = s >> 3;
        const int cs = (s & 7) ^ (row & 7);
        const int lb = (s & ~63) << 3;
        const size_t gq = (size_t)(b * SS + q0 + row) * 3072 + h * HDD + (cs << 3);
        gl16(qh + gq, &sKh[lb]);
        gl16(ql + gq, &sKl[lb]);
    }
    __syncthreads();
    bf16x8 qah[2], qal[2];
#pragma unroll
    for (int ks = 0; ks < 2; ++ks) {
        const int ar = (w << 4) + l15;
        const int ac = (ks << 2) + lg;
        const int pa = ((ar << 3) | (ac ^ (ar & 7))) << 3;
        qah[ks] = *(const bf16x8*)&sKh[pa];
        qal[ks] = *(const bf16x8*)&sKl[pa];
    }
    __syncthreads();

    f32x4 accO[4];
#pragma unroll
    for (int nt = 0; nt < 4; ++nt) accO[nt] = (f32x4){0.f, 0.f, 0.f, 0.f};
    float m_run[4], l_run[4];
#pragma unroll
    for (int r2 = 0; r2 < 4; ++r2) { m_run[r2] = -3.0e38f; l_run[r2] = 0.f; }

    const int kvbeg = z << 9;
    for (int kv0 = kvbeg; kv0 < kvbeg + 512; kv0 += 64) {
        // stage K tile + V^T tile (async direct-to-LDS)
#pragma unroll
        for (int r = 0; r < 2; ++r) {
            const int s = (r << 8) + tid;
            const int row = s >> 3;
            const int cs = (s & 7) ^ (row & 7);
            const int lb = (s & ~63) << 3;
            const size_t gk = (size_t)(b * SS + kv0 + row) * 3072 + DD + h * HDD + (cs << 3);
            gl16(qh + gk, &sKh[lb]);
            gl16(ql + gk, &sKl[lb]);
            const size_t gv = (size_t)(bh * HDD + row) * SS + kv0 + (cs << 3);
            gl16(vth + gv, &sVh[lb]);
            gl16(vtl + gv, &sVl[lb]);
        }
        __syncthreads();

        // QK^T: S[q=w*16+lg*4+r2][kv=i*16+l15]  (scores in log2 units)
        f32x4 sacc[4];
#pragma unroll
        for (int i = 0; i < 4; ++i) sacc[i] = (f32x4){0.f, 0.f, 0.f, 0.f};
        __builtin_amdgcn_s_setprio(1);
#pragma unroll
        for (int ks = 0; ks < 2; ++ks) {
            const int ac = (ks << 2) + lg;
#pragma unroll
            for (int i = 0; i < 4; ++i) {
                const int br = (i << 4) + l15;
                const int pb = ((br << 3) | (ac ^ (br & 7))) << 3;
                const bf16x8 kbh = *(const bf16x8*)&sKh[pb];
                const bf16x8 kbl = *(const bf16x8*)&sKl[pb];
                sacc[i] = __builtin_amdgcn_mfma_f32_16x16x32_bf16(qah[ks], kbh, sacc[i], 0, 0, 0);
                sacc[i] = __builtin_amdgcn_mfma_f32_16x16x32_bf16(qah[ks], kbl, sacc[i], 0, 0, 0);
                sacc[i] = __builtin_amdgcn_mfma_f32_16x16x32_bf16(qal[ks], kbh, sacc[i], 0, 0, 0);
            }
        }
        __builtin_amdgcn_s_setprio(0);
        __syncthreads();   // all waves done reading K before P overwrites it

        // online softmax per q-row (exp2 domain), reduce across 16 lanes
#pragma unroll
        for (int r2 = 0; r2 < 4; ++r2) {
            float mx = fmaxf(fmaxf(sacc[0][r2], sacc[1][r2]), fmaxf(sacc[2][r2], sacc[3][r2]));
#pragma unroll
            for (int off = 1; off < 16; off <<= 1) mx = fmaxf(mx, __shfl_xor(mx, off));
            const float mn = fmaxf(m_run[r2], mx);
            const float corr = exp2f(m_run[r2] - mn);
            m_run[r2] = mn;
            float ls = 0.f;
#pragma unroll
            for (int nt = 0; nt < 4; ++nt) {
                const float p = exp2f(sacc[nt][r2] - mn);
                sacc[nt][r2] = p;
                ls += p;
            }
#pragma unroll
            for (int off = 1; off < 16; off <<= 1) ls += __shfl_xor(ls, off);
            l_run[r2] = l_run[r2] * corr + ls;
#pragma unroll
            for (int nt = 0; nt < 4; ++nt) accO[nt][r2] *= corr;
        }

        // store P[q][kv] hi/lo into dead K LDS (wave-private rows, truncating split)
#pragma unroll
        for (int nt = 0; nt < 4; ++nt)
#pragma unroll
            for (int r2 = 0; r2 < 4; ++r2) {
                const int qq = (w << 4) + (lg << 2) + r2;
                const int kv = (nt << 4) + l15;
                const int idx = (qq << 6) + ((((kv >> 3) ^ (qq & 7))) << 3) + (kv & 7);
                const float p = sacc[nt][r2];
                const unsigned short hb = (unsigned short)(__float_as_uint(p) >> 16);
                sKh[idx] = hb;
                sKl[idx] = (unsigned short)(__float_as_uint(p - bf2f(hb)) >> 16);
            }
        // no barrier: each wave reads back only its own 16 q-rows

        // PV: O[q][d=nt*16+l15] += P[q][kv] * V[kv][d]
        __builtin_amdgcn_s_setprio(1);
#pragma unroll
        for (int ks = 0; ks < 2; ++ks) {
            const int qq = (w << 4) + l15;
            const int slot = (ks << 2) + lg;
            const int pidx = (qq << 6) + ((slot ^ (qq & 7)) << 3);
            const bf16x8 pah = *(const bf16x8*)&sKh[pidx];
            const bf16x8 pal = *(const bf16x8*)&sKl[pidx];
            const int ac = (ks << 2) + lg;
#pragma unroll
            for (int nt = 0; nt < 4; ++nt) {
                const int dr = (nt << 4) + l15;
                const int pv = ((dr << 3) | (ac ^ (dr & 7))) << 3;
                const bf16x8 vbh = *(const bf16x8*)&sVh[pv];
                const bf16x8 vbl = *(const bf16x8*)&sVl[pv];
                accO[nt] = __builtin_amdgcn_mfma_f32_16x16x32_bf16(pah, vbh, accO[nt], 0, 0, 0);
                accO[nt] = __builtin_amdgcn_mfma_f32_16x16x32_bf16(pah, vbl, accO[nt], 0, 0, 0);
                accO[nt] = __builtin_amdgcn_mfma_f32_16x16x32_bf16(pal, vbh, accO[nt], 0, 0, 0);
            }
        }
        __builtin_amdgcn_s_setprio(0);
        __syncthreads();   // P/V reads done before next tile's staging
    }

    // epilogue: unnormalized partial O' + per-row (m,l)
#pragma unroll
    for (int nt = 0; nt < 4; ++nt)
#pragma unroll
        for (int r2 = 0; r2 < 4; ++r2) {
            const int qq = q0 + (w << 4) + (lg << 2) + r2;
            const int dd = h * HDD + (nt << 4) + l15;
            opart[((size_t)z * TT + b * SS + qq) * DD + dd] = accO[nt][r2];
        }
    if (l15 == 0) {
#pragma unroll
        for (int r2 = 0; r2 < 4; ++r2) {
            const int qq = q0 + (w << 4) + (lg << 2) + r2;
            const int idx = z * (32 * SS) + bh * SS + qq;
            mpart[idx] = m_run[r2];
            lpart[idx] = l_run[r2];
        }
    }
}

// ---------------------------------------------------------------------------
// Combine the 2 kv-split partials -> split o hi/lo planes (exp2 domain m/l).
// ---------------------------------------------------------------------------
__global__ __launch_bounds__(256) void attn_combine_kernel(
    const float* __restrict__ opart, const float* __restrict__ mpart,
    const float* __restrict__ lpart, unsigned short* __restrict__ ohi,
    unsigned short* __restrict__ olo)
{
    const int t = blockIdx.x;
    const int tid = threadIdx.x;
    const int b = t >> 10, q = t & 1023;
    const int d0 = tid << 2;
    const int bh = (b << 4) + (d0 >> 6);
    const int mi = bh * SS + q;
    const float m0 = mpart[mi], m1 = mpart[32 * SS + mi];
    const float l0 = lpart[mi], l1 = lpart[32 * SS + mi];
    const float m = fmaxf(m0, m1);
    const float e0 = exp2f(m0 - m), e1 = exp2f(m1 - m);
    const float inv = 1.0f / (l0 * e0 + l1 * e1);
    const float4 a = *(const float4*)(opart + (size_t)t * DD + d0);
    const float4 c = *(const float4*)(opart + (size_t)(TT + t) * DD + d0);
    const float vv[4] = { (a.x * e0 + c.x * e1) * inv, (a.y * e0 + c.y * e1) * inv,
                          (a.z * e0 + c.z * e1) * inv, (a.w * e0 + c.w * e1) * inv };
    ush4 hh, ll;
#pragma unroll
    for (int j = 0; j < 4; ++j) {
        const unsigned short hb = f2bf(vv[j]);
        hh[j] = hb;
        ll[j] = f2bf(vv[j] - bf2f(hb));
    }
    *(ush4*)(ohi + (size_t)t * DD + d0) = hh;
    *(ush4*)(olo + (size_t)t * DD + d0) = ll;
}

// ---------------------------------------------------------------------------
// LayerNorm per row (LN2).
// ---------------------------------------------------------------------------
__global__ __launch_bounds__(256) void ln_kernel(
    const float* __restrict__ in, const float* __restrict__ gamma,
    const float* __restrict__ beta, float* __restrict__ outf)
{
    const int t = blockIdx.x;
    const int tid = threadIdx.x;
    __shared__ float red[8];
    const float4 v = ((const float4*)(in + (size_t)t * DD))[tid];
    float s = v.x + v.y + v.z + v.w;
    s = wave_sum(s);
    const int wid = tid >> 6, lane = tid & 63;
    if (lane == 0) red[wid] = s;
    __syncthreads();
    const float mu = (red[0] + red[1] + red[2] + red[3]) * (1.0f / DD);
    const float d0 = v.x - mu, d1 = v.y - mu, d2 = v.z - mu, d3 = v.w - mu;
    float q = d0 * d0 + d1 * d1 + d2 * d2 + d3 * d3;
    q = wave_sum(q);
    if (lane == 0) red[4 + wid] = q;
    __syncthreads();
    const float var = (red[4] + red[5] + red[6] + red[7]) * (1.0f / DD);
    const float rstd = 1.0f / sqrtf(var + 1e-5f);
    const float4 g4 = ((const float4*)gamma)[tid];
    const float4 b4 = ((const float4*)beta)[tid];
    float4 ov = { d0 * rstd * g4.x + b4.x, d1 * rstd * g4.y + b4.y,
                  d2 * rstd * g4.z + b4.z, d3 * rstd * g4.w + b4.w };
    ((float4*)(outf + (size_t)t * DD))[tid] = ov;
}

// ---------------------------------------------------------------------------
// Fused LN1 + hierarchical top-1 routing. One token per block.
// ---------------------------------------------------------------------------
__global__ __launch_bounds__(256) void ln_route_kernel(
    const float* __restrict__ in, const float* __restrict__ gamma,
    const float* __restrict__ beta, float* __restrict__ outf,
    unsigned short* __restrict__ outb,
    const float* __restrict__ wg, const float* __restrict__ bg,
    const float* __restrict__ we, const float* __restrict__ be,
    int* __restrict__ eid, float* __restrict__ gate, int* __restrict__ counts)
{
    const int t = blockIdx.x;
    const int tid = threadIdx.x;
    __shared__ float red[8];
    __shared__ float red2[4][12];
    const float4 v = ((const float4*)(in + (size_t)t * DD))[tid];
    float s = v.x + v.y + v.z + v.w;
    s = wave_sum(s);
    const int wid = tid >> 6, lane = tid & 63;
    if (lane == 0) red[wid] = s;
    __syncthreads();
    const float mu = (red[0] + red[1] + red[2] + red[3]) * (1.0f / DD);
    const float d0 = v.x - mu, d1 = v.y - mu, d2 = v.z - mu, d3 = v.w - mu;
    float q = d0 * d0 + d1 * d1 + d2 * d2 + d3 * d3;
    q = wave_sum(q);
    if (lane == 0) red[4 + wid] = q;
    __syncthreads();
    const float var = (red[4] + red[5] + red[6] + red[7]) * (1.0f / DD);
    const float rstd = 1.0f / sqrtf(var + 1e-5f);
    const float4 g4 = ((const float4*)gamma)[tid];
    const float4 b4 = ((const float4*)beta)[tid];
    const float o0 = d0 * rstd * g4.x + b4.x;
    const float o1 = d1 * rstd * g4.y + b4.y;
    const float o2 = d2 * rstd * g4.z + b4.z;
    const float o3 = d3 * rstd * g4.w + b4.w;
    float4 ov = {o0, o1, o2, o3};
    ((float4*)(outf + (size_t)t * DD))[tid] = ov;
    ush4 wv = { f2bf(o0), f2bf(o1), f2bf(o2), f2bf(o3) };
    *(ush4*)(outb + (size_t)t * DD + (tid << 2)) = wv;

    // routing partials: 4 group + 8 expert logits
    float pz[12];
#pragma unroll
    for (int k = 0; k < 12; ++k) pz[k] = 0.f;
    const float xo[4] = {o0, o1, o2, o3};
#pragma unroll
    for (int j = 0; j < 4; ++j) {
        const int c = (tid << 2) + j;
        const float xv = xo[j];
        const float4 wgv = *(const float4*)(wg + c * NG);
        pz[0] = fmaf(xv, wgv.x, pz[0]);
        pz[1] = fmaf(xv, wgv.y, pz[1]);
        pz[2] = fmaf(xv, wgv.z, pz[2]);
        pz[3] = fmaf(xv, wgv.w, pz[3]);
#pragma unroll
        for (int g = 0; g < NG; ++g) {
            const float2 wev = *(const float2*)(we + ((size_t)g * DD + c) * EPG);
            pz[4 + 2 * g]     = fmaf(xv, wev.x, pz[4 + 2 * g]);
            pz[4 + 2 * g + 1] = fmaf(xv, wev.y, pz[4 + 2 * g + 1]);
        }
    }
#pragma unroll
    for (int k = 0; k < 12; ++k) pz[k] = wave_sum(pz[k]);
    if (lane == 0) {
#pragma unroll
        for (int k = 0; k < 12; ++k) red2[wid][k] = pz[k];
    }
    __syncthreads();
    if (tid == 0) {
        float zs[12];
#pragma unroll
        for (int k = 0; k < 12; ++k)
            zs[k] = red2[0][k] + red2[1][k] + red2[2][k] + red2[3][k];
        float z[NG];
#pragma unroll
        for (int g = 0; g < NG; ++g) z[g] = zs[g] + bg[g];
        int gi = 0; float zb = z[0];
#pragma unroll
        for (int g = 1; g < NG; ++g) if (z[g] > zb) { zb = z[g]; gi = g; }
        float se = 0.f;
#pragma unroll
        for (int g = 0; g < NG; ++g) se += __expf(z[g] - zb);
        const float gprob = 1.0f / se;
        float e0 = 0.f, e1 = 0.f;
#pragma unroll
        for (int g = 0; g < NG; ++g) {
            if (g == gi) {
                e0 = zs[4 + 2 * g] + be[g * EPG + 0];
                e1 = zs[4 + 2 * g + 1] + be[g * EPG + 1];
            }
        }
        const int ei = (e1 > e0) ? 1 : 0;
        const float ehi = ei ? e1 : e0, elo = ei ? e0 : e1;
        const float eprob = 1.0f / (1.0f + __expf(elo - ehi));
        eid[t] = gi * EPG + ei;
        gate[t] = gprob * eprob;
        atomicAdd(&counts[gi * EPG + ei], 1);
    }
}

__global__ void zero_counts_kernel(int* __restrict__ counts) {
    if (threadIdx.x < NE) counts[threadIdx.x] = 0;
}

__global__ void offsets_kernel(const int* __restrict__ counts, int* __restrict__ offs,
                               int* __restrict__ cursor) {
    if (threadIdx.x == 0) {
        int run = 0;
        for (int e = 0; e < NE; ++e) { offs[e] = run; cursor[e] = run; run += counts[e]; }
        offs[NE] = run;
    }
}

__global__ __launch_bounds__(256) void scatter_kernel(const int* __restrict__ eid,
                                                      int* __restrict__ cursor,
                                                      int* __restrict__ perm) {
    const int t = blockIdx.x * 256 + threadIdx.x;
    const int slot = atomicAdd(&cursor[eid[t]], 1);
    perm[slot] = t;
}

// ---------------------------------------------------------------------------
// fp32 [batch][R][C] -> bf16 [batch][C][R] (LDS-tiled transpose + convert)
// ---------------------------------------------------------------------------
__global__ __launch_bounds__(256) void transpose_bf16_kernel(
    const float* __restrict__ in, unsigned short* __restrict__ out, int R, int C)
{
    __shared__ float tile[32][33];
    const int c0 = blockIdx.x << 5, r0 = blockIdx.y << 5;
    const size_t bo = (size_t)blockIdx.z * R * C;
    const int tc = threadIdx.x & 31, tr8 = threadIdx.x >> 5;
#pragma unroll
    for (int p = 0; p < 4; ++p) {
        const int rr = tr8 + (p << 3);
        tile[rr][tc] = in[bo + (size_t)(r0 + rr) * C + c0 + tc];
    }
    __syncthreads();
#pragma unroll
    for (int p = 0; p < 4; ++p) {
        const int rr = tr8 + (p << 3);
        out[bo + (size_t)(c0 + rr) * R + r0 + tc] = f2bf(tile[tc][rr]);
    }
}

// ---------------------------------------------------------------------------
// MoE expert GEMM 1: h[slot][F] = relu(x1b[perm[slot]] . w1t[e]^T + b1[e])
// ---------------------------------------------------------------------------
__global__ __launch_bounds__(256) void moe_gemm1_kernel(
    const unsigned short* __restrict__ x1b, const unsigned short* __restrict__ w1t,
    const float* __restrict__ b1, const int* __restrict__ offs,
    const int* __restrict__ perm, unsigned short* __restrict__ hbuf)
{
    const int e = blockIdx.y >> 5, mt = blockIdx.y & 31;
    const int row0 = offs[e] + (mt << 6);
    const int rend = offs[e + 1];
    if (row0 >= rend) return;
    const int valid = (rend - row0 < 64) ? (rend - row0) : 64;
    const int n0 = blockIdx.x << 6;
    __shared__ unsigned short As[64][72];
    __shared__ unsigned short Bs[64][72];
    const int lane = threadIdx.x & 63, wid = threadIdx.x >> 6;
    const int l15 = lane & 15, lg = lane >> 4;
    f32x4 acc0 = {0.f, 0.f, 0.f, 0.f}, acc1 = acc0, acc2 = acc0, acc3 = acc0;
    const unsigned short* Bbase = w1t + (size_t)e * FF * DD + (size_t)n0 * DD;
    for (int k0 = 0; k0 < DD; k0 += 64) {
#pragma unroll
        for (int rep = 0; rep < 2; ++rep) {
            const int idx = threadIdx.x + (rep << 8);
            const int rr = idx >> 3, c8 = (idx & 7) << 3;
            bf16x8 av = {0, 0, 0, 0, 0, 0, 0, 0};
            if (rr < valid) {
                const int tk = perm[row0 + rr];
                av = *(const bf16x8*)(x1b + (size_t)tk * DD + k0 + c8);
            }
            *(bf16x8*)&As[rr][c8] = av;
            const bf16x8 bv = *(const bf16x8*)(Bbase + (size_t)rr * DD + k0 + c8);
            *(bf16x8*)&Bs[rr][c8] = bv;
        }
        __syncthreads();
#pragma unroll
        for (int ks = 0; ks < 2; ++ks) {
            const int kc = (ks << 5) + (lg << 3);
            const bf16x8 a  = *(const bf16x8*)&As[(wid << 4) + l15][kc];
            const bf16x8 f0 = *(const bf16x8*)&Bs[ 0 + l15][kc];
            const bf16x8 f1 = *(const bf16x8*)&Bs[16 + l15][kc];
            const bf16x8 f2 = *(const bf16x8*)&Bs[32 + l15][kc];
            const bf16x8 f3 = *(const bf16x8*)&Bs[48 + l15][kc];
            acc0 = __builtin_amdgcn_mfma_f32_16x16x32_bf16(a, f0, acc0, 0, 0, 0);
            acc1 = __builtin_amdgcn_mfma_f32_16x16x32_bf16(a, f1, acc1, 0, 0, 0);
            acc2 = __builtin_amdgcn_mfma_f32_16x16x32_bf16(a, f2, acc2, 0, 0, 0);
            acc3 = __builtin_amdgcn_mfma_f32_16x16x32_bf16(a, f3, acc3, 0, 0, 0);
        }
        __syncthreads();
    }
    const float* bias = b1 + e * FF + n0;
    const int mbase = (wid << 4) + (lg << 2);
#pragma unroll
    for (int nt = 0; nt < 4; ++nt) {
        const f32x4 ac = (nt == 0) ? acc0 : (nt == 1) ? acc1 : (nt == 2) ? acc2 : acc3;
        const int n = (nt << 4) + l15;
#pragma unroll
        for (int r2 = 0; r2 < 4; ++r2) {
            const int m = mbase + r2;
            if (m < valid) {
                float v = ac[r2] + bias[n];
                v = fmaxf(v, 0.f);
                hbuf[(size_t)(row0 + m) * FF + n0 + n] = f2bf(v);
            }
        }
    }
}

// ---------------------------------------------------------------------------
// MoE expert GEMM 2: res2[tk] = x1[tk] + gate[tk]*(h[slot] . w2t[e]^T + b2[e])
// ---------------------------------------------------------------------------
__global__ __launch_bounds__(256) void moe_gemm2_kernel(
    const unsigned short* __restrict__ hbuf, const unsigned short* __restrict__ w2t,
    const float* __restrict__ b2, const int* __restrict__ offs,
    const int* __restrict__ perm, const float* __restrict__ gate,
    const float* __restrict__ x1, float* __restrict__ res2)
{
    const int e = blockIdx.y >> 5, mt = blockIdx.y & 31;
    const int row0 = offs[e] + (mt << 6);
    const int rend = offs[e + 1];
    if (row0 >= rend) return;
    const int valid = (rend - row0 < 64) ? (rend - row0) : 64;
    const int n0 = blockIdx.x << 6;
    __shared__ unsigned short As[64][72];
    __shared__ unsigned short Bs[64][72];
    const int lane = threadIdx.x & 63, wid = threadIdx.x >> 6;
    const int l15 = lane & 15, lg = lane >> 4;
    f32x4 acc0 = {0.f, 0.f, 0.f, 0.f}, acc1 = acc0, acc2 = acc0, acc3 = acc0;
    const unsigned short* Bbase = w2t + (size_t)e * DD * FF + (size_t)n0 * FF;
    for (int k0 = 0; k0 < FF; k0 += 64) {
#pragma unroll
        for (int rep = 0; rep < 2; ++rep) {
            const int idx = threadIdx.x + (rep << 8);
            const int rr = idx >> 3, c8 = (idx & 7) << 3;
            bf16x8 av = {0, 0, 0, 0, 0, 0, 0, 0};
            if (rr < valid) av = *(const bf16x8*)(hbuf + (size_t)(row0 + rr) * FF + k0 + c8);
            *(bf16x8*)&As[rr][c8] = av;
            const bf16x8 bv = *(const bf16x8*)(Bbase + (size_t)rr * FF + k0 + c8);
            *(bf16x8*)&Bs[rr][c8] = bv;
        }
        __syncthreads();
#pragma unroll
        for (int ks = 0; ks < 2; ++ks) {
            const int kc = (ks << 5) + (lg << 3);
            const bf16x8 a  = *(const bf16x8*)&As[(wid << 4) + l15][kc];
            const bf16x8 f0 = *(const bf16x8*)&Bs[ 0 + l15][kc];
            const bf16x8 f1 = *(const bf16x8*)&Bs[16 + l15][kc];
            const bf16x8 f2 = *(const bf16x8*)&Bs[32 + l15][kc];
            const bf16x8 f3 = *(const bf16x8*)&Bs[48 + l15][kc];
            acc0 = __builtin_amdgcn_mfma_f32_16x16x32_bf16(a, f0, acc0, 0, 0, 0);
            acc1 = __builtin_amdgcn_mfma_f32_16x16x32_bf16(a, f1, acc1, 0, 0, 0);
            acc2 = __builtin_amdgcn_mfma_f32_16x16x32_bf16(a, f2, acc2, 0, 0, 0);
            acc3 = __builtin_amdgcn_mfma_f32_16x16x32_bf16(a, f3, acc3, 0, 0, 0);
        }
        __syncthreads();
    }
    const int mbase = (wid << 4) + (lg << 2);
#pragma unroll
    for (int nt = 0; nt < 4; ++nt) {
        const f32x4 ac = (nt == 0) ? acc0 : (nt == 1) ? acc1 : (nt == 2) ? acc2 : acc3;
        const int nl = (nt << 4) + l15;
#pragma unroll
        for (int r2 = 0; r2 < 4; ++r2) {
            const int m = mbase + r2;
            if (m < valid) {
                const int tk = perm[row0 + m];
                const float v = ac[r2] + b2[e * DD + n0 + nl];
                const size_t oi = (size_t)tk * DD + n0 + nl;
                res2[oi] = x1[oi] + gate[tk] * v;
            }
        }
    }
}

// ---------------------------------------------------------------------------
extern "C" void kernel_launch(void* const* d_in, const int* in_sizes, int n_in,
                              void* d_out, int out_size, void* d_ws, size_t ws_size,
                              hipStream_t stream)
{
    (void)in_sizes; (void)n_in; (void)out_size; (void)ws_size;
    const float* x   = (const float*)d_in[0];
    const float* wi  = (const float*)d_in[1];
    const float* bi  = (const float*)d_in[2];
    const float* wo  = (const float*)d_in[3];
    const float* bo  = (const float*)d_in[4];
    const float* g1  = (const float*)d_in[5];
    const float* be1 = (const float*)d_in[6];
    const float* g2  = (const float*)d_in[7];
    const float* be2 = (const float*)d_in[8];
    const float* wgr = (const float*)d_in[9];
    const float* bgr = (const float*)d_in[10];
    const float* wex = (const float*)d_in[11];
    const float* bex = (const float*)d_in[12];
    const float* w1  = (const float*)d_in[13];
    const float* b1  = (const float*)d_in[14];
    const float* w2  = (const float*)d_in[15];
    const float* b2  = (const float*)d_in[16];
    float* out = (float*)d_out;

    char* ws = (char*)d_ws;
    unsigned short* qkvh  = (unsigned short*)(ws + 0);         // 12 MB [t][3072]
    unsigned short* qkvl  = (unsigned short*)(ws + 12582912);  // 12 MB
    unsigned short* hbuf  = (unsigned short*)(ws + 0);         // 8 MB (post-attn)
    float* res2           = (float*)(ws + 8388608);            // 8 MB (post-attn)
    unsigned short* vth   = (unsigned short*)(ws + 25165824);  // 4 MB [bh][64][1024]
    unsigned short* vtl   = (unsigned short*)(ws + 29360128);  // 4 MB
    float* res1           = (float*)(ws + 33554432);           // 8 MB
    float* x1             = (float*)(ws + 41943040);           // 8 MB
    unsigned short* x1b   = (unsigned short*)(ws + 50331648);  // 4 MB
    unsigned short* w1t   = (unsigned short*)(ws + 54525952);  // 32 MB
    unsigned short* w2t   = (unsigned short*)(ws + 88080384);  // 32 MB
    char* misc = ws + 121634816;
    int*   eid    = (int*)(misc);
    float* gate   = (float*)(misc + 8192);
    int*   perm   = (int*)(misc + 16384);
    int*   counts = (int*)(misc + 24576);
    int*   offs   = (int*)(misc + 24640);
    int*   cursor = (int*)(misc + 24704);

    // Aliased split-plane buffers (dead before their host region is written):
    unsigned short* xs_hi = (unsigned short*)(ws + 33554432);            // res1 region
    unsigned short* xs_lo = (unsigned short*)(ws + 33554432 + 4194304);
    unsigned short* wi_hi = (unsigned short*)(ws + 54525952);            // w1t region
    unsigned short* wi_lo = (unsigned short*)(ws + 54525952 + 6291456);
    unsigned short* o_hi  = (unsigned short*)(ws + 41943040);            // x1 region
    unsigned short* o_lo  = (unsigned short*)(ws + 41943040 + 4194304);
    unsigned short* wo_hi = (unsigned short*)(ws + 88080384);            // w2t region
    unsigned short* wo_lo = (unsigned short*)(ws + 88080384 + 2097152);

    // Attention partials in the w1t region (dead until expert-weight transposes):
    float* opart = (float*)(ws + 54525952);
    float* mpart = (float*)(ws + 54525952 + 16777216);
    float* lpart = (float*)(ws + 54525952 + 17039360);

    zero_counts_kernel<<<dim3(1), dim3(64), 0, stream>>>(counts);

    // --- split x and in_proj_w; QKV = x @ wi^T + bi -> split planes, Q pre-scaled
    split_bf16_kernel<<<dim3((TT * DD / 4 + 255) / 256), dim3(256), 0, stream>>>(x, xs_hi, xs_lo, TT * DD / 4);
    split_bf16_kernel<<<dim3((3 * DD * DD / 4 + 255) / 256), dim3(256), 0, stream>>>(wi, wi_hi, wi_lo, 3 * DD * DD / 4);
    gemm_split_kernel<<<dim3(3 * DD / 64, TT / 128), dim3(256), 0, stream>>>(
        xs_hi, xs_lo, wi_hi, wi_lo, bi, (const float*)nullptr,
        (float*)nullptr, qkvh, qkvl, DD, TT, 3 * DD, DD);

    // --- V^T planes for the PV MFMA B-operand
    vtrans_kernel<<<dim3(SS / 64, 2 * NHD), dim3(256), 0, stream>>>(qkvh, vth);
    vtrans_kernel<<<dim3(SS / 64, 2 * NHD), dim3(256), 0, stream>>>(qkvl, vtl);

    // --- split-precision MFMA flash attention (kv-split x2) + combine
    attn_mfma_kernel<<<dim3(SS / 64, 2 * NHD, 2), dim3(256), 0, stream>>>(
        qkvh, qkvl, vth, vtl, opart, mpart, lpart);
    attn_combine_kernel<<<dim3(TT), dim3(256), 0, stream>>>(opart, mpart, lpart, o_hi, o_lo);

    // --- split out_proj_w; res1 = x + o @ wo^T + bo (fp32 out)
    split_bf16_kernel<<<dim3((DD * DD / 4 + 255) / 256), dim3(256), 0, stream>>>(wo, wo_hi, wo_lo, DD * DD / 4);
    gemm_split_kernel<<<dim3(DD / 64, TT / 128), dim3(256), 0, stream>>>(
        o_hi, o_lo, wo_hi, wo_lo, bo, x,
        res1, (unsigned short*)nullptr, (unsigned short*)nullptr, 0, TT, DD, DD);

    // --- fused LN1 + routing -> x1, x1b, eid, gate, counts
    ln_route_kernel<<<dim3(TT), dim3(256), 0, stream>>>(
        res1, g1, be1, x1, x1b, wgr, bgr, wex, bex, eid, gate, counts);
    offsets_kernel<<<dim3(1), dim3(64), 0, stream>>>(counts, offs, cursor);
    scatter_kernel<<<dim3(TT / 256), dim3(256), 0, stream>>>(eid, cursor, perm);

    // --- expert weights -> bf16 [N][K] (overwrites attn partials: now dead)
    transpose_bf16_kernel<<<dim3(FF / 32, DD / 32, NE), dim3(256), 0, stream>>>(w1, w1t, DD, FF);
    transpose_bf16_kernel<<<dim3(DD / 32, FF / 32, NE), dim3(256), 0, stream>>>(w2, w2t, FF, DD);

    // --- sparse expert FFN (bf16 MFMA)
    moe_gemm1_kernel<<<dim3(FF / 64, NE * 32), dim3(256), 0, stream>>>(x1b, w1t, b1, offs, perm, hbuf);
    moe_gemm2_kernel<<<dim3(DD / 64, NE * 32), dim3(256), 0, stream>>>(hbuf, w2t, b2, offs, perm, gate, x1, res2);

    // --- LN2 -> final output (fp32)
    ln_kernel<<<dim3(TT), dim3(256), 0, stream>>>(res2, g2, be2, out);
}

// Round 7
// 291.518 us; speedup vs baseline: 1.2567x; 1.0927x over previous
//
#include <hip/hip_runtime.h>
#include <hip/hip_bf16.h>

// Problem constants (B=2, S=1024, D=1024, F=2048, H=16, hd=64, G=4, Epg=2, E=8)
#define TT 2048
#define DD 1024
#define FF 2048
#define SS 1024
#define NHD 16
#define HDD 64
#define NG 4
#define EPG 2
#define NE 8

// 0.125 (1/sqrt(hd)) * log2(e): puts QK^T scores in exp2 domain.
#define QSC 0.18033688011112042f

typedef __attribute__((ext_vector_type(8))) short bf16x8;
typedef __attribute__((ext_vector_type(4))) float f32x4;
typedef __attribute__((ext_vector_type(4))) unsigned short ush4;

__device__ __forceinline__ unsigned short f2bf(float x) {
    unsigned int u = __float_as_uint(x);
    u = (u + 0x7fffu + ((u >> 16) & 1u)) >> 16;
    return (unsigned short)u;
}
__device__ __forceinline__ float bf2f(unsigned short h) {
    return __uint_as_float((unsigned int)h << 16);
}

__device__ __forceinline__ float wave_sum(float s) {
#pragma unroll
    for (int off = 32; off > 0; off >>= 1) s += __shfl_xor(s, off);
    return s;
}

// async global -> LDS, 16B per lane; lds dest = wave-uniform base + lane*16
__device__ __forceinline__ void gl16(const void* g, void* l) {
    auto gp = reinterpret_cast<const unsigned int __attribute__((address_space(1)))*>(
        (unsigned long long)g);
    auto lp = reinterpret_cast<unsigned int __attribute__((address_space(3)))*>(
        (unsigned int)(unsigned long long)l);
    __builtin_amdgcn_global_load_lds(gp, lp, 16, 0, 0);
}

// ---------------------------------------------------------------------------
// fp32 -> bf16 hi/lo split planes
// ---------------------------------------------------------------------------
__global__ __launch_bounds__(256) void split_bf16_kernel(
    const float* __restrict__ in, unsigned short* __restrict__ hi,
    unsigned short* __restrict__ lo, int n4)
{
    const int i = blockIdx.x * 256 + threadIdx.x;
    if (i >= n4) return;
    const float4 v = ((const float4*)in)[i];
    float vv[4] = {v.x, v.y, v.z, v.w};
    ush4 h, l;
#pragma unroll
    for (int j = 0; j < 4; ++j) {
        const unsigned short hb = f2bf(vv[j]);
        ((unsigned short*)&h)[j] = hb;
        ((unsigned short*)&l)[j] = f2bf(vv[j] - bf2f(hb));
    }
    ((ush4*)hi)[i] = h;
    ((ush4*)lo)[i] = l;
}

// ---------------------------------------------------------------------------
// Split-precision GEMM: C[M,N] = A[M,K] . B[N,K]^T + bias (+resid).
// 3-term MFMA. 128(M)x64(N) tile, BK=64, 4 waves each 32 rows x 64 cols.
// ---------------------------------------------------------------------------
__global__ __launch_bounds__(256, 3) void gemm_split_kernel(
    const unsigned short* __restrict__ Ah, const unsigned short* __restrict__ Al,
    const unsigned short* __restrict__ Bh, const unsigned short* __restrict__ Bl,
    const float* __restrict__ bias, const float* __restrict__ resid,
    float* __restrict__ C, unsigned short* __restrict__ Chi,
    unsigned short* __restrict__ Clo, int qscale_n, int M, int N, int K)
{
    __shared__ unsigned short sAh[128 * 64];
    __shared__ unsigned short sAl[128 * 64];
    __shared__ unsigned short sBh[64 * 64];
    __shared__ unsigned short sBl[64 * 64];
    const int tid = threadIdx.x;
    const int lane = tid & 63, wid = tid >> 6;
    const int l15 = lane & 15, lg = lane >> 4;
    const int n0 = blockIdx.x << 6, m0 = blockIdx.y << 7;

    f32x4 acc[2][4];
#pragma unroll
    for (int mi = 0; mi < 2; ++mi)
#pragma unroll
        for (int ni = 0; ni < 4; ++ni) acc[mi][ni] = (f32x4){0.f, 0.f, 0.f, 0.f};

    for (int k0 = 0; k0 < K; k0 += 64) {
#pragma unroll
        for (int r = 0; r < 4; ++r) {
            const int s = (r << 8) + tid;
            const int row = s >> 3;
            const int cs = (s & 7) ^ (row & 7);
            const int lb = (s & ~63) << 3;
            const size_t ga = (size_t)(m0 + row) * K + k0 + (cs << 3);
            gl16(Ah + ga, &sAh[lb]);
            gl16(Al + ga, &sAl[lb]);
        }
#pragma unroll
        for (int r = 0; r < 2; ++r) {
            const int s = (r << 8) + tid;
            const int row = s >> 3;
            const int cs = (s & 7) ^ (row & 7);
            const int lb = (s & ~63) << 3;
            const size_t gb = (size_t)(n0 + row) * K + k0 + (cs << 3);
            gl16(Bh + gb, &sBh[lb]);
            gl16(Bl + gb, &sBl[lb]);
        }
        __syncthreads();
#pragma unroll
        for (int ks = 0; ks < 2; ++ks) {
            bf16x8 ah[2], al[2], bh[4], bl[4];
            const int ac = (ks << 2) + lg;
#pragma unroll
            for (int i = 0; i < 2; ++i) {
                const int ar = (wid << 5) + (i << 4) + l15;
                const int pa = ((ar << 3) | (ac ^ (ar & 7))) << 3;
                ah[i] = *(const bf16x8*)&sAh[pa];
                al[i] = *(const bf16x8*)&sAl[pa];
            }
#pragma unroll
            for (int i = 0; i < 4; ++i) {
                const int br = (i << 4) + l15;
                const int pb = ((br << 3) | (ac ^ (br & 7))) << 3;
                bh[i] = *(const bf16x8*)&sBh[pb];
                bl[i] = *(const bf16x8*)&sBl[pb];
            }
#pragma unroll
            for (int mi = 0; mi < 2; ++mi)
#pragma unroll
                for (int ni = 0; ni < 4; ++ni) {
                    acc[mi][ni] = __builtin_amdgcn_mfma_f32_16x16x32_bf16(ah[mi], bh[ni], acc[mi][ni], 0, 0, 0);
                    acc[mi][ni] = __builtin_amdgcn_mfma_f32_16x16x32_bf16(ah[mi], bl[ni], acc[mi][ni], 0, 0, 0);
                    acc[mi][ni] = __builtin_amdgcn_mfma_f32_16x16x32_bf16(al[mi], bh[ni], acc[mi][ni], 0, 0, 0);
                }
        }
        __syncthreads();
    }
#pragma unroll
    for (int mi = 0; mi < 2; ++mi)
#pragma unroll
        for (int ni = 0; ni < 4; ++ni)
#pragma unroll
            for (int r2 = 0; r2 < 4; ++r2) {
                const int m = m0 + (wid << 5) + (mi << 4) + (lg << 2) + r2;
                const int n = n0 + (ni << 4) + l15;
                float v = acc[mi][ni][r2] + bias[n];
                if (resid) v += resid[(size_t)m * N + n];
                const size_t idx = (size_t)m * N + n;
                if (Chi) {
                    if (n < qscale_n) v *= QSC;
                    const unsigned short hb = f2bf(v);
                    Chi[idx] = hb;
                    Clo[idx] = f2bf(v - bf2f(hb));
                } else {
                    C[idx] = v;
                }
            }
}

// ---------------------------------------------------------------------------
// V^T extraction: bf16 plane [t][3072] -> [bh][64 d][1024 s] transposed plane.
// ---------------------------------------------------------------------------
__global__ __launch_bounds__(256) void vtrans_kernel(
    const unsigned short* __restrict__ src, unsigned short* __restrict__ dst)
{
    __shared__ unsigned short tile[64][65];
    const int bh = blockIdx.y, b = bh >> 4, h = bh & 15;
    const int s0 = blockIdx.x << 6;
    const int tid = threadIdx.x;
#pragma unroll
    for (int r = 0; r < 2; ++r) {
        const int sl = tid + (r << 8);
        const int rr = sl >> 3, c8 = (sl & 7) << 3;
        const bf16x8 v = *(const bf16x8*)(src + (size_t)(b * SS + s0 + rr) * 3072 + 2048 + h * HDD + c8);
#pragma unroll
        for (int j = 0; j < 8; ++j) tile[rr][c8 + j] = ((const unsigned short*)&v)[j];
    }
    __syncthreads();
#pragma unroll
    for (int r = 0; r < 2; ++r) {
        const int sl = tid + (r << 8);
        const int d = sl >> 3, s8 = (sl & 7) << 3;
        bf16x8 o;
#pragma unroll
        for (int j = 0; j < 8; ++j) ((unsigned short*)&o)[j] = tile[s8 + j][d];
        *(bf16x8*)(dst + (size_t)(bh * HDD + d) * SS + s0 + s8) = o;
    }
}

// ---------------------------------------------------------------------------
// Split-precision MFMA flash attention, kv-split x2, Q in registers.
// ---------------------------------------------------------------------------
__global__ __launch_bounds__(256, 4) void attn_mfma_kernel(
    const unsigned short* __restrict__ qh, const unsigned short* __restrict__ ql,
    const unsigned short* __restrict__ vth, const unsigned short* __restrict__ vtl,
    float* __restrict__ opart, float* __restrict__ mpart, float* __restrict__ lpart)
{
    __shared__ unsigned short sKh[4096], sKl[4096];   // K tiles; P[q][kv] after QK
    __shared__ unsigned short sVh[4096], sVl[4096];
    const int bh = blockIdx.y, b = bh >> 4, h = bh & 15;
    const int q0 = blockIdx.x << 6;
    const int z = blockIdx.z;
    const int tid = threadIdx.x, lane = tid & 63, w = tid >> 6;
    const int l15 = lane & 15, lg = lane >> 4;

    // stage Q tile through (currently dead) sK, pull fragments to registers
#pragma unroll
    for (int r = 0; r < 2; ++r) {
        const int s = (r << 8) + tid;
        const int row = s >> 3;
        const int cs = (s & 7) ^ (row & 7);
        const int lb = (s & ~63) << 3;
        const size_t gq = (size_t)(b * SS + q0 + row) * 3072 + h * HDD + (cs << 3);
        gl16(qh + gq, &sKh[lb]);
        gl16(ql + gq, &sKl[lb]);
    }
    __syncthreads();
    bf16x8 qah[2], qal[2];
#pragma unroll
    for (int ks = 0; ks < 2; ++ks) {
        const int ar = (w << 4) + l15;
        const int ac = (ks << 2) + lg;
        const int pa = ((ar << 3) | (ac ^ (ar & 7))) << 3;
        qah[ks] = *(const bf16x8*)&sKh[pa];
        qal[ks] = *(const bf16x8*)&sKl[pa];
    }
    __syncthreads();

    f32x4 accO[4];
#pragma unroll
    for (int nt = 0; nt < 4; ++nt) accO[nt] = (f32x4){0.f, 0.f, 0.f, 0.f};
    float m_run[4], l_run[4];
#pragma unroll
    for (int r2 = 0; r2 < 4; ++r2) { m_run[r2] = -3.0e38f; l_run[r2] = 0.f; }

    const int kvbeg = z << 9;
    for (int kv0 = kvbeg; kv0 < kvbeg + 512; kv0 += 64) {
        // stage K tile + V^T tile (async direct-to-LDS)
#pragma unroll
        for (int r = 0; r < 2; ++r) {
            const int s = (r << 8) + tid;
            const int row = s >> 3;
            const int cs = (s & 7) ^ (row & 7);
            const int lb = (s & ~63) << 3;
            const size_t gk = (size_t)(b * SS + kv0 + row) * 3072 + DD + h * HDD + (cs << 3);
            gl16(qh + gk, &sKh[lb]);
            gl16(ql + gk, &sKl[lb]);
            const size_t gv = (size_t)(bh * HDD + row) * SS + kv0 + (cs << 3);
            gl16(vth + gv, &sVh[lb]);
            gl16(vtl + gv, &sVl[lb]);
        }
        __syncthreads();

        // QK^T: S[q=w*16+lg*4+r2][kv=i*16+l15]  (scores in log2 units)
        f32x4 sacc[4];
#pragma unroll
        for (int i = 0; i < 4; ++i) sacc[i] = (f32x4){0.f, 0.f, 0.f, 0.f};
        __builtin_amdgcn_s_setprio(1);
#pragma unroll
        for (int ks = 0; ks < 2; ++ks) {
            const int ac = (ks << 2) + lg;
#pragma unroll
            for (int i = 0; i < 4; ++i) {
                const int br = (i << 4) + l15;
                const int pb = ((br << 3) | (ac ^ (br & 7))) << 3;
                const bf16x8 kbh = *(const bf16x8*)&sKh[pb];
                const bf16x8 kbl = *(const bf16x8*)&sKl[pb];
                sacc[i] = __builtin_amdgcn_mfma_f32_16x16x32_bf16(qah[ks], kbh, sacc[i], 0, 0, 0);
                sacc[i] = __builtin_amdgcn_mfma_f32_16x16x32_bf16(qah[ks], kbl, sacc[i], 0, 0, 0);
                sacc[i] = __builtin_amdgcn_mfma_f32_16x16x32_bf16(qal[ks], kbh, sacc[i], 0, 0, 0);
            }
        }
        __builtin_amdgcn_s_setprio(0);
        __syncthreads();   // all waves done reading K before P overwrites it

        // online softmax per q-row (exp2 domain), reduce across 16 lanes
#pragma unroll
        for (int r2 = 0; r2 < 4; ++r2) {
            float mx = fmaxf(fmaxf(sacc[0][r2], sacc[1][r2]), fmaxf(sacc[2][r2], sacc[3][r2]));
#pragma unroll
            for (int off = 1; off < 16; off <<= 1) mx = fmaxf(mx, __shfl_xor(mx, off));
            const float mn = fmaxf(m_run[r2], mx);
            const float corr = exp2f(m_run[r2] - mn);
            m_run[r2] = mn;
            float ls = 0.f;
#pragma unroll
            for (int nt = 0; nt < 4; ++nt) {
                const float p = exp2f(sacc[nt][r2] - mn);
                sacc[nt][r2] = p;
                ls += p;
            }
#pragma unroll
            for (int off = 1; off < 16; off <<= 1) ls += __shfl_xor(ls, off);
            l_run[r2] = l_run[r2] * corr + ls;
#pragma unroll
            for (int nt = 0; nt < 4; ++nt) accO[nt][r2] *= corr;
        }

        // store P[q][kv] hi/lo into dead K LDS (wave-private rows, truncating split)
#pragma unroll
        for (int nt = 0; nt < 4; ++nt)
#pragma unroll
            for (int r2 = 0; r2 < 4; ++r2) {
                const int qq = (w << 4) + (lg << 2) + r2;
                const int kv = (nt << 4) + l15;
                const int idx = (qq << 6) + ((((kv >> 3) ^ (qq & 7))) << 3) + (kv & 7);
                const float p = sacc[nt][r2];
                const unsigned short hb = (unsigned short)(__float_as_uint(p) >> 16);
                sKh[idx] = hb;
                sKl[idx] = (unsigned short)(__float_as_uint(p - bf2f(hb)) >> 16);
            }
        // no barrier: each wave reads back only its own 16 q-rows

        // PV: O[q][d=nt*16+l15] += P[q][kv] * V[kv][d]
        __builtin_amdgcn_s_setprio(1);
#pragma unroll
        for (int ks = 0; ks < 2; ++ks) {
            const int qq = (w << 4) + l15;
            const int slot = (ks << 2) + lg;
            const int pidx = (qq << 6) + ((slot ^ (qq & 7)) << 3);
            const bf16x8 pah = *(const bf16x8*)&sKh[pidx];
            const bf16x8 pal = *(const bf16x8*)&sKl[pidx];
            const int ac = (ks << 2) + lg;
#pragma unroll
            for (int nt = 0; nt < 4; ++nt) {
                const int dr = (nt << 4) + l15;
                const int pv = ((dr << 3) | (ac ^ (dr & 7))) << 3;
                const bf16x8 vbh = *(const bf16x8*)&sVh[pv];
                const bf16x8 vbl = *(const bf16x8*)&sVl[pv];
                accO[nt] = __builtin_amdgcn_mfma_f32_16x16x32_bf16(pah, vbh, accO[nt], 0, 0, 0);
                accO[nt] = __builtin_amdgcn_mfma_f32_16x16x32_bf16(pah, vbl, accO[nt], 0, 0, 0);
                accO[nt] = __builtin_amdgcn_mfma_f32_16x16x32_bf16(pal, vbh, accO[nt], 0, 0, 0);
            }
        }
        __builtin_amdgcn_s_setprio(0);
        __syncthreads();   // P/V reads done before next tile's staging
    }

    // epilogue: unnormalized partial O' + per-row (m,l)
#pragma unroll
    for (int nt = 0; nt < 4; ++nt)
#pragma unroll
        for (int r2 = 0; r2 < 4; ++r2) {
            const int qq = q0 + (w << 4) + (lg << 2) + r2;
            const int dd = h * HDD + (nt << 4) + l15;
            opart[((size_t)z * TT + b * SS + qq) * DD + dd] = accO[nt][r2];
        }
    if (l15 == 0) {
#pragma unroll
        for (int r2 = 0; r2 < 4; ++r2) {
            const int qq = q0 + (w << 4) + (lg << 2) + r2;
            const int idx = z * (32 * SS) + bh * SS + qq;
            mpart[idx] = m_run[r2];
            lpart[idx] = l_run[r2];
        }
    }
}

// ---------------------------------------------------------------------------
// Combine the 2 kv-split partials -> split o hi/lo planes (exp2 domain m/l).
// ---------------------------------------------------------------------------
__global__ __launch_bounds__(256) void attn_combine_kernel(
    const float* __restrict__ opart, const float* __restrict__ mpart,
    const float* __restrict__ lpart, unsigned short* __restrict__ ohi,
    unsigned short* __restrict__ olo)
{
    const int t = blockIdx.x;
    const int tid = threadIdx.x;
    const int b = t >> 10, q = t & 1023;
    const int d0 = tid << 2;
    const int bh = (b << 4) + (d0 >> 6);
    const int mi = bh * SS + q;
    const float m0 = mpart[mi], m1 = mpart[32 * SS + mi];
    const float l0 = lpart[mi], l1 = lpart[32 * SS + mi];
    const float m = fmaxf(m0, m1);
    const float e0 = exp2f(m0 - m), e1 = exp2f(m1 - m);
    const float inv = 1.0f / (l0 * e0 + l1 * e1);
    const float4 a = *(const float4*)(opart + (size_t)t * DD + d0);
    const float4 c = *(const float4*)(opart + (size_t)(TT + t) * DD + d0);
    const float vv[4] = { (a.x * e0 + c.x * e1) * inv, (a.y * e0 + c.y * e1) * inv,
                          (a.z * e0 + c.z * e1) * inv, (a.w * e0 + c.w * e1) * inv };
    ush4 hh, ll;
#pragma unroll
    for (int j = 0; j < 4; ++j) {
        const unsigned short hb = f2bf(vv[j]);
        hh[j] = hb;
        ll[j] = f2bf(vv[j] - bf2f(hb));
    }
    *(ush4*)(ohi + (size_t)t * DD + d0) = hh;
    *(ush4*)(olo + (size_t)t * DD + d0) = ll;
}

// ---------------------------------------------------------------------------
// LayerNorm per row (LN2).
// ---------------------------------------------------------------------------
__global__ __launch_bounds__(256) void ln_kernel(
    const float* __restrict__ in, const float* __restrict__ gamma,
    const float* __restrict__ beta, float* __restrict__ outf)
{
    const int t = blockIdx.x;
    const int tid = threadIdx.x;
    __shared__ float red[8];
    const float4 v = ((const float4*)(in + (size_t)t * DD))[tid];
    float s = v.x + v.y + v.z + v.w;
    s = wave_sum(s);
    const int wid = tid >> 6, lane = tid & 63;
    if (lane == 0) red[wid] = s;
    __syncthreads();
    const float mu = (red[0] + red[1] + red[2] + red[3]) * (1.0f / DD);
    const float d0 = v.x - mu, d1 = v.y - mu, d2 = v.z - mu, d3 = v.w - mu;
    float q = d0 * d0 + d1 * d1 + d2 * d2 + d3 * d3;
    q = wave_sum(q);
    if (lane == 0) red[4 + wid] = q;
    __syncthreads();
    const float var = (red[4] + red[5] + red[6] + red[7]) * (1.0f / DD);
    const float rstd = 1.0f / sqrtf(var + 1e-5f);
    const float4 g4 = ((const float4*)gamma)[tid];
    const float4 b4 = ((const float4*)beta)[tid];
    float4 ov = { d0 * rstd * g4.x + b4.x, d1 * rstd * g4.y + b4.y,
                  d2 * rstd * g4.z + b4.z, d3 * rstd * g4.w + b4.w };
    ((float4*)(outf + (size_t)t * DD))[tid] = ov;
}

// ---------------------------------------------------------------------------
// Fused LN1 + hierarchical top-1 routing. One token per block.
// ---------------------------------------------------------------------------
__global__ __launch_bounds__(256) void ln_route_kernel(
    const float* __restrict__ in, const float* __restrict__ gamma,
    const float* __restrict__ beta, float* __restrict__ outf,
    unsigned short* __restrict__ outb,
    const float* __restrict__ wg, const float* __restrict__ bg,
    const float* __restrict__ we, const float* __restrict__ be,
    int* __restrict__ eid, float* __restrict__ gate, int* __restrict__ counts)
{
    const int t = blockIdx.x;
    const int tid = threadIdx.x;
    __shared__ float red[8];
    __shared__ float red2[4][12];
    const float4 v = ((const float4*)(in + (size_t)t * DD))[tid];
    float s = v.x + v.y + v.z + v.w;
    s = wave_sum(s);
    const int wid = tid >> 6, lane = tid & 63;
    if (lane == 0) red[wid] = s;
    __syncthreads();
    const float mu = (red[0] + red[1] + red[2] + red[3]) * (1.0f / DD);
    const float d0 = v.x - mu, d1 = v.y - mu, d2 = v.z - mu, d3 = v.w - mu;
    float q = d0 * d0 + d1 * d1 + d2 * d2 + d3 * d3;
    q = wave_sum(q);
    if (lane == 0) red[4 + wid] = q;
    __syncthreads();
    const float var = (red[4] + red[5] + red[6] + red[7]) * (1.0f / DD);
    const float rstd = 1.0f / sqrtf(var + 1e-5f);
    const float4 g4 = ((const float4*)gamma)[tid];
    const float4 b4 = ((const float4*)beta)[tid];
    const float o0 = d0 * rstd * g4.x + b4.x;
    const float o1 = d1 * rstd * g4.y + b4.y;
    const float o2 = d2 * rstd * g4.z + b4.z;
    const float o3 = d3 * rstd * g4.w + b4.w;
    float4 ov = {o0, o1, o2, o3};
    ((float4*)(outf + (size_t)t * DD))[tid] = ov;
    ush4 wv = { f2bf(o0), f2bf(o1), f2bf(o2), f2bf(o3) };
    *(ush4*)(outb + (size_t)t * DD + (tid << 2)) = wv;

    // routing partials: 4 group + 8 expert logits
    float pz[12];
#pragma unroll
    for (int k = 0; k < 12; ++k) pz[k] = 0.f;
    const float xo[4] = {o0, o1, o2, o3};
#pragma unroll
    for (int j = 0; j < 4; ++j) {
        const int c = (tid << 2) + j;
        const float xv = xo[j];
        const float4 wgv = *(const float4*)(wg + c * NG);
        pz[0] = fmaf(xv, wgv.x, pz[0]);
        pz[1] = fmaf(xv, wgv.y, pz[1]);
        pz[2] = fmaf(xv, wgv.z, pz[2]);
        pz[3] = fmaf(xv, wgv.w, pz[3]);
#pragma unroll
        for (int g = 0; g < NG; ++g) {
            const float2 wev = *(const float2*)(we + ((size_t)g * DD + c) * EPG);
            pz[4 + 2 * g]     = fmaf(xv, wev.x, pz[4 + 2 * g]);
            pz[4 + 2 * g + 1] = fmaf(xv, wev.y, pz[4 + 2 * g + 1]);
        }
    }
#pragma unroll
    for (int k = 0; k < 12; ++k) pz[k] = wave_sum(pz[k]);
    if (lane == 0) {
#pragma unroll
        for (int k = 0; k < 12; ++k) red2[wid][k] = pz[k];
    }
    __syncthreads();
    if (tid == 0) {
        float zs[12];
#pragma unroll
        for (int k = 0; k < 12; ++k)
            zs[k] = red2[0][k] + red2[1][k] + red2[2][k] + red2[3][k];
        float z[NG];
#pragma unroll
        for (int g = 0; g < NG; ++g) z[g] = zs[g] + bg[g];
        int gi = 0; float zb = z[0];
#pragma unroll
        for (int g = 1; g < NG; ++g) if (z[g] > zb) { zb = z[g]; gi = g; }
        float se = 0.f;
#pragma unroll
        for (int g = 0; g < NG; ++g) se += __expf(z[g] - zb);
        const float gprob = 1.0f / se;
        float e0 = 0.f, e1 = 0.f;
#pragma unroll
        for (int g = 0; g < NG; ++g) {
            if (g == gi) {
                e0 = zs[4 + 2 * g] + be[g * EPG + 0];
                e1 = zs[4 + 2 * g + 1] + be[g * EPG + 1];
            }
        }
        const int ei = (e1 > e0) ? 1 : 0;
        const float ehi = ei ? e1 : e0, elo = ei ? e0 : e1;
        const float eprob = 1.0f / (1.0f + __expf(elo - ehi));
        eid[t] = gi * EPG + ei;
        gate[t] = gprob * eprob;
        atomicAdd(&counts[gi * EPG + ei], 1);
    }
}

__global__ void zero_counts_kernel(int* __restrict__ counts) {
    if (threadIdx.x < NE) counts[threadIdx.x] = 0;
}

__global__ void offsets_kernel(const int* __restrict__ counts, int* __restrict__ offs,
                               int* __restrict__ cursor) {
    if (threadIdx.x == 0) {
        int run = 0;
        for (int e = 0; e < NE; ++e) { offs[e] = run; cursor[e] = run; run += counts[e]; }
        offs[NE] = run;
    }
}

__global__ __launch_bounds__(256) void scatter_kernel(const int* __restrict__ eid,
                                                      int* __restrict__ cursor,
                                                      int* __restrict__ perm) {
    const int t = blockIdx.x * 256 + threadIdx.x;
    const int slot = atomicAdd(&cursor[eid[t]], 1);
    perm[slot] = t;
}

// ---------------------------------------------------------------------------
// fp32 [batch][R][C] -> bf16 [batch][C][R] (LDS-tiled transpose + convert)
// ---------------------------------------------------------------------------
__global__ __launch_bounds__(256) void transpose_bf16_kernel(
    const float* __restrict__ in, unsigned short* __restrict__ out, int R, int C)
{
    __shared__ float tile[32][33];
    const int c0 = blockIdx.x << 5, r0 = blockIdx.y << 5;
    const size_t bo = (size_t)blockIdx.z * R * C;
    const int tc = threadIdx.x & 31, tr8 = threadIdx.x >> 5;
#pragma unroll
    for (int p = 0; p < 4; ++p) {
        const int rr = tr8 + (p << 3);
        tile[rr][tc] = in[bo + (size_t)(r0 + rr) * C + c0 + tc];
    }
    __syncthreads();
#pragma unroll
    for (int p = 0; p < 4; ++p) {
        const int rr = tr8 + (p << 3);
        out[bo + (size_t)(c0 + rr) * R + r0 + tc] = f2bf(tile[tc][rr]);
    }
}

// ---------------------------------------------------------------------------
// MoE GEMM 1: h[slot][F] = relu(x1b[perm[slot]] . w1t[e]^T + b1[e])
// 64x64 tile, BK=64, double-buffered LDS, gl16 staging, prefetch pipeline.
// 4 waves, each 16 rows x 64 cols.
// ---------------------------------------------------------------------------
__global__ __launch_bounds__(256, 4) void moe_gemm1_kernel(
    const unsigned short* __restrict__ x1b, const unsigned short* __restrict__ w1t,
    const float* __restrict__ b1, const int* __restrict__ offs,
    const int* __restrict__ perm, unsigned short* __restrict__ hbuf)
{
    const int e = blockIdx.y >> 5, mt = blockIdx.y & 31;
    const int row0 = offs[e] + (mt << 6);
    const int rend = offs[e + 1];
    if (row0 >= rend) return;
    const int valid = min(rend - row0, 64);
    const int n0 = blockIdx.x << 6;
    __shared__ unsigned short sA[2][64 * 64];
    __shared__ unsigned short sB[2][64 * 64];
    const int tid = threadIdx.x;
    const int lane = tid & 63, w = tid >> 6;
    const int l15 = lane & 15, lg = lane >> 4;

    // per-thread staging descriptors (A rows perm-gathered, clamped)
    size_t abase[2], bbase[2];
    int lbs[2];
#pragma unroll
    for (int r = 0; r < 2; ++r) {
        const int s = (r << 8) + tid;
        const int row = s >> 3;
        const int cs = (s & 7) ^ (row & 7);
        lbs[r] = (s & ~63) << 3;
        const int tk = perm[min(row0 + row, rend - 1)];
        abase[r] = (size_t)tk * DD + (cs << 3);
        bbase[r] = ((size_t)e * FF + n0 + row) * DD + (cs << 3);
    }

    f32x4 acc[4];
#pragma unroll
    for (int nt = 0; nt < 4; ++nt) acc[nt] = (f32x4){0.f, 0.f, 0.f, 0.f};

#pragma unroll
    for (int r = 0; r < 2; ++r) {
        gl16(x1b + abase[r], &sA[0][lbs[r]]);
        gl16(w1t + bbase[r], &sB[0][lbs[r]]);
    }
    __syncthreads();
    int cur = 0;
    for (int k0 = 0; k0 < DD; k0 += 64) {
        const int nxt = k0 + 64;
        if (nxt < DD) {
#pragma unroll
            for (int r = 0; r < 2; ++r) {
                gl16(x1b + abase[r] + nxt, &sA[cur ^ 1][lbs[r]]);
                gl16(w1t + bbase[r] + nxt, &sB[cur ^ 1][lbs[r]]);
            }
        }
#pragma unroll
        for (int ks = 0; ks < 2; ++ks) {
            const int ac = (ks << 2) + lg;
            const int ar = (w << 4) + l15;
            const int pa = ((ar << 3) | (ac ^ (ar & 7))) << 3;
            const bf16x8 a = *(const bf16x8*)&sA[cur][pa];
#pragma unroll
            for (int nt = 0; nt < 4; ++nt) {
                const int br = (nt << 4) + l15;
                const int pb = ((br << 3) | (ac ^ (br & 7))) << 3;
                acc[nt] = __builtin_amdgcn_mfma_f32_16x16x32_bf16(
                    a, *(const bf16x8*)&sB[cur][pb], acc[nt], 0, 0, 0);
            }
        }
        __syncthreads();
        cur ^= 1;
    }

    const float* bias = b1 + e * FF + n0;
    const int mbase = (w << 4) + (lg << 2);
#pragma unroll
    for (int nt = 0; nt < 4; ++nt) {
        const int n = (nt << 4) + l15;
#pragma unroll
        for (int r2 = 0; r2 < 4; ++r2) {
            const int m = mbase + r2;
            if (m < valid) {
                float v = fmaxf(acc[nt][r2] + bias[n], 0.f);
                hbuf[(size_t)(row0 + m) * FF + n0 + n] = f2bf(v);
            }
        }
    }
}

// ---------------------------------------------------------------------------
// MoE GEMM 2 (split-K x2): pbuf[z][slot][D] = h[slot] . w2t[e]^T (K-half z).
// Same pipeline structure as gemm1.
// ---------------------------------------------------------------------------
__global__ __launch_bounds__(256, 4) void moe_gemm2_kernel(
    const unsigned short* __restrict__ hbuf, const unsigned short* __restrict__ w2t,
    const int* __restrict__ offs, float* __restrict__ p0, float* __restrict__ p1)
{
    const int e = blockIdx.y >> 5, mt = blockIdx.y & 31;
    const int row0 = offs[e] + (mt << 6);
    const int rend = offs[e + 1];
    if (row0 >= rend) return;
    const int valid = min(rend - row0, 64);
    const int n0 = blockIdx.x << 6;
    const int z = blockIdx.z;
    float* __restrict__ pbuf = z ? p1 : p0;
    __shared__ unsigned short sA[2][64 * 64];
    __shared__ unsigned short sB[2][64 * 64];
    const int tid = threadIdx.x;
    const int lane = tid & 63, w = tid >> 6;
    const int l15 = lane & 15, lg = lane >> 4;

    size_t abase[2], bbase[2];
    int lbs[2];
#pragma unroll
    for (int r = 0; r < 2; ++r) {
        const int s = (r << 8) + tid;
        const int row = s >> 3;
        const int cs = (s & 7) ^ (row & 7);
        lbs[r] = (s & ~63) << 3;
        abase[r] = (size_t)(row0 + row) * FF + (cs << 3);   // slot rows (contiguous)
        bbase[r] = ((size_t)e * DD + n0 + row) * FF + (cs << 3);
    }

    f32x4 acc[4];
#pragma unroll
    for (int nt = 0; nt < 4; ++nt) acc[nt] = (f32x4){0.f, 0.f, 0.f, 0.f};

    const int kbeg = z << 10, kend = kbeg + 1024;
#pragma unroll
    for (int r = 0; r < 2; ++r) {
        gl16(hbuf + abase[r] + kbeg, &sA[0][lbs[r]]);
        gl16(w2t + bbase[r] + kbeg, &sB[0][lbs[r]]);
    }
    __syncthreads();
    int cur = 0;
    for (int k0 = kbeg; k0 < kend; k0 += 64) {
        const int nxt = k0 + 64;
        if (nxt < kend) {
#pragma unroll
            for (int r = 0; r < 2; ++r) {
                gl16(hbuf + abase[r] + nxt, &sA[cur ^ 1][lbs[r]]);
                gl16(w2t + bbase[r] + nxt, &sB[cur ^ 1][lbs[r]]);
            }
        }
#pragma unroll
        for (int ks = 0; ks < 2; ++ks) {
            const int ac = (ks << 2) + lg;
            const int ar = (w << 4) + l15;
            const int pa = ((ar << 3) | (ac ^ (ar & 7))) << 3;
            const bf16x8 a = *(const bf16x8*)&sA[cur][pa];
#pragma unroll
            for (int nt = 0; nt < 4; ++nt) {
                const int br = (nt << 4) + l15;
                const int pb = ((br << 3) | (ac ^ (br & 7))) << 3;
                acc[nt] = __builtin_amdgcn_mfma_f32_16x16x32_bf16(
                    a, *(const bf16x8*)&sB[cur][pb], acc[nt], 0, 0, 0);
            }
        }
        __syncthreads();
        cur ^= 1;
    }

    const int mbase = (w << 4) + (lg << 2);
#pragma unroll
    for (int nt = 0; nt < 4; ++nt) {
        const int n = (nt << 4) + l15;
#pragma unroll
        for (int r2 = 0; r2 < 4; ++r2) {
            const int m = mbase + r2;
            if (m < valid) pbuf[(size_t)(row0 + m) * DD + n0 + n] = acc[nt][r2];
        }
    }
}

// ---------------------------------------------------------------------------
// MoE combine: res2[tk] = x1[tk] + gate[tk] * (P0[slot] + P1[slot] + b2[e])
// ---------------------------------------------------------------------------
__global__ __launch_bounds__(256) void moe2_combine_kernel(
    const float* __restrict__ p0, const float* __restrict__ p1,
    const int* __restrict__ offs, const int* __restrict__ perm,
    const float* __restrict__ gate, const float* __restrict__ b2,
    const float* __restrict__ x1, float* __restrict__ res2)
{
    const int s = blockIdx.x;
    const int tid = threadIdx.x;
    int e = 0;
#pragma unroll
    for (int g = 1; g < NE; ++g) e += (s >= offs[g]) ? 1 : 0;
    const int tk = perm[s];
    const float gt = gate[tk];
    const int c0 = tid << 2;
    const float4 a  = *(const float4*)(p0 + (size_t)s * DD + c0);
    const float4 b  = *(const float4*)(p1 + (size_t)s * DD + c0);
    const float4 bb = *(const float4*)(b2 + (size_t)e * DD + c0);
    const float4 xx = *(const float4*)(x1 + (size_t)tk * DD + c0);
    float4 o = { xx.x + gt * (a.x + b.x + bb.x), xx.y + gt * (a.y + b.y + bb.y),
                 xx.z + gt * (a.z + b.z + bb.z), xx.w + gt * (a.w + b.w + bb.w) };
    *(float4*)(res2 + (size_t)tk * DD + c0) = o;
}

// ---------------------------------------------------------------------------
extern "C" void kernel_launch(void* const* d_in, const int* in_sizes, int n_in,
                              void* d_out, int out_size, void* d_ws, size_t ws_size,
                              hipStream_t stream)
{
    (void)in_sizes; (void)n_in; (void)out_size; (void)ws_size;
    const float* x   = (const float*)d_in[0];
    const float* wi  = (const float*)d_in[1];
    const float* bi  = (const float*)d_in[2];
    const float* wo  = (const float*)d_in[3];
    const float* bo  = (const float*)d_in[4];
    const float* g1  = (const float*)d_in[5];
    const float* be1 = (const float*)d_in[6];
    const float* g2  = (const float*)d_in[7];
    const float* be2 = (const float*)d_in[8];
    const float* wgr = (const float*)d_in[9];
    const float* bgr = (const float*)d_in[10];
    const float* wex = (const float*)d_in[11];
    const float* bex = (const float*)d_in[12];
    const float* w1  = (const float*)d_in[13];
    const float* b1  = (const float*)d_in[14];
    const float* w2  = (const float*)d_in[15];
    const float* b2  = (const float*)d_in[16];
    float* out = (float*)d_out;

    char* ws = (char*)d_ws;
    unsigned short* qkvh  = (unsigned short*)(ws + 0);         // 12 MB [t][3072]
    unsigned short* qkvl  = (unsigned short*)(ws + 12582912);  // 12 MB
    unsigned short* hbuf  = (unsigned short*)(ws + 0);         // 8 MB (post-attn)
    float* res2           = (float*)(ws + 8388608);            // 8 MB (post-attn)
    unsigned short* vth   = (unsigned short*)(ws + 25165824);  // 4 MB [bh][64][1024]
    unsigned short* vtl   = (unsigned short*)(ws + 29360128);  // 4 MB
    float* res1           = (float*)(ws + 33554432);           // 8 MB
    float* x1             = (float*)(ws + 41943040);           // 8 MB
    unsigned short* x1b   = (unsigned short*)(ws + 50331648);  // 4 MB
    unsigned short* w1t   = (unsigned short*)(ws + 54525952);  // 32 MB
    unsigned short* w2t   = (unsigned short*)(ws + 88080384);  // 32 MB
    char* misc = ws + 121634816;
    int*   eid    = (int*)(misc);
    float* gate   = (float*)(misc + 8192);
    int*   perm   = (int*)(misc + 16384);
    int*   counts = (int*)(misc + 24576);
    int*   offs   = (int*)(misc + 24640);
    int*   cursor = (int*)(misc + 24704);

    // Aliased split-plane buffers (dead before their host region is written):
    unsigned short* xs_hi = (unsigned short*)(ws + 33554432);            // res1 region
    unsigned short* xs_lo = (unsigned short*)(ws + 33554432 + 4194304);
    unsigned short* wi_hi = (unsigned short*)(ws + 54525952);            // w1t region
    unsigned short* wi_lo = (unsigned short*)(ws + 54525952 + 6291456);
    unsigned short* o_hi  = (unsigned short*)(ws + 41943040);            // x1 region
    unsigned short* o_lo  = (unsigned short*)(ws + 41943040 + 4194304);
    unsigned short* wo_hi = (unsigned short*)(ws + 88080384);            // w2t region
    unsigned short* wo_lo = (unsigned short*)(ws + 88080384 + 2097152);

    // Attention partials in the w1t region (dead until expert-weight transposes):
    float* opart = (float*)(ws + 54525952);
    float* mpart = (float*)(ws + 54525952 + 16777216);
    float* lpart = (float*)(ws + 54525952 + 17039360);

    // MoE gemm2 split-K partials (dead regions post-attn): qkvl tail + vth/vtl
    float* mp0 = (float*)(ws + 16777216);   // 8 MB
    float* mp1 = (float*)(ws + 25165824);   // 8 MB

    zero_counts_kernel<<<dim3(1), dim3(64), 0, stream>>>(counts);

    // --- split x and in_proj_w; QKV = x @ wi^T + bi -> split planes, Q pre-scaled
    split_bf16_kernel<<<dim3((TT * DD / 4 + 255) / 256), dim3(256), 0, stream>>>(x, xs_hi, xs_lo, TT * DD / 4);
    split_bf16_kernel<<<dim3((3 * DD * DD / 4 + 255) / 256), dim3(256), 0, stream>>>(wi, wi_hi, wi_lo, 3 * DD * DD / 4);
    gemm_split_kernel<<<dim3(3 * DD / 64, TT / 128), dim3(256), 0, stream>>>(
        xs_hi, xs_lo, wi_hi, wi_lo, bi, (const float*)nullptr,
        (float*)nullptr, qkvh, qkvl, DD, TT, 3 * DD, DD);

    // --- V^T planes for the PV MFMA B-operand
    vtrans_kernel<<<dim3(SS / 64, 2 * NHD), dim3(256), 0, stream>>>(qkvh, vth);
    vtrans_kernel<<<dim3(SS / 64, 2 * NHD), dim3(256), 0, stream>>>(qkvl, vtl);

    // --- split-precision MFMA flash attention (kv-split x2) + combine
    attn_mfma_kernel<<<dim3(SS / 64, 2 * NHD, 2), dim3(256), 0, stream>>>(
        qkvh, qkvl, vth, vtl, opart, mpart, lpart);
    attn_combine_kernel<<<dim3(TT), dim3(256), 0, stream>>>(opart, mpart, lpart, o_hi, o_lo);

    // --- split out_proj_w; res1 = x + o @ wo^T + bo (fp32 out)
    split_bf16_kernel<<<dim3((DD * DD / 4 + 255) / 256), dim3(256), 0, stream>>>(wo, wo_hi, wo_lo, DD * DD / 4);
    gemm_split_kernel<<<dim3(DD / 64, TT / 128), dim3(256), 0, stream>>>(
        o_hi, o_lo, wo_hi, wo_lo, bo, x,
        res1, (unsigned short*)nullptr, (unsigned short*)nullptr, 0, TT, DD, DD);

    // --- fused LN1 + routing -> x1, x1b, eid, gate, counts
    ln_route_kernel<<<dim3(TT), dim3(256), 0, stream>>>(
        res1, g1, be1, x1, x1b, wgr, bgr, wex, bex, eid, gate, counts);
    offsets_kernel<<<dim3(1), dim3(64), 0, stream>>>(counts, offs, cursor);
    scatter_kernel<<<dim3(TT / 256), dim3(256), 0, stream>>>(eid, cursor, perm);

    // --- expert weights -> bf16 [N][K] (overwrites attn partials: now dead)
    transpose_bf16_kernel<<<dim3(FF / 32, DD / 32, NE), dim3(256), 0, stream>>>(w1, w1t, DD, FF);
    transpose_bf16_kernel<<<dim3(DD / 32, FF / 32, NE), dim3(256), 0, stream>>>(w2, w2t, FF, DD);

    // --- sparse expert FFN (bf16 MFMA, pipelined; gemm2 split-K x2 + combine)
    moe_gemm1_kernel<<<dim3(FF / 64, NE * 32), dim3(256), 0, stream>>>(x1b, w1t, b1, offs, perm, hbuf);
    moe_gemm2_kernel<<<dim3(DD / 64, NE * 32, 2), dim3(256), 0, stream>>>(hbuf, w2t, offs, mp0, mp1);
    moe2_combine_kernel<<<dim3(TT), dim3(256), 0, stream>>>(mp0, mp1, offs, perm, gate, b2, x1, res2);

    // --- LN2 -> final output (fp32)
    ln_kernel<<<dim3(TT), dim3(256), 0, stream>>>(res2, g2, be2, out);
}

// Round 8
// 273.680 us; speedup vs baseline: 1.3386x; 1.0652x over previous
//
#include <hip/hip_runtime.h>
#include <hip/hip_bf16.h>

// Problem constants (B=2, S=1024, D=1024, F=2048, H=16, hd=64, G=4, Epg=2, E=8)
#define TT 2048
#define DD 1024
#define FF 2048
#define SS 1024
#define NHD 16
#define HDD 64
#define NG 4
#define EPG 2
#define NE 8

// 0.125 (1/sqrt(hd)) * log2(e): puts QK^T scores in exp2 domain.
#define QSC 0.18033688011112042f

typedef __attribute__((ext_vector_type(8))) short bf16x8;
typedef __attribute__((ext_vector_type(4))) float f32x4;
typedef __attribute__((ext_vector_type(4))) unsigned short ush4;

__device__ __forceinline__ unsigned short f2bf(float x) {
    unsigned int u = __float_as_uint(x);
    u = (u + 0x7fffu + ((u >> 16) & 1u)) >> 16;
    return (unsigned short)u;
}
__device__ __forceinline__ float bf2f(unsigned short h) {
    return __uint_as_float((unsigned int)h << 16);
}

__device__ __forceinline__ float wave_sum(float s) {
#pragma unroll
    for (int off = 32; off > 0; off >>= 1) s += __shfl_xor(s, off);
    return s;
}

// async global -> LDS, 16B per lane; lds dest = wave-uniform base + lane*16
__device__ __forceinline__ void gl16(const void* g, void* l) {
    auto gp = reinterpret_cast<const unsigned int __attribute__((address_space(1)))*>(
        (unsigned long long)g);
    auto lp = reinterpret_cast<unsigned int __attribute__((address_space(3)))*>(
        (unsigned int)(unsigned long long)l);
    __builtin_amdgcn_global_load_lds(gp, lp, 16, 0, 0);
}

// ---------------------------------------------------------------------------
// fp32 -> bf16 hi/lo split planes
// ---------------------------------------------------------------------------
__global__ __launch_bounds__(256) void split_bf16_kernel(
    const float* __restrict__ in, unsigned short* __restrict__ hi,
    unsigned short* __restrict__ lo, int n4)
{
    const int i = blockIdx.x * 256 + threadIdx.x;
    if (i >= n4) return;
    const float4 v = ((const float4*)in)[i];
    float vv[4] = {v.x, v.y, v.z, v.w};
    ush4 h, l;
#pragma unroll
    for (int j = 0; j < 4; ++j) {
        const unsigned short hb = f2bf(vv[j]);
        ((unsigned short*)&h)[j] = hb;
        ((unsigned short*)&l)[j] = f2bf(vv[j] - bf2f(hb));
    }
    ((ush4*)hi)[i] = h;
    ((ush4*)lo)[i] = l;
}

// ---------------------------------------------------------------------------
// Split-precision GEMM: C[M,N] = A[M,K] . B[N,K]^T (+bias) (+resid).
// 3-term MFMA. 128(M)x64(N) tile, BK=64, 4 waves each 32 rows x 64 cols.
// Split-K via gridDim.z: block z covers K-range [z*K/nz, (z+1)*K/nz), writes
// C + z*M*N. bias/resid nullable.
// ---------------------------------------------------------------------------
__global__ __launch_bounds__(256, 3) void gemm_split_kernel(
    const unsigned short* __restrict__ Ah, const unsigned short* __restrict__ Al,
    const unsigned short* __restrict__ Bh, const unsigned short* __restrict__ Bl,
    const float* __restrict__ bias, const float* __restrict__ resid,
    float* __restrict__ C, unsigned short* __restrict__ Chi,
    unsigned short* __restrict__ Clo, int qscale_n, int M, int N, int K)
{
    __shared__ unsigned short sAh[128 * 64];
    __shared__ unsigned short sAl[128 * 64];
    __shared__ unsigned short sBh[64 * 64];
    __shared__ unsigned short sBl[64 * 64];
    const int tid = threadIdx.x;
    const int lane = tid & 63, wid = tid >> 6;
    const int l15 = lane & 15, lg = lane >> 4;
    const int n0 = blockIdx.x << 6, m0 = blockIdx.y << 7;
    const int kper = K / gridDim.z;
    const int kbeg = blockIdx.z * kper, kend = kbeg + kper;
    float* __restrict__ Cz = C ? (C + (size_t)blockIdx.z * M * N) : C;

    f32x4 acc[2][4];
#pragma unroll
    for (int mi = 0; mi < 2; ++mi)
#pragma unroll
        for (int ni = 0; ni < 4; ++ni) acc[mi][ni] = (f32x4){0.f, 0.f, 0.f, 0.f};

    for (int k0 = kbeg; k0 < kend; k0 += 64) {
#pragma unroll
        for (int r = 0; r < 4; ++r) {
            const int s = (r << 8) + tid;
            const int row = s >> 3;
            const int cs = (s & 7) ^ (row & 7);
            const int lb = (s & ~63) << 3;
            const size_t ga = (size_t)(m0 + row) * K + k0 + (cs << 3);
            gl16(Ah + ga, &sAh[lb]);
            gl16(Al + ga, &sAl[lb]);
        }
#pragma unroll
        for (int r = 0; r < 2; ++r) {
            const int s = (r << 8) + tid;
            const int row = s >> 3;
            const int cs = (s & 7) ^ (row & 7);
            const int lb = (s & ~63) << 3;
            const size_t gb = (size_t)(n0 + row) * K + k0 + (cs << 3);
            gl16(Bh + gb, &sBh[lb]);
            gl16(Bl + gb, &sBl[lb]);
        }
        __syncthreads();
#pragma unroll
        for (int ks = 0; ks < 2; ++ks) {
            bf16x8 ah[2], al[2], bh[4], bl[4];
            const int ac = (ks << 2) + lg;
#pragma unroll
            for (int i = 0; i < 2; ++i) {
                const int ar = (wid << 5) + (i << 4) + l15;
                const int pa = ((ar << 3) | (ac ^ (ar & 7))) << 3;
                ah[i] = *(const bf16x8*)&sAh[pa];
                al[i] = *(const bf16x8*)&sAl[pa];
            }
#pragma unroll
            for (int i = 0; i < 4; ++i) {
                const int br = (i << 4) + l15;
                const int pb = ((br << 3) | (ac ^ (br & 7))) << 3;
                bh[i] = *(const bf16x8*)&sBh[pb];
                bl[i] = *(const bf16x8*)&sBl[pb];
            }
#pragma unroll
            for (int mi = 0; mi < 2; ++mi)
#pragma unroll
                for (int ni = 0; ni < 4; ++ni) {
                    acc[mi][ni] = __builtin_amdgcn_mfma_f32_16x16x32_bf16(ah[mi], bh[ni], acc[mi][ni], 0, 0, 0);
                    acc[mi][ni] = __builtin_amdgcn_mfma_f32_16x16x32_bf16(ah[mi], bl[ni], acc[mi][ni], 0, 0, 0);
                    acc[mi][ni] = __builtin_amdgcn_mfma_f32_16x16x32_bf16(al[mi], bh[ni], acc[mi][ni], 0, 0, 0);
                }
        }
        __syncthreads();
    }
#pragma unroll
    for (int mi = 0; mi < 2; ++mi)
#pragma unroll
        for (int ni = 0; ni < 4; ++ni)
#pragma unroll
            for (int r2 = 0; r2 < 4; ++r2) {
                const int m = m0 + (wid << 5) + (mi << 4) + (lg << 2) + r2;
                const int n = n0 + (ni << 4) + l15;
                float v = acc[mi][ni][r2];
                if (bias) v += bias[n];
                if (resid) v += resid[(size_t)m * N + n];
                const size_t idx = (size_t)m * N + n;
                if (Chi) {
                    if (n < qscale_n) v *= QSC;
                    const unsigned short hb = f2bf(v);
                    Chi[idx] = hb;
                    Clo[idx] = f2bf(v - bf2f(hb));
                } else {
                    Cz[idx] = v;
                }
            }
}

// ---------------------------------------------------------------------------
// V^T extraction: bf16 plane [t][3072] -> [bh][64 d][1024 s] transposed plane.
// ---------------------------------------------------------------------------
__global__ __launch_bounds__(256) void vtrans_kernel(
    const unsigned short* __restrict__ src, unsigned short* __restrict__ dst)
{
    __shared__ unsigned short tile[64][65];
    const int bh = blockIdx.y, b = bh >> 4, h = bh & 15;
    const int s0 = blockIdx.x << 6;
    const int tid = threadIdx.x;
#pragma unroll
    for (int r = 0; r < 2; ++r) {
        const int sl = tid + (r << 8);
        const int rr = sl >> 3, c8 = (sl & 7) << 3;
        const bf16x8 v = *(const bf16x8*)(src + (size_t)(b * SS + s0 + rr) * 3072 + 2048 + h * HDD + c8);
#pragma unroll
        for (int j = 0; j < 8; ++j) tile[rr][c8 + j] = ((const unsigned short*)&v)[j];
    }
    __syncthreads();
#pragma unroll
    for (int r = 0; r < 2; ++r) {
        const int sl = tid + (r << 8);
        const int d = sl >> 3, s8 = (sl & 7) << 3;
        bf16x8 o;
#pragma unroll
        for (int j = 0; j < 8; ++j) ((unsigned short*)&o)[j] = tile[s8 + j][d];
        *(bf16x8*)(dst + (size_t)(bh * HDD + d) * SS + s0 + s8) = o;
    }
}

// ---------------------------------------------------------------------------
// Split-precision MFMA flash attention, kv-split x2, Q in registers.
// QK^T computed SWAPPED (mfma(K,Q) -> D[kv][q]) so each lane owns one q-row's
// 16 kv scores: in-lane softmax + 2 shfl_xor, vectorized b64 P stores.
// ---------------------------------------------------------------------------
__global__ __launch_bounds__(256, 4) void attn_mfma_kernel(
    const unsigned short* __restrict__ qh, const unsigned short* __restrict__ ql,
    const unsigned short* __restrict__ vth, const unsigned short* __restrict__ vtl,
    float* __restrict__ opart, float* __restrict__ mpart, float* __restrict__ lpart)
{
    __shared__ unsigned short sKh[4096], sKl[4096];   // K tiles; P[q][kv] after QK
    __shared__ unsigned short sVh[4096], sVl[4096];
    const int bh = blockIdx.y, b = bh >> 4, h = bh & 15;
    const int q0 = blockIdx.x << 6;
    const int z = blockIdx.z;
    const int tid = threadIdx.x, lane = tid & 63, w = tid >> 6;
    const int l15 = lane & 15, lg = lane >> 4;

    // stage Q tile through (currently dead) sK, pull fragments to registers
#pragma unroll
    for (int r = 0; r < 2; ++r) {
        const int s = (r << 8) + tid;
        const int row = s >> 3;
        const int cs = (s & 7) ^ (row & 7);
        const int lb = (s & ~63) << 3;
        const size_t gq = (size_t)(b * SS + q0 + row) * 3072 + h * HDD + (cs << 3);
        gl16(qh + gq, &sKh[lb]);
        gl16(ql + gq, &sKl[lb]);
    }
    __syncthreads();
    bf16x8 qah[2], qal[2];   // B-operand fragments: this lane's q = (w<<4)+l15
#pragma unroll
    for (int ks = 0; ks < 2; ++ks) {
        const int ar = (w << 4) + l15;
        const int ac = (ks << 2) + lg;
        const int pa = ((ar << 3) | (ac ^ (ar & 7))) << 3;
        qah[ks] = *(const bf16x8*)&sKh[pa];
        qal[ks] = *(const bf16x8*)&sKl[pa];
    }
    __syncthreads();

    f32x4 accO[4];
#pragma unroll
    for (int nt = 0; nt < 4; ++nt) accO[nt] = (f32x4){0.f, 0.f, 0.f, 0.f};
    float m_run = -3.0e38f, l_run = 0.f;   // state for q = q0 + (w<<4) + l15

    const int kvbeg = z << 9;
    for (int kv0 = kvbeg; kv0 < kvbeg + 512; kv0 += 64) {
        // stage K tile + V^T tile (async direct-to-LDS)
#pragma unroll
        for (int r = 0; r < 2; ++r) {
            const int s = (r << 8) + tid;
            const int row = s >> 3;
            const int cs = (s & 7) ^ (row & 7);
            const int lb = (s & ~63) << 3;
            const size_t gk = (size_t)(b * SS + kv0 + row) * 3072 + DD + h * HDD + (cs << 3);
            gl16(qh + gk, &sKh[lb]);
            gl16(ql + gk, &sKl[lb]);
            const size_t gv = (size_t)(bh * HDD + row) * SS + kv0 + (cs << 3);
            gl16(vth + gv, &sVh[lb]);
            gl16(vtl + gv, &sVl[lb]);
        }
        __syncthreads();

        // QK^T swapped: sacc[i][r2] = S[kv = i*16 + lg*4 + r2][q = (w<<4)+l15]
        f32x4 sacc[4];
#pragma unroll
        for (int i = 0; i < 4; ++i) sacc[i] = (f32x4){0.f, 0.f, 0.f, 0.f};
        __builtin_amdgcn_s_setprio(1);
#pragma unroll
        for (int ks = 0; ks < 2; ++ks) {
            const int ac = (ks << 2) + lg;
#pragma unroll
            for (int i = 0; i < 4; ++i) {
                const int br = (i << 4) + l15;
                const int pb = ((br << 3) | (ac ^ (br & 7))) << 3;
                const bf16x8 kbh = *(const bf16x8*)&sKh[pb];
                const bf16x8 kbl = *(const bf16x8*)&sKl[pb];
                sacc[i] = __builtin_amdgcn_mfma_f32_16x16x32_bf16(kbh, qah[ks], sacc[i], 0, 0, 0);
                sacc[i] = __builtin_amdgcn_mfma_f32_16x16x32_bf16(kbh, qal[ks], sacc[i], 0, 0, 0);
                sacc[i] = __builtin_amdgcn_mfma_f32_16x16x32_bf16(kbl, qah[ks], sacc[i], 0, 0, 0);
            }
        }
        __builtin_amdgcn_s_setprio(0);
        __syncthreads();   // all waves done reading K before P overwrites it

        // in-lane online softmax (exp2 domain): 16 values per lane, one q-row
        float mx = sacc[0][0];
#pragma unroll
        for (int i = 0; i < 4; ++i)
#pragma unroll
            for (int r2 = 0; r2 < 4; ++r2) mx = fmaxf(mx, sacc[i][r2]);
        mx = fmaxf(mx, __shfl_xor(mx, 16));
        mx = fmaxf(mx, __shfl_xor(mx, 32));
        const float mn = fmaxf(m_run, mx);
        const float corr = exp2f(m_run - mn);
        m_run = mn;
        float ls = 0.f;
        const int qrow = (w << 4) | l15;
#pragma unroll
        for (int i = 0; i < 4; ++i) {
            ush4 hp, lp;
#pragma unroll
            for (int r2 = 0; r2 < 4; ++r2) {
                const float p = exp2f(sacc[i][r2] - mn);
                ls += p;
                const unsigned short hb = (unsigned short)(__float_as_uint(p) >> 16);
                hp[r2] = hb;
                lp[r2] = (unsigned short)(__float_as_uint(p - bf2f(hb)) >> 16);
            }
            const int kvb = (i << 4) + (lg << 2);
            const int idx = (qrow << 6) + (((kvb >> 3) ^ (qrow & 7)) << 3) + (kvb & 7);
            *(ush4*)&sKh[idx] = hp;
            *(ush4*)&sKl[idx] = lp;
        }
        ls += __shfl_xor(ls, 16);
        ls += __shfl_xor(ls, 32);
        l_run = l_run * corr + ls;
        // redistribute corr to accO rows (q = (w<<4) + lg*4 + r2)
        float c4[4];
#pragma unroll
        for (int r2 = 0; r2 < 4; ++r2)
            c4[r2] = __shfl(corr, (lane & 48) | ((lg << 2) + r2));
#pragma unroll
        for (int nt = 0; nt < 4; ++nt)
#pragma unroll
            for (int r2 = 0; r2 < 4; ++r2) accO[nt][r2] *= c4[r2];
        // no barrier: each wave reads back only its own 16 q-rows

        // PV: O[q][d=nt*16+l15] += P[q][kv] * V[kv][d]
        __builtin_amdgcn_s_setprio(1);
#pragma unroll
        for (int ks = 0; ks < 2; ++ks) {
            const int qq = (w << 4) + l15;
            const int slot = (ks << 2) + lg;
            const int pidx = (qq << 6) + ((slot ^ (qq & 7)) << 3);
            const bf16x8 pah = *(const bf16x8*)&sKh[pidx];
            const bf16x8 pal = *(const bf16x8*)&sKl[pidx];
            const int ac = (ks << 2) + lg;
#pragma unroll
            for (int nt = 0; nt < 4; ++nt) {
                const int dr = (nt << 4) + l15;
                const int pv = ((dr << 3) | (ac ^ (dr & 7))) << 3;
                const bf16x8 vbh = *(const bf16x8*)&sVh[pv];
                const bf16x8 vbl = *(const bf16x8*)&sVl[pv];
                accO[nt] = __builtin_amdgcn_mfma_f32_16x16x32_bf16(pah, vbh, accO[nt], 0, 0, 0);
                accO[nt] = __builtin_amdgcn_mfma_f32_16x16x32_bf16(pah, vbl, accO[nt], 0, 0, 0);
                accO[nt] = __builtin_amdgcn_mfma_f32_16x16x32_bf16(pal, vbh, accO[nt], 0, 0, 0);
            }
        }
        __builtin_amdgcn_s_setprio(0);
        __syncthreads();   // P/V reads done before next tile's staging
    }

    // epilogue: unnormalized partial O' + per-row (m,l)
#pragma unroll
    for (int nt = 0; nt < 4; ++nt)
#pragma unroll
        for (int r2 = 0; r2 < 4; ++r2) {
            const int qq = q0 + (w << 4) + (lg << 2) + r2;
            const int dd = h * HDD + (nt << 4) + l15;
            opart[((size_t)z * TT + b * SS + qq) * DD + dd] = accO[nt][r2];
        }
    if (lane < 16) {
        const int qq = q0 + (w << 4) + lane;
        const int idx = z * (32 * SS) + bh * SS + qq;
        mpart[idx] = m_run;
        lpart[idx] = l_run;
    }
}

// ---------------------------------------------------------------------------
// Combine the 2 kv-split partials -> split o hi/lo planes (exp2 domain m/l).
// ---------------------------------------------------------------------------
__global__ __launch_bounds__(256) void attn_combine_kernel(
    const float* __restrict__ opart, const float* __restrict__ mpart,
    const float* __restrict__ lpart, unsigned short* __restrict__ ohi,
    unsigned short* __restrict__ olo)
{
    const int t = blockIdx.x;
    const int tid = threadIdx.x;
    const int b = t >> 10, q = t & 1023;
    const int d0 = tid << 2;
    const int bh = (b << 4) + (d0 >> 6);
    const int mi = bh * SS + q;
    const float m0 = mpart[mi], m1 = mpart[32 * SS + mi];
    const float l0 = lpart[mi], l1 = lpart[32 * SS + mi];
    const float m = fmaxf(m0, m1);
    const float e0 = exp2f(m0 - m), e1 = exp2f(m1 - m);
    const float inv = 1.0f / (l0 * e0 + l1 * e1);
    const float4 a = *(const float4*)(opart + (size_t)t * DD + d0);
    const float4 c = *(const float4*)(opart + (size_t)(TT + t) * DD + d0);
    const float vv[4] = { (a.x * e0 + c.x * e1) * inv, (a.y * e0 + c.y * e1) * inv,
                          (a.z * e0 + c.z * e1) * inv, (a.w * e0 + c.w * e1) * inv };
    ush4 hh, ll;
#pragma unroll
    for (int j = 0; j < 4; ++j) {
        const unsigned short hb = f2bf(vv[j]);
        hh[j] = hb;
        ll[j] = f2bf(vv[j] - bf2f(hb));
    }
    *(ush4*)(ohi + (size_t)t * DD + d0) = hh;
    *(ush4*)(olo + (size_t)t * DD + d0) = ll;
}

// ---------------------------------------------------------------------------
// LayerNorm per row (LN2).
// ---------------------------------------------------------------------------
__global__ __launch_bounds__(256) void ln_kernel(
    const float* __restrict__ in, const float* __restrict__ gamma,
    const float* __restrict__ beta, float* __restrict__ outf)
{
    const int t = blockIdx.x;
    const int tid = threadIdx.x;
    __shared__ float red[8];
    const float4 v = ((const float4*)(in + (size_t)t * DD))[tid];
    float s = v.x + v.y + v.z + v.w;
    s = wave_sum(s);
    const int wid = tid >> 6, lane = tid & 63;
    if (lane == 0) red[wid] = s;
    __syncthreads();
    const float mu = (red[0] + red[1] + red[2] + red[3]) * (1.0f / DD);
    const float d0 = v.x - mu, d1 = v.y - mu, d2 = v.z - mu, d3 = v.w - mu;
    float q = d0 * d0 + d1 * d1 + d2 * d2 + d3 * d3;
    q = wave_sum(q);
    if (lane == 0) red[4 + wid] = q;
    __syncthreads();
    const float var = (red[4] + red[5] + red[6] + red[7]) * (1.0f / DD);
    const float rstd = 1.0f / sqrtf(var + 1e-5f);
    const float4 g4 = ((const float4*)gamma)[tid];
    const float4 b4 = ((const float4*)beta)[tid];
    float4 ov = { d0 * rstd * g4.x + b4.x, d1 * rstd * g4.y + b4.y,
                  d2 * rstd * g4.z + b4.z, d3 * rstd * g4.w + b4.w };
    ((float4*)(outf + (size_t)t * DD))[tid] = ov;
}

// ---------------------------------------------------------------------------
// Fused out-proj-combine + LN1 + hierarchical top-1 routing. One token/block.
// res1 = x + p0 + p1 + bo (split-K partials), then LN + routing.
// ---------------------------------------------------------------------------
__global__ __launch_bounds__(256) void ln_route_kernel(
    const float* __restrict__ x, const float* __restrict__ p0,
    const float* __restrict__ p1, const float* __restrict__ bo,
    const float* __restrict__ gamma, const float* __restrict__ beta,
    float* __restrict__ outf, unsigned short* __restrict__ outb,
    const float* __restrict__ wg, const float* __restrict__ bg,
    const float* __restrict__ we, const float* __restrict__ be,
    int* __restrict__ eid, float* __restrict__ gate, int* __restrict__ counts)
{
    const int t = blockIdx.x;
    const int tid = threadIdx.x;
    __shared__ float red[8];
    __shared__ float red2[4][12];
    const float4 xv = ((const float4*)(x + (size_t)t * DD))[tid];
    const float4 a4 = ((const float4*)(p0 + (size_t)t * DD))[tid];
    const float4 c4v = ((const float4*)(p1 + (size_t)t * DD))[tid];
    const float4 bo4 = ((const float4*)bo)[tid];
    const float4 v = { xv.x + a4.x + c4v.x + bo4.x, xv.y + a4.y + c4v.y + bo4.y,
                       xv.z + a4.z + c4v.z + bo4.z, xv.w + a4.w + c4v.w + bo4.w };
    float s = v.x + v.y + v.z + v.w;
    s = wave_sum(s);
    const int wid = tid >> 6, lane = tid & 63;
    if (lane == 0) red[wid] = s;
    __syncthreads();
    const float mu = (red[0] + red[1] + red[2] + red[3]) * (1.0f / DD);
    const float d0 = v.x - mu, d1 = v.y - mu, d2 = v.z - mu, d3 = v.w - mu;
    float q = d0 * d0 + d1 * d1 + d2 * d2 + d3 * d3;
    q = wave_sum(q);
    if (lane == 0) red[4 + wid] = q;
    __syncthreads();
    const float var = (red[4] + red[5] + red[6] + red[7]) * (1.0f / DD);
    const float rstd = 1.0f / sqrtf(var + 1e-5f);
    const float4 g4 = ((const float4*)gamma)[tid];
    const float4 b4 = ((const float4*)beta)[tid];
    const float o0 = d0 * rstd * g4.x + b4.x;
    const float o1 = d1 * rstd * g4.y + b4.y;
    const float o2 = d2 * rstd * g4.z + b4.z;
    const float o3 = d3 * rstd * g4.w + b4.w;
    float4 ov = {o0, o1, o2, o3};
    ((float4*)(outf + (size_t)t * DD))[tid] = ov;
    ush4 wv = { f2bf(o0), f2bf(o1), f2bf(o2), f2bf(o3) };
    *(ush4*)(outb + (size_t)t * DD + (tid << 2)) = wv;

    // routing partials: 4 group + 8 expert logits
    float pz[12];
#pragma unroll
    for (int k = 0; k < 12; ++k) pz[k] = 0.f;
    const float xo[4] = {o0, o1, o2, o3};
#pragma unroll
    for (int j = 0; j < 4; ++j) {
        const int c = (tid << 2) + j;
        const float xvv = xo[j];
        const float4 wgv = *(const float4*)(wg + c * NG);
        pz[0] = fmaf(xvv, wgv.x, pz[0]);
        pz[1] = fmaf(xvv, wgv.y, pz[1]);
        pz[2] = fmaf(xvv, wgv.z, pz[2]);
        pz[3] = fmaf(xvv, wgv.w, pz[3]);
#pragma unroll
        for (int g = 0; g < NG; ++g) {
            const float2 wev = *(const float2*)(we + ((size_t)g * DD + c) * EPG);
            pz[4 + 2 * g]     = fmaf(xvv, wev.x, pz[4 + 2 * g]);
            pz[4 + 2 * g + 1] = fmaf(xvv, wev.y, pz[4 + 2 * g + 1]);
        }
    }
#pragma unroll
    for (int k = 0; k < 12; ++k) pz[k] = wave_sum(pz[k]);
    if (lane == 0) {
#pragma unroll
        for (int k = 0; k < 12; ++k) red2[wid][k] = pz[k];
    }
    __syncthreads();
    if (tid == 0) {
        float zs[12];
#pragma unroll
        for (int k = 0; k < 12; ++k)
            zs[k] = red2[0][k] + red2[1][k] + red2[2][k] + red2[3][k];
        float z[NG];
#pragma unroll
        for (int g = 0; g < NG; ++g) z[g] = zs[g] + bg[g];
        int gi = 0; float zb = z[0];
#pragma unroll
        for (int g = 1; g < NG; ++g) if (z[g] > zb) { zb = z[g]; gi = g; }
        float se = 0.f;
#pragma unroll
        for (int g = 0; g < NG; ++g) se += __expf(z[g] - zb);
        const float gprob = 1.0f / se;
        float e0 = 0.f, e1 = 0.f;
#pragma unroll
        for (int g = 0; g < NG; ++g) {
            if (g == gi) {
                e0 = zs[4 + 2 * g] + be[g * EPG + 0];
                e1 = zs[4 + 2 * g + 1] + be[g * EPG + 1];
            }
        }
        const int ei = (e1 > e0) ? 1 : 0;
        const float ehi = ei ? e1 : e0, elo = ei ? e0 : e1;
        const float eprob = 1.0f / (1.0f + __expf(elo - ehi));
        eid[t] = gi * EPG + ei;
        gate[t] = gprob * eprob;
        atomicAdd(&counts[gi * EPG + ei], 1);
    }
}

__global__ void zero_counts_kernel(int* __restrict__ counts) {
    if (threadIdx.x < NE) counts[threadIdx.x] = 0;
}

__global__ void offsets_kernel(const int* __restrict__ counts, int* __restrict__ offs,
                               int* __restrict__ cursor) {
    if (threadIdx.x == 0) {
        int run = 0;
        for (int e = 0; e < NE; ++e) { offs[e] = run; cursor[e] = run; run += counts[e]; }
        offs[NE] = run;
    }
}

__global__ __launch_bounds__(256) void scatter_kernel(const int* __restrict__ eid,
                                                      int* __restrict__ cursor,
                                                      int* __restrict__ perm) {
    const int t = blockIdx.x * 256 + threadIdx.x;
    const int slot = atomicAdd(&cursor[eid[t]], 1);
    perm[slot] = t;
}

// ---------------------------------------------------------------------------
// fp32 [batch][R][C] -> bf16 [batch][C][R] (LDS-tiled transpose + convert)
// ---------------------------------------------------------------------------
__global__ __launch_bounds__(256) void transpose_bf16_kernel(
    const float* __restrict__ in, unsigned short* __restrict__ out, int R, int C)
{
    __shared__ float tile[32][33];
    const int c0 = blockIdx.x << 5, r0 = blockIdx.y << 5;
    const size_t bo = (size_t)blockIdx.z * R * C;
    const int tc = threadIdx.x & 31, tr8 = threadIdx.x >> 5;
#pragma unroll
    for (int p = 0; p < 4; ++p) {
        const int rr = tr8 + (p << 3);
        tile[rr][tc] = in[bo + (size_t)(r0 + rr) * C + c0 + tc];
    }
    __syncthreads();
#pragma unroll
    for (int p = 0; p < 4; ++p) {
        const int rr = tr8 + (p << 3);
        out[bo + (size_t)(c0 + rr) * R + r0 + tc] = f2bf(tile[tc][rr]);
    }
}

// ---------------------------------------------------------------------------
// MoE GEMM 1: h[slot][F] = relu(x1b[perm[slot]] . w1t[e]^T + b1[e])
// 64x64 tile, BK=64, double-buffered LDS, gl16 staging, prefetch pipeline.
// ---------------------------------------------------------------------------
__global__ __launch_bounds__(256, 4) void moe_gemm1_kernel(
    const unsigned short* __restrict__ x1b, const unsigned short* __restrict__ w1t,
    const float* __restrict__ b1, const int* __restrict__ offs,
    const int* __restrict__ perm, unsigned short* __restrict__ hbuf)
{
    const int e = blockIdx.y >> 5, mt = blockIdx.y & 31;
    const int row0 = offs[e] + (mt << 6);
    const int rend = offs[e + 1];
    if (row0 >= rend) return;
    const int valid = min(rend - row0, 64);
    const int n0 = blockIdx.x << 6;
    __shared__ unsigned short sA[2][64 * 64];
    __shared__ unsigned short sB[2][64 * 64];
    const int tid = threadIdx.x;
    const int lane = tid & 63, w = tid >> 6;
    const int l15 = lane & 15, lg = lane >> 4;

    size_t abase[2], bbase[2];
    int lbs[2];
#pragma unroll
    for (int r = 0; r < 2; ++r) {
        const int s = (r << 8) + tid;
        const int row = s >> 3;
        const int cs = (s & 7) ^ (row & 7);
        lbs[r] = (s & ~63) << 3;
        const int tk = perm[min(row0 + row, rend - 1)];
        abase[r] = (size_t)tk * DD + (cs << 3);
        bbase[r] = ((size_t)e * FF + n0 + row) * DD + (cs << 3);
    }

    f32x4 acc[4];
#pragma unroll
    for (int nt = 0; nt < 4; ++nt) acc[nt] = (f32x4){0.f, 0.f, 0.f, 0.f};

#pragma unroll
    for (int r = 0; r < 2; ++r) {
        gl16(x1b + abase[r], &sA[0][lbs[r]]);
        gl16(w1t + bbase[r], &sB[0][lbs[r]]);
    }
    __syncthreads();
    int cur = 0;
    for (int k0 = 0; k0 < DD; k0 += 64) {
        const int nxt = k0 + 64;
        if (nxt < DD) {
#pragma unroll
            for (int r = 0; r < 2; ++r) {
                gl16(x1b + abase[r] + nxt, &sA[cur ^ 1][lbs[r]]);
                gl16(w1t + bbase[r] + nxt, &sB[cur ^ 1][lbs[r]]);
            }
        }
#pragma unroll
        for (int ks = 0; ks < 2; ++ks) {
            const int ac = (ks << 2) + lg;
            const int ar = (w << 4) + l15;
            const int pa = ((ar << 3) | (ac ^ (ar & 7))) << 3;
            const bf16x8 a = *(const bf16x8*)&sA[cur][pa];
#pragma unroll
            for (int nt = 0; nt < 4; ++nt) {
                const int br = (nt << 4) + l15;
                const int pb = ((br << 3) | (ac ^ (br & 7))) << 3;
                acc[nt] = __builtin_amdgcn_mfma_f32_16x16x32_bf16(
                    a, *(const bf16x8*)&sB[cur][pb], acc[nt], 0, 0, 0);
            }
        }
        __syncthreads();
        cur ^= 1;
    }

    const float* bias = b1 + e * FF + n0;
    const int mbase = (w << 4) + (lg << 2);
#pragma unroll
    for (int nt = 0; nt < 4; ++nt) {
        const int n = (nt << 4) + l15;
#pragma unroll
        for (int r2 = 0; r2 < 4; ++r2) {
            const int m = mbase + r2;
            if (m < valid) {
                float v = fmaxf(acc[nt][r2] + bias[n], 0.f);
                hbuf[(size_t)(row0 + m) * FF + n0 + n] = f2bf(v);
            }
        }
    }
}

// ---------------------------------------------------------------------------
// MoE GEMM 2 (split-K x2): pbuf[z][slot][D] = h[slot] . w2t[e]^T (K-half z).
// ---------------------------------------------------------------------------
__global__ __launch_bounds__(256, 4) void moe_gemm2_kernel(
    const unsigned short* __restrict__ hbuf, const unsigned short* __restrict__ w2t,
    const int* __restrict__ offs, float* __restrict__ p0, float* __restrict__ p1)
{
    const int e = blockIdx.y >> 5, mt = blockIdx.y & 31;
    const int row0 = offs[e] + (mt << 6);
    const int rend = offs[e + 1];
    if (row0 >= rend) return;
    const int valid = min(rend - row0, 64);
    const int n0 = blockIdx.x << 6;
    const int z = blockIdx.z;
    float* __restrict__ pbuf = z ? p1 : p0;
    __shared__ unsigned short sA[2][64 * 64];
    __shared__ unsigned short sB[2][64 * 64];
    const int tid = threadIdx.x;
    const int lane = tid & 63, w = tid >> 6;
    const int l15 = lane & 15, lg = lane >> 4;

    size_t abase[2], bbase[2];
    int lbs[2];
#pragma unroll
    for (int r = 0; r < 2; ++r) {
        const int s = (r << 8) + tid;
        const int row = s >> 3;
        const int cs = (s & 7) ^ (row & 7);
        lbs[r] = (s & ~63) << 3;
        abase[r] = (size_t)(row0 + row) * FF + (cs << 3);
        bbase[r] = ((size_t)e * DD + n0 + row) * FF + (cs << 3);
    }

    f32x4 acc[4];
#pragma unroll
    for (int nt = 0; nt < 4; ++nt) acc[nt] = (f32x4){0.f, 0.f, 0.f, 0.f};

    const int kbeg = z << 10, kend = kbeg + 1024;
#pragma unroll
    for (int r = 0; r < 2; ++r) {
        gl16(hbuf + abase[r] + kbeg, &sA[0][lbs[r]]);
        gl16(w2t + bbase[r] + kbeg, &sB[0][lbs[r]]);
    }
    __syncthreads();
    int cur = 0;
    for (int k0 = kbeg; k0 < kend; k0 += 64) {
        const int nxt = k0 + 64;
        if (nxt < kend) {
#pragma unroll
            for (int r = 0; r < 2; ++r) {
                gl16(hbuf + abase[r] + nxt, &sA[cur ^ 1][lbs[r]]);
                gl16(w2t + bbase[r] + nxt, &sB[cur ^ 1][lbs[r]]);
            }
        }
#pragma unroll
        for (int ks = 0; ks < 2; ++ks) {
            const int ac = (ks << 2) + lg;
            const int ar = (w << 4) + l15;
            const int pa = ((ar << 3) | (ac ^ (ar & 7))) << 3;
            const bf16x8 a = *(const bf16x8*)&sA[cur][pa];
#pragma unroll
            for (int nt = 0; nt < 4; ++nt) {
                const int br = (nt << 4) + l15;
                const int pb = ((br << 3) | (ac ^ (br & 7))) << 3;
                acc[nt] = __builtin_amdgcn_mfma_f32_16x16x32_bf16(
                    a, *(const bf16x8*)&sB[cur][pb], acc[nt], 0, 0, 0);
            }
        }
        __syncthreads();
        cur ^= 1;
    }

    const int mbase = (w << 4) + (lg << 2);
#pragma unroll
    for (int nt = 0; nt < 4; ++nt) {
        const int n = (nt << 4) + l15;
#pragma unroll
        for (int r2 = 0; r2 < 4; ++r2) {
            const int m = mbase + r2;
            if (m < valid) pbuf[(size_t)(row0 + m) * DD + n0 + n] = acc[nt][r2];
        }
    }
}

// ---------------------------------------------------------------------------
// MoE combine: res2[tk] = x1[tk] + gate[tk] * (P0[slot] + P1[slot] + b2[e])
// ---------------------------------------------------------------------------
__global__ __launch_bounds__(256) void moe2_combine_kernel(
    const float* __restrict__ p0, const float* __restrict__ p1,
    const int* __restrict__ offs, const int* __restrict__ perm,
    const float* __restrict__ gate, const float* __restrict__ b2,
    const float* __restrict__ x1, float* __restrict__ res2)
{
    const int s = blockIdx.x;
    const int tid = threadIdx.x;
    int e = 0;
#pragma unroll
    for (int g = 1; g < NE; ++g) e += (s >= offs[g]) ? 1 : 0;
    const int tk = perm[s];
    const float gt = gate[tk];
    const int c0 = tid << 2;
    const float4 a  = *(const float4*)(p0 + (size_t)s * DD + c0);
    const float4 b  = *(const float4*)(p1 + (size_t)s * DD + c0);
    const float4 bb = *(const float4*)(b2 + (size_t)e * DD + c0);
    const float4 xx = *(const float4*)(x1 + (size_t)tk * DD + c0);
    float4 o = { xx.x + gt * (a.x + b.x + bb.x), xx.y + gt * (a.y + b.y + bb.y),
                 xx.z + gt * (a.z + b.z + bb.z), xx.w + gt * (a.w + b.w + bb.w) };
    *(float4*)(res2 + (size_t)tk * DD + c0) = o;
}

// ---------------------------------------------------------------------------
extern "C" void kernel_launch(void* const* d_in, const int* in_sizes, int n_in,
                              void* d_out, int out_size, void* d_ws, size_t ws_size,
                              hipStream_t stream)
{
    (void)in_sizes; (void)n_in; (void)out_size; (void)ws_size;
    const float* x   = (const float*)d_in[0];
    const float* wi  = (const float*)d_in[1];
    const float* bi  = (const float*)d_in[2];
    const float* wo  = (const float*)d_in[3];
    const float* bo  = (const float*)d_in[4];
    const float* g1  = (const float*)d_in[5];
    const float* be1 = (const float*)d_in[6];
    const float* g2  = (const float*)d_in[7];
    const float* be2 = (const float*)d_in[8];
    const float* wgr = (const float*)d_in[9];
    const float* bgr = (const float*)d_in[10];
    const float* wex = (const float*)d_in[11];
    const float* bex = (const float*)d_in[12];
    const float* w1  = (const float*)d_in[13];
    const float* b1  = (const float*)d_in[14];
    const float* w2  = (const float*)d_in[15];
    const float* b2  = (const float*)d_in[16];
    float* out = (float*)d_out;

    char* ws = (char*)d_ws;
    unsigned short* qkvh  = (unsigned short*)(ws + 0);         // 12 MB [t][3072]
    unsigned short* qkvl  = (unsigned short*)(ws + 12582912);  // 12 MB
    unsigned short* hbuf  = (unsigned short*)(ws + 0);         // 8 MB (MoE phase)
    float* res2           = (float*)(ws + 8388608);            // 8 MB (MoE phase)
    unsigned short* vth   = (unsigned short*)(ws + 25165824);  // 4 MB [bh][64][1024]
    unsigned short* vtl   = (unsigned short*)(ws + 29360128);  // 4 MB
    float* x1             = (float*)(ws + 41943040);           // 8 MB
    unsigned short* x1b   = (unsigned short*)(ws + 50331648);  // 4 MB
    unsigned short* w1t   = (unsigned short*)(ws + 54525952);  // 32 MB
    unsigned short* w2t   = (unsigned short*)(ws + 88080384);  // 32 MB
    char* misc = ws + 121634816;
    int*   eid    = (int*)(misc);
    float* gate   = (float*)(misc + 8192);
    int*   perm   = (int*)(misc + 16384);
    int*   counts = (int*)(misc + 24576);
    int*   offs   = (int*)(misc + 24640);
    int*   cursor = (int*)(misc + 24704);

    // Aliased split-plane buffers (dead before their host region is written):
    unsigned short* xs_hi = (unsigned short*)(ws + 33554432);            // scratch region
    unsigned short* xs_lo = (unsigned short*)(ws + 33554432 + 4194304);
    unsigned short* wi_hi = (unsigned short*)(ws + 54525952);            // w1t region
    unsigned short* wi_lo = (unsigned short*)(ws + 54525952 + 6291456);
    unsigned short* o_hi  = (unsigned short*)(ws + 41943040);            // x1 region
    unsigned short* o_lo  = (unsigned short*)(ws + 41943040 + 4194304);
    unsigned short* wo_hi = (unsigned short*)(ws + 88080384);            // w2t region
    unsigned short* wo_lo = (unsigned short*)(ws + 88080384 + 2097152);

    // Attention partials in the w1t region (dead until expert-weight transposes):
    float* opart = (float*)(ws + 54525952);
    float* mpart = (float*)(ws + 54525952 + 16777216);
    float* lpart = (float*)(ws + 54525952 + 17039360);

    // Out-proj split-K partials: 16 MB at ws+0 (qkv planes dead post-attn).
    float* oproj = (float*)(ws + 0);

    // MoE gemm2 split-K partials (dead post-attn regions):
    float* mp0 = (float*)(ws + 16777216);   // 8 MB
    float* mp1 = (float*)(ws + 25165824);   // 8 MB

    zero_counts_kernel<<<dim3(1), dim3(64), 0, stream>>>(counts);

    // --- split x and in_proj_w; QKV = x @ wi^T + bi -> split planes, Q pre-scaled
    split_bf16_kernel<<<dim3((TT * DD / 4 + 255) / 256), dim3(256), 0, stream>>>(x, xs_hi, xs_lo, TT * DD / 4);
    split_bf16_kernel<<<dim3((3 * DD * DD / 4 + 255) / 256), dim3(256), 0, stream>>>(wi, wi_hi, wi_lo, 3 * DD * DD / 4);
    gemm_split_kernel<<<dim3(3 * DD / 64, TT / 128, 1), dim3(256), 0, stream>>>(
        xs_hi, xs_lo, wi_hi, wi_lo, bi, (const float*)nullptr,
        (float*)nullptr, qkvh, qkvl, DD, TT, 3 * DD, DD);

    // --- V^T planes for the PV MFMA B-operand
    vtrans_kernel<<<dim3(SS / 64, 2 * NHD), dim3(256), 0, stream>>>(qkvh, vth);
    vtrans_kernel<<<dim3(SS / 64, 2 * NHD), dim3(256), 0, stream>>>(qkvl, vtl);

    // --- split-precision MFMA flash attention (kv-split x2) + combine
    attn_mfma_kernel<<<dim3(SS / 64, 2 * NHD, 2), dim3(256), 0, stream>>>(
        qkvh, qkvl, vth, vtl, opart, mpart, lpart);
    attn_combine_kernel<<<dim3(TT), dim3(256), 0, stream>>>(opart, mpart, lpart, o_hi, o_lo);

    // --- split out_proj_w; out-proj split-K x2 -> raw fp32 partials
    split_bf16_kernel<<<dim3((DD * DD / 4 + 255) / 256), dim3(256), 0, stream>>>(wo, wo_hi, wo_lo, DD * DD / 4);
    gemm_split_kernel<<<dim3(DD / 64, TT / 128, 2), dim3(256), 0, stream>>>(
        o_hi, o_lo, wo_hi, wo_lo, (const float*)nullptr, (const float*)nullptr,
        oproj, (unsigned short*)nullptr, (unsigned short*)nullptr, 0, TT, DD, DD);

    // --- fused out-proj-combine + LN1 + routing -> x1, x1b, eid, gate, counts
    ln_route_kernel<<<dim3(TT), dim3(256), 0, stream>>>(
        x, oproj, oproj + (size_t)TT * DD, bo, g1, be1, x1, x1b,
        wgr, bgr, wex, bex, eid, gate, counts);
    offsets_kernel<<<dim3(1), dim3(64), 0, stream>>>(counts, offs, cursor);
    scatter_kernel<<<dim3(TT / 256), dim3(256), 0, stream>>>(eid, cursor, perm);

    // --- expert weights -> bf16 [N][K] (overwrites attn partials: now dead)
    transpose_bf16_kernel<<<dim3(FF / 32, DD / 32, NE), dim3(256), 0, stream>>>(w1, w1t, DD, FF);
    transpose_bf16_kernel<<<dim3(DD / 32, FF / 32, NE), dim3(256), 0, stream>>>(w2, w2t, FF, DD);

    // --- sparse expert FFN (bf16 MFMA, pipelined; gemm2 split-K x2 + combine)
    moe_gemm1_kernel<<<dim3(FF / 64, NE * 32), dim3(256), 0, stream>>>(x1b, w1t, b1, offs, perm, hbuf);
    moe_gemm2_kernel<<<dim3(DD / 64, NE * 32, 2), dim3(256), 0, stream>>>(hbuf, w2t, offs, mp0, mp1);
    moe2_combine_kernel<<<dim3(TT), dim3(256), 0, stream>>>(mp0, mp1, offs, perm, gate, b2, x1, res2);

    // --- LN2 -> final output (fp32)
    ln_kernel<<<dim3(TT), dim3(256), 0, stream>>>(res2, g2, be2, out);
}